// Round 1
// baseline (1853.873 us; speedup 1.0000x reference)
//
#include <hip/hip_runtime.h>
#include <cstdint>
#include <cstddef>

// ============================================================================
// EfficientMemoryHadamard — round 4.
//  R1: atomic-free GEMM partials. R3: register-resident bdsqr/geqrf + spec hist.
//  R4: coarse histogram ELIMINATED from hot path — register counters
//      (below / bin401 / bin402) + shuffle reduce; full coarse hist demoted to
//      early-exit fallback chain. Non-temporal stores for the Hadamard product.
// Verified assumption stack (rounds 1-3 PASSED, absmax 0.1245):
//  A1: jax threefry_partitionable; A2: quantile = order stat 33218888;
//  A3: gesdd tail gelqf->gebd2->bdsqr->ormbr; A4: LAPACK>=3.10 slartg.
// ============================================================================

#define DEV __device__ __forceinline__

typedef float nfloat4 __attribute__((ext_vector_type(4)));

constexpr long long NTOT = 33554432LL;
constexpr unsigned long long KSEL = 33218888ULL;

constexpr long long OUT_T1  = 33554432LL;
constexpr long long OUT_R1  = 33554433LL;
constexpr long long OUT_RI1 = 33619969LL;
constexpr long long OUT_T2  = 33685505LL;
constexpr long long OUT_R2  = 33685506LL;
constexpr long long OUT_RI2 = 33751042LL;

// ---- workspace layout (float units) ----
constexpr size_t OFF_SPEC   = 0;         // 2 x 2M u32 speculative fine hist (zeroed)
constexpr size_t OFF_BPART  = 0;         // alias: 2*16*65536 floats (after quantile)
constexpr size_t OFF_FB     = 4194304;   // 2 x 1M u32 fallback fine hist (zeroed)
constexpr size_t OFF_CNT    = 6291456;   // 6 u32 counters (aliases CHIST head; zeroed)
constexpr size_t ZERO_FLOATS= 6291472;   // memset range (covers SPEC+FB+CNT)
constexpr size_t OFF_CHIST  = 6291456;   // 512*2*2048 u32 partial coarse hists (fallback only)
constexpr size_t OFF_COARSE = 8388608;   // 2*2048 u32
constexpr size_t OFF_SEGS   = 8392704;   // 2*1024 u32
constexpr size_t OFF_SELR   = 8394752;   // 2*4 ints (bin, rank, valid)
constexpr size_t OFF_TSEL   = 8394768;   // 2 floats (+pad)
constexpr size_t OFF_OMT    = 8394784;   // 2*65536
constexpr size_t OFF_BIGY   = 8525856;   // 2*131072
constexpr size_t OFF_BIGQ   = 8788000;   // 2*131072
constexpr size_t OFF_ZT     = 9050144;   // 2*65536
constexpr size_t OFF_QQR    = 9181216;   // 2*65536
constexpr size_t OFF_TMAT   = 9312288;   // 2*65536
constexpr size_t OFF_GRAMP  = 9443360;   // 2*64*256
constexpr size_t OFF_S      = 9476128;   // 2*256
constexpr size_t OFF_QTOP   = 9476640;   // 2*256
constexpr size_t OFF_RG     = 9477152;   // 2*256
constexpr size_t OFF_VTL    = 9477664;   // 2*256
// total 9478176 floats ~= 37.9 MB (unchanged from r3)

// ---------------------------------------------------------------------------
#define TFR(a,b,r) { a += b; b = (b << r) | (b >> (32 - r)); b ^= a; }

DEV void d_threefry(uint32_t k0, uint32_t k1, uint32_t x0, uint32_t x1,
                    uint32_t& o0, uint32_t& o1){
  uint32_t ks2 = k0 ^ k1 ^ 0x1BD11BDAu;
  x0 += k0; x1 += k1;
  TFR(x0,x1,13) TFR(x0,x1,15) TFR(x0,x1,26) TFR(x0,x1,6)
  x0 += k1; x1 += ks2 + 1u;
  TFR(x0,x1,17) TFR(x0,x1,29) TFR(x0,x1,16) TFR(x0,x1,24)
  x0 += ks2; x1 += k0 + 2u;
  TFR(x0,x1,13) TFR(x0,x1,15) TFR(x0,x1,26) TFR(x0,x1,6)
  x0 += k0; x1 += k1 + 3u;
  TFR(x0,x1,17) TFR(x0,x1,29) TFR(x0,x1,16) TFR(x0,x1,24)
  x0 += k1; x1 += ks2 + 4u;
  TFR(x0,x1,13) TFR(x0,x1,15) TFR(x0,x1,26) TFR(x0,x1,6)
  x0 += ks2; x1 += k0 + 5u;
  o0 = x0; o1 = x1;
}

static void h_threefry(uint32_t k0, uint32_t k1, uint32_t x0, uint32_t x1,
                       uint32_t& o0, uint32_t& o1){
  uint32_t ks2 = k0 ^ k1 ^ 0x1BD11BDAu;
  x0 += k0; x1 += k1;
  TFR(x0,x1,13) TFR(x0,x1,15) TFR(x0,x1,26) TFR(x0,x1,6)
  x0 += k1; x1 += ks2 + 1u;
  TFR(x0,x1,17) TFR(x0,x1,29) TFR(x0,x1,16) TFR(x0,x1,24)
  x0 += ks2; x1 += k0 + 2u;
  TFR(x0,x1,13) TFR(x0,x1,15) TFR(x0,x1,26) TFR(x0,x1,6)
  x0 += k0; x1 += k1 + 3u;
  TFR(x0,x1,17) TFR(x0,x1,29) TFR(x0,x1,16) TFR(x0,x1,24)
  x0 += k1; x1 += ks2 + 4u;
  TFR(x0,x1,13) TFR(x0,x1,15) TFR(x0,x1,26) TFR(x0,x1,6)
  x0 += ks2; x1 += k0 + 5u;
  o0 = x0; o1 = x1;
}

DEV float erfinv_f32(float x){
  float w = -log1pf(-x*x);
  float p;
  if (w < 5.0f){
    w -= 2.5f;
    p = 2.81022636e-08f;
    p = fmaf(p, w, 3.43273939e-07f);
    p = fmaf(p, w, -3.5233877e-06f);
    p = fmaf(p, w, -4.39150654e-06f);
    p = fmaf(p, w, 0.00021858087f);
    p = fmaf(p, w, -0.00125372503f);
    p = fmaf(p, w, -0.00417768164f);
    p = fmaf(p, w, 0.246640727f);
    p = fmaf(p, w, 1.50140941f);
  } else {
    w = sqrtf(w) - 3.0f;
    p = -0.000200214257f;
    p = fmaf(p, w, 0.000100950558f);
    p = fmaf(p, w, 0.00134934322f);
    p = fmaf(p, w, -0.00367342844f);
    p = fmaf(p, w, 0.00573950773f);
    p = fmaf(p, w, -0.0076224613f);
    p = fmaf(p, w, 0.00943887047f);
    p = fmaf(p, w, 1.00167406f);
    p = fmaf(p, w, 2.83297682f);
  }
  return p * x;
}

DEV float lapy2f(float x, float y){
  float xa = fabsf(x), ya = fabsf(y);
  float w = fmaxf(xa, ya), z = fminf(xa, ya);
  if (z == 0.f) return w;
  float q = z / w;
  return w * sqrtf(1.f + q*q);
}

DEV void slartg_(float f, float g, float& c, float& s, float& r){
  if (g == 0.f){ c = 1.f; s = 0.f; r = f; }
  else if (f == 0.f){ c = 0.f; s = copysignf(1.f, g); r = fabsf(g); }
  else {
    float d = sqrtf(f*f + g*g);
    c = fabsf(f) / d;
    r = copysignf(d, f);
    s = g / r;
  }
}

DEV void slas2_(float f, float g, float h, float& ssmin, float& ssmax){
  float fa = fabsf(f), ga = fabsf(g), ha = fabsf(h);
  float fhmn = fminf(fa, ha), fhmx = fmaxf(fa, ha);
  if (fhmn == 0.f){
    ssmin = 0.f;
    if (fhmx == 0.f) ssmax = ga;
    else {
      float mx = fmaxf(fhmx, ga), mn = fminf(fhmx, ga);
      float q = mn/mx;
      ssmax = mx*sqrtf(1.f + q*q);
    }
  } else {
    if (ga < fhmx){
      float as_ = 1.f + fhmn/fhmx;
      float at_ = (fhmx - fhmn)/fhmx;
      float au = ga/fhmx; au = au*au;
      float cc = 2.f/(sqrtf(as_*as_ + au) + sqrtf(at_*at_ + au));
      ssmin = fhmn*cc; ssmax = fhmx/cc;
    } else {
      float au = fhmx/ga;
      if (au == 0.f){ ssmin = (fhmn*fhmx)/ga; ssmax = ga; }
      else {
        float as_ = 1.f + fhmn/fhmx;
        float at_ = (fhmx - fhmn)/fhmx;
        float q1 = as_*au, q2 = at_*au;
        float cc = 1.f/(sqrtf(1.f + q1*q1) + sqrtf(1.f + q2*q2));
        ssmin = (fhmn*cc)*au; ssmin = ssmin + ssmin;
        ssmax = ga/(cc + cc);
      }
    }
  }
}

DEV void slasv2_(float f, float g, float h, float& ssmin, float& ssmax,
                 float& snr, float& csr, float& snl, float& csl){
  const float eps = 5.9604645e-08f;
  float ft = f, fa = fabsf(f), ht = h, ha = fabsf(h);
  int pmax = 1;
  bool swp = (ha > fa);
  if (swp){ pmax = 3; float t; t=ft; ft=ht; ht=t; t=fa; fa=ha; ha=t; }
  float gt = g, ga = fabsf(g);
  float clt = 0.f, crt = 0.f, slt = 0.f, srt = 0.f;
  if (ga == 0.f){ ssmin = ha; ssmax = fa; clt = 1.f; crt = 1.f; slt = 0.f; srt = 0.f; }
  else {
    bool gasmal = true;
    if (ga > fa){
      pmax = 2;
      if ((fa/ga) < eps){
        gasmal = false;
        ssmax = ga;
        if (ha > 1.f) ssmin = fa/(ga/ha); else ssmin = (fa/ga)*ha;
        clt = 1.f; slt = ht/gt; srt = 1.f; crt = ft/gt;
      }
    }
    if (gasmal){
      float dd = fa - ha;
      float L = (dd == fa) ? 1.f : dd/fa;
      float Mv = gt/ft;
      float T = 2.f - L;
      float MM = Mv*Mv, TT = T*T;
      float Sv = sqrtf(TT + MM);
      float Rv = (L == 0.f) ? fabsf(Mv) : sqrtf(L*L + MM);
      float Av = 0.5f*(Sv + Rv);
      ssmin = ha/Av; ssmax = fa*Av;
      float Tv;
      if (MM == 0.f){
        if (L == 0.f) Tv = copysignf(2.f, ft)*copysignf(1.f, gt);
        else Tv = gt/copysignf(dd, ft) + Mv/T;
      } else {
        Tv = (Mv/(Sv + T) + Mv/(Rv + L))*(1.f + Av);
      }
      float Lv = sqrtf(Tv*Tv + 4.f);
      crt = 2.f/Lv; srt = Tv/Lv;
      clt = (crt + srt*Mv)/Av;
      slt = (ht/ft)*srt/Av;
    }
  }
  if (swp){ csl = srt; snl = crt; csr = slt; snr = clt; }
  else    { csl = clt; snl = slt; csr = crt; snr = srt; }
  float tsign = 1.f;
  if (pmax == 1) tsign = copysignf(1.f, csr)*copysignf(1.f, csl)*copysignf(1.f, f);
  if (pmax == 2) tsign = copysignf(1.f, snr)*copysignf(1.f, csl)*copysignf(1.f, g);
  if (pmax == 3) tsign = copysignf(1.f, snr)*copysignf(1.f, snl)*copysignf(1.f, h);
  ssmax = copysignf(ssmax, tsign);
  ssmin = copysignf(ssmin, tsign*copysignf(1.f, f)*copysignf(1.f, h));
}

// ===========================================================================
// K1 (r4): hadamard + register counters (below / bin401 / bin402) + spec fine
// hist. Zero LDS atomics; 6 global atomics per wave at loop exit. NT stores
// for the product so x1/x2 (256 MB = L3 size) stay resident for GEMM passes.
// ===========================================================================
__global__ __launch_bounds__(256) void k_had(const float* __restrict__ x1,
    const float* __restrict__ x2, float* __restrict__ out, float* __restrict__ ws){
  uint32_t* cnt = (uint32_t*)(ws + OFF_CNT);   // [0..2]=x1 below/c401/c402, [3..5]=x2
  uint32_t* s1 = (uint32_t*)(ws + OFF_SPEC);
  uint32_t* s2 = s1 + 2097152;
  const float4* a4 = (const float4*)x1;
  const float4* b4 = (const float4*)x2;
  nfloat4* o4 = (nfloat4*)out;
  int cb1 = 0, c11 = 0, c21 = 0, cb2 = 0, c12 = 0, c22 = 0;
  long long n4 = NTOT/4;
  long long stride = (long long)gridDim.x * 256;
  for (long long i = (long long)blockIdx.x*256 + threadIdx.x; i < n4; i += stride){
    float4 a = a4[i], b = b4[i];
    nfloat4 o;
    o.x = a.x*b.x; o.y = a.y*b.y; o.z = a.z*b.z; o.w = a.w*b.w;
    __builtin_nontemporal_store(o, &o4[i]);
    uint32_t u, dd;
    u = __float_as_uint(a.x)&0x7fffffffu; cb1 += (u < 0x40100000u);
    dd = u - 0x40100000u;
    if (dd < 0x200000u){ atomicAdd(&s1[dd], 1u); if (dd < 0x100000u) c11++; else c21++; }
    u = __float_as_uint(a.y)&0x7fffffffu; cb1 += (u < 0x40100000u);
    dd = u - 0x40100000u;
    if (dd < 0x200000u){ atomicAdd(&s1[dd], 1u); if (dd < 0x100000u) c11++; else c21++; }
    u = __float_as_uint(a.z)&0x7fffffffu; cb1 += (u < 0x40100000u);
    dd = u - 0x40100000u;
    if (dd < 0x200000u){ atomicAdd(&s1[dd], 1u); if (dd < 0x100000u) c11++; else c21++; }
    u = __float_as_uint(a.w)&0x7fffffffu; cb1 += (u < 0x40100000u);
    dd = u - 0x40100000u;
    if (dd < 0x200000u){ atomicAdd(&s1[dd], 1u); if (dd < 0x100000u) c11++; else c21++; }
    u = __float_as_uint(b.x)&0x7fffffffu; cb2 += (u < 0x40100000u);
    dd = u - 0x40100000u;
    if (dd < 0x200000u){ atomicAdd(&s2[dd], 1u); if (dd < 0x100000u) c12++; else c22++; }
    u = __float_as_uint(b.y)&0x7fffffffu; cb2 += (u < 0x40100000u);
    dd = u - 0x40100000u;
    if (dd < 0x200000u){ atomicAdd(&s2[dd], 1u); if (dd < 0x100000u) c12++; else c22++; }
    u = __float_as_uint(b.z)&0x7fffffffu; cb2 += (u < 0x40100000u);
    dd = u - 0x40100000u;
    if (dd < 0x200000u){ atomicAdd(&s2[dd], 1u); if (dd < 0x100000u) c12++; else c22++; }
    u = __float_as_uint(b.w)&0x7fffffffu; cb2 += (u < 0x40100000u);
    dd = u - 0x40100000u;
    if (dd < 0x200000u){ atomicAdd(&s2[dd], 1u); if (dd < 0x100000u) c12++; else c22++; }
  }
  // wave reduce 6 counters, one atomic each per wave
  #pragma unroll
  for (int off = 32; off > 0; off >>= 1){
    cb1 += __shfl_xor(cb1, off, 64);
    c11 += __shfl_xor(c11, off, 64);
    c21 += __shfl_xor(c21, off, 64);
    cb2 += __shfl_xor(cb2, off, 64);
    c12 += __shfl_xor(c12, off, 64);
    c22 += __shfl_xor(c22, off, 64);
  }
  if ((threadIdx.x & 63) == 0){
    atomicAdd(&cnt[0], (uint32_t)cb1);
    atomicAdd(&cnt[1], (uint32_t)c11);
    atomicAdd(&cnt[2], (uint32_t)c21);
    atomicAdd(&cnt[3], (uint32_t)cb2);
    atomicAdd(&cnt[4], (uint32_t)c12);
    atomicAdd(&cnt[5], (uint32_t)c22);
  }
}

// K1b: derive (bin, rank-in-bin, valid) directly from the 3 counters.
__global__ __launch_bounds__(64) void k_select(float* __restrict__ ws){
  if (threadIdx.x != 0) return;
  int ty = blockIdx.x;
  const uint32_t* cnt = (const uint32_t*)(ws + OFF_CNT) + ty*3;
  int* selr = (int*)(ws + OFF_SELR) + ty*4;
  unsigned long long cb = cnt[0], c1 = cnt[1], c2 = cnt[2], K = KSEL;
  if (K >= cb && K < cb + c1){
    selr[0] = 0x401; selr[1] = (int)(K - cb); selr[2] = 1;
  } else if (K >= cb + c1 && K < cb + c1 + c2){
    selr[0] = 0x402; selr[1] = (int)(K - cb - c1); selr[2] = 1;
  } else {
    selr[2] = 0;
  }
}

// Fallback full coarse histogram (r3's hot-path hist, now early-exit).
// Grid MUST be 512 (CHIST partial layout).
__global__ __launch_bounds__(256) void k_hist_fb(const float* __restrict__ x1,
    const float* __restrict__ x2, float* __restrict__ ws){
  const int* selr = (const int*)(ws + OFF_SELR);
  if (selr[2] && selr[4 + 2]) return;
  __shared__ uint32_t lh[2][4][2048];
  for (int i = threadIdx.x; i < 2*4*2048; i += 256) (&lh[0][0][0])[i] = 0u;
  __syncthreads();
  int rep = threadIdx.x & 3;
  const float4* a4 = (const float4*)x1;
  const float4* b4 = (const float4*)x2;
  long long n4 = NTOT/4;
  long long stride = (long long)gridDim.x * 256;
  for (long long i = (long long)blockIdx.x*256 + threadIdx.x; i < n4; i += stride){
    float4 a = a4[i], b = b4[i];
    uint32_t u;
    u = __float_as_uint(a.x)&0x7fffffffu; atomicAdd(&lh[0][rep][u>>20], 1u);
    u = __float_as_uint(a.y)&0x7fffffffu; atomicAdd(&lh[0][rep][u>>20], 1u);
    u = __float_as_uint(a.z)&0x7fffffffu; atomicAdd(&lh[0][rep][u>>20], 1u);
    u = __float_as_uint(a.w)&0x7fffffffu; atomicAdd(&lh[0][rep][u>>20], 1u);
    u = __float_as_uint(b.x)&0x7fffffffu; atomicAdd(&lh[1][rep][u>>20], 1u);
    u = __float_as_uint(b.y)&0x7fffffffu; atomicAdd(&lh[1][rep][u>>20], 1u);
    u = __float_as_uint(b.z)&0x7fffffffu; atomicAdd(&lh[1][rep][u>>20], 1u);
    u = __float_as_uint(b.w)&0x7fffffffu; atomicAdd(&lh[1][rep][u>>20], 1u);
  }
  __syncthreads();
  uint32_t* ch = (uint32_t*)(ws + OFF_CHIST);
  for (int i = threadIdx.x; i < 2048; i += 256){
    uint32_t c0 = lh[0][0][i] + lh[0][1][i] + lh[0][2][i] + lh[0][3][i];
    uint32_t c1 = lh[1][0][i] + lh[1][1][i] + lh[1][2][i] + lh[1][3][i];
    ch[((size_t)blockIdx.x*2 + 0)*2048 + i] = c0;
    ch[((size_t)blockIdx.x*2 + 1)*2048 + i] = c1;
  }
}

__global__ __launch_bounds__(256) void k_coarse_red(float* __restrict__ ws){
  int ty = blockIdx.y;
  if (((const int*)(ws + OFF_SELR))[ty*4 + 2]) return;
  const uint32_t* ch = (const uint32_t*)(ws + OFF_CHIST);
  uint32_t* h = (uint32_t*)(ws + OFF_COARSE) + ty*2048;
  int bin = blockIdx.x*128 + (threadIdx.x & 127);
  int half = threadIdx.x >> 7;
  uint32_t s = 0;
  for (int p = half*256; p < half*256 + 256; p++)
    s += ch[((size_t)p*2 + ty)*2048 + bin];
  __shared__ uint32_t sh[256];
  sh[threadIdx.x] = s;
  __syncthreads();
  if (threadIdx.x < 128) h[bin] = sh[threadIdx.x] + sh[threadIdx.x + 128];
}

__global__ __launch_bounds__(256) void k_coarse_scan(float* __restrict__ ws){
  int ty = blockIdx.x;
  int* selr = (int*)(ws + OFF_SELR) + ty*4;
  if (selr[2]) return;
  const uint32_t* h = (const uint32_t*)(ws + OFF_COARSE) + ty*2048;
  __shared__ unsigned long long ps[256];
  unsigned long long s = 0;
  for (int j = 0; j < 8; j++) s += h[threadIdx.x*8 + j];
  ps[threadIdx.x] = s;
  __syncthreads();
  if (threadIdx.x == 0){
    unsigned long long cum = 0, K = KSEL;
    int g = 0;
    for (; g < 256; g++){ if (cum + ps[g] > K) break; cum += ps[g]; }
    if (g > 255) g = 255;
    int bin = 2047;
    for (int j = 0; j < 8; j++){
      uint32_t c = h[g*8 + j];
      if (cum + c > K){ bin = g*8 + j; break; }
      cum += c;
    }
    selr[0] = bin;
    selr[1] = (int)(K - cum);
    selr[2] = 0;  // fallback path: fine hist must be recomputed into OFF_FB
  }
}

// fallback fine hist — early-exits when speculation valid (the normal case)
__global__ __launch_bounds__(256) void k_fine_fb(const float* __restrict__ x1,
    const float* __restrict__ x2, float* __restrict__ ws){
  int ty = blockIdx.y;
  const int* selr = (const int*)(ws + OFF_SELR) + ty*4;
  if (selr[2]) return;
  const float4* x4 = (const float4*)(ty ? x2 : x1);
  uint32_t bin = (uint32_t)selr[0];
  uint32_t* f = (uint32_t*)(ws + OFF_FB) + ((size_t)ty<<20);
  long long n4 = NTOT/4;
  long long stride = (long long)gridDim.x * 256;
  for (long long i = (long long)blockIdx.x*256 + threadIdx.x; i < n4; i += stride){
    float4 a = x4[i];
    uint32_t u;
    u = __float_as_uint(a.x)&0x7fffffffu; if ((u>>20)==bin) atomicAdd(&f[u&0xFFFFFu],1u);
    u = __float_as_uint(a.y)&0x7fffffffu; if ((u>>20)==bin) atomicAdd(&f[u&0xFFFFFu],1u);
    u = __float_as_uint(a.z)&0x7fffffffu; if ((u>>20)==bin) atomicAdd(&f[u&0xFFFFFu],1u);
    u = __float_as_uint(a.w)&0x7fffffffu; if ((u>>20)==bin) atomicAdd(&f[u&0xFFFFFu],1u);
  }
}

DEV const uint32_t* fine_base(const float* ws, int ty){
  const int* selr = (const int*)(ws + OFF_SELR) + ty*4;
  if (selr[2])
    return (const uint32_t*)(ws + OFF_SPEC) + ((size_t)ty<<21)
           + (((uint32_t)selr[0] - 0x401u) << 20);
  return (const uint32_t*)(ws + OFF_FB) + ((size_t)ty<<20);
}

__global__ __launch_bounds__(256) void k_seg_sum(float* __restrict__ ws){
  int ty = blockIdx.y;
  const uint32_t* f = fine_base(ws, ty);
  uint32_t* segs = (uint32_t*)(ws + OFF_SEGS) + ty*1024;
  uint32_t s = 0;
  int base = blockIdx.x*1024;
  for (int k = 0; k < 4; k++) s += f[base + k*256 + threadIdx.x];
  __shared__ uint32_t sh[256];
  sh[threadIdx.x] = s;
  __syncthreads();
  for (int off = 128; off > 0; off >>= 1){
    if (threadIdx.x < off) sh[threadIdx.x] += sh[threadIdx.x + off];
    __syncthreads();
  }
  if (threadIdx.x == 0) segs[blockIdx.x] = sh[0];
}

__global__ __launch_bounds__(256) void k_fine_scan2(float* __restrict__ ws, float* __restrict__ out){
  int ty = blockIdx.x;
  const uint32_t* f = fine_base(ws, ty);
  const uint32_t* segs = (const uint32_t*)(ws + OFF_SEGS) + ty*1024;
  const int* selr = (const int*)(ws + OFF_SELR) + ty*4;
  __shared__ uint32_t sh[1024];
  __shared__ uint32_t ps[256];
  __shared__ int gsel; __shared__ uint32_t csel;
  int t = threadIdx.x;
  uint32_t K = (uint32_t)selr[1];
  for (int k = 0; k < 4; k++) sh[k*256 + t] = segs[k*256 + t];
  __syncthreads();
  ps[t] = sh[4*t] + sh[4*t+1] + sh[4*t+2] + sh[4*t+3];
  __syncthreads();
  if (t == 0){
    uint32_t cum = 0; int q = 0;
    for (; q < 256; q++){ if (cum + ps[q] > K) break; cum += ps[q]; }
    if (q > 255) q = 255;
    int g = q*4;
    for (int j = 0; j < 4; j++){
      uint32_t c = sh[q*4 + j];
      if (cum + c > K){ g = q*4 + j; break; }
      cum += c;
      if (j == 3) g = q*4 + 3;
    }
    gsel = g; csel = cum;
  }
  __syncthreads();
  int g = gsel;
  for (int k = 0; k < 4; k++) sh[k*256 + t] = f[(size_t)g*1024 + k*256 + t];
  __syncthreads();
  ps[t] = sh[4*t] + sh[4*t+1] + sh[4*t+2] + sh[4*t+3];
  __syncthreads();
  if (t == 0){
    uint32_t cum = csel; int q = 0;
    for (; q < 256; q++){ if (cum + ps[q] > K) break; cum += ps[q]; }
    if (q > 255) q = 255;
    int j = q*4 + 3;
    for (int jj = 0; jj < 4; jj++){
      uint32_t c = sh[q*4 + jj];
      if (cum + c > K){ j = q*4 + jj; break; }
      cum += c;
    }
    uint32_t bits = (((uint32_t)selr[0])<<20) | (uint32_t)((g*1024 + j) & 0xFFFFF);
    float th = __uint_as_float(bits);
    ws[OFF_TSEL + ty] = th;
    out[ty ? OUT_T2 : OUT_T1] = th;
  }
}

__global__ __launch_bounds__(256) void k_omega(uint32_t a0, uint32_t a1,
    uint32_t b0, uint32_t b1, float* __restrict__ ws){
  int ty = blockIdx.y;
  uint32_t k0 = ty ? b0 : a0, k1 = ty ? b1 : a1;
  int i = blockIdx.x*256 + threadIdx.x;
  uint32_t o0, o1;
  d_threefry(k0, k1, 0u, (uint32_t)i, o0, o1);
  uint32_t bits = o0 ^ o1;
  float fr = __uint_as_float((bits >> 9) | 0x3f800000u) - 1.0f;
  const float lo = -0.99999994f;
  float u = fr * 2.0f + lo;
  u = fmaxf(lo, u);
  float v = 1.41421356237f * erfinv_f32(u);
  int row = i >> 4, col = i & 15;
  ws[OFF_OMT + (size_t)ty*65536 + (size_t)col*4096 + row] = v;
}

// K6: Y(8192x16) = residual(x) * W  (W^T 16x4096 in ws)
__global__ __launch_bounds__(256) void k_atype(const float* __restrict__ x1,
    const float* __restrict__ x2, float* __restrict__ ws, size_t wtOff){
  int ty = blockIdx.y;
  const float* x = ty ? x2 : x1;
  const float* wt = ws + wtOff + (size_t)ty*65536;
  float* Y = ws + OFF_BIGY + (size_t)ty*131072;
  float t = ws[OFF_TSEL + ty];
  int wave = threadIdx.x >> 6, lane = threadIdx.x & 63;
  __shared__ __align__(16) float wts[16][256];
  __shared__ float outs[16][16];
  float acc[4][16];
  #pragma unroll
  for (int r = 0; r < 4; r++)
    #pragma unroll
    for (int j = 0; j < 16; j++) acc[r][j] = 0.f;
  int rowbase = blockIdx.x*16 + wave*4;
  for (int c = 0; c < 4096; c += 256){
    __syncthreads();
    for (int idx = threadIdx.x; idx < 16*64; idx += 256){
      int j = idx >> 6, q = idx & 63;
      ((float4*)&wts[j][0])[q] = ((const float4*)(wt + (size_t)j*4096 + c))[q];
    }
    __syncthreads();
    float4 xv[4];
    #pragma unroll
    for (int rr = 0; rr < 4; rr++){
      int row = rowbase + rr;
      float4 a = ((const float4*)(x + (size_t)row*4096 + c))[lane];
      a.x = fabsf(a.x) > t ? 0.f : a.x;
      a.y = fabsf(a.y) > t ? 0.f : a.y;
      a.z = fabsf(a.z) > t ? 0.f : a.z;
      a.w = fabsf(a.w) > t ? 0.f : a.w;
      xv[rr] = a;
    }
    #pragma unroll
    for (int j = 0; j < 16; j++){
      float4 w4 = ((const float4*)&wts[j][0])[lane];
      #pragma unroll
      for (int rr = 0; rr < 4; rr++){
        acc[rr][j] = fmaf(xv[rr].x, w4.x, acc[rr][j]);
        acc[rr][j] = fmaf(xv[rr].y, w4.y, acc[rr][j]);
        acc[rr][j] = fmaf(xv[rr].z, w4.z, acc[rr][j]);
        acc[rr][j] = fmaf(xv[rr].w, w4.w, acc[rr][j]);
      }
    }
  }
  #pragma unroll
  for (int rr = 0; rr < 4; rr++)
    for (int j = 0; j < 16; j++){
      float v = acc[rr][j];
      for (int off = 32; off > 0; off >>= 1) v += __shfl_xor(v, off, 64);
      if (lane == 0) outs[wave*4 + rr][j] = v;
    }
  __syncthreads();
  int r = threadIdx.x >> 4, cc = threadIdx.x & 15;
  Y[(size_t)(blockIdx.x*16 + r)*16 + cc] = outs[r][cc];
}

__global__ __launch_bounds__(256) void k_gramP(float* __restrict__ ws, size_t mOff,
    size_t mStr){
  int ty = blockIdx.y;
  const float* M = ws + mOff + (size_t)ty*mStr;
  float* gp = ws + OFF_GRAMP + (size_t)(ty*64 + blockIdx.x)*256;
  __shared__ __align__(16) float buf[128][16];
  int t = threadIdx.x;
  for (int q = t; q < 512; q += 256)
    ((float4*)&buf[0][0])[q] = ((const float4*)(M + (size_t)blockIdx.x*2048))[q];
  __syncthreads();
  int i = t >> 4, j = t & 15;
  float s = 0.f;
  int rstart = (blockIdx.x == 0) ? 16 : 0;
  for (int r = rstart; r < 128; r++) s += buf[r][i]*buf[r][j];
  gp[t] = s;
}

__global__ __launch_bounds__(256) void k_btype(const float* __restrict__ x1,
    const float* __restrict__ x2, float* __restrict__ ws){
  int ty = blockIdx.y;
  const float* x = ty ? x2 : x1;
  const float* Q = ws + OFF_BIGQ + (size_t)ty*131072;
  float t = ws[OFF_TSEL + ty];
  int cb = blockIdx.x & 15;
  int rc = blockIdx.x >> 4;
  int c = cb*256 + threadIdx.x;
  int r0 = rc*512;
  __shared__ __align__(16) float Qs[64][16];
  float acc[16];
  #pragma unroll
  for (int j = 0; j < 16; j++) acc[j] = 0.f;
  for (int tile = 0; tile < 8; tile++){
    __syncthreads();
    ((float4*)&Qs[0][0])[threadIdx.x] =
        ((const float4*)(Q + (size_t)(r0 + tile*64)*16))[threadIdx.x];
    __syncthreads();
    const float* xp = x + (size_t)(r0 + tile*64)*4096 + c;
    #pragma unroll 4
    for (int rr = 0; rr < 64; rr++){
      float v = xp[(size_t)rr*4096];
      v = fabsf(v) > t ? 0.f : v;
      float4 qa = ((const float4*)&Qs[rr][0])[0];
      float4 qb = ((const float4*)&Qs[rr][0])[1];
      float4 qc = ((const float4*)&Qs[rr][0])[2];
      float4 qd = ((const float4*)&Qs[rr][0])[3];
      acc[ 0] = fmaf(v, qa.x, acc[ 0]);
      acc[ 1] = fmaf(v, qa.y, acc[ 1]);
      acc[ 2] = fmaf(v, qa.z, acc[ 2]);
      acc[ 3] = fmaf(v, qa.w, acc[ 3]);
      acc[ 4] = fmaf(v, qb.x, acc[ 4]);
      acc[ 5] = fmaf(v, qb.y, acc[ 5]);
      acc[ 6] = fmaf(v, qb.z, acc[ 6]);
      acc[ 7] = fmaf(v, qb.w, acc[ 7]);
      acc[ 8] = fmaf(v, qc.x, acc[ 8]);
      acc[ 9] = fmaf(v, qc.y, acc[ 9]);
      acc[10] = fmaf(v, qc.z, acc[10]);
      acc[11] = fmaf(v, qc.w, acc[11]);
      acc[12] = fmaf(v, qd.x, acc[12]);
      acc[13] = fmaf(v, qd.y, acc[13]);
      acc[14] = fmaf(v, qd.z, acc[14]);
      acc[15] = fmaf(v, qd.w, acc[15]);
    }
  }
  float* BP = ws + OFF_BPART + (((size_t)(ty*16 + rc))<<16) + (size_t)c*16;
  #pragma unroll
  for (int q = 0; q < 4; q++){
    float4 o; o.x = acc[q*4]; o.y = acc[q*4+1]; o.z = acc[q*4+2]; o.w = acc[q*4+3];
    ((float4*)BP)[q] = o;
  }
}

__global__ __launch_bounds__(256) void k_bredgram(float* __restrict__ ws){
  int ty = blockIdx.y;
  const float* BP = ws + OFF_BPART + (((size_t)ty*16)<<16);
  float* T = ws + OFF_TMAT + (size_t)ty*65536;
  float* gp = ws + OFF_GRAMP + (size_t)(ty*64 + blockIdx.x)*256;
  __shared__ float sh[64][16];
  int t = threadIdx.x;
  for (int k = 0; k < 4; k++){
    int e = blockIdx.x*1024 + k*256 + t;
    float s = 0.f;
    #pragma unroll
    for (int rc = 0; rc < 16; rc++) s += BP[((size_t)rc<<16) + e];
    T[e] = s;
    int le = k*256 + t;
    sh[le >> 4][le & 15] = s;
  }
  __syncthreads();
  int i = t >> 4, j = t & 15;
  float s = 0.f;
  int rstart = (blockIdx.x == 0) ? 16 : 0;
  for (int r = rstart; r < 64; r++) s += sh[r][i]*sh[r][j];
  gp[t] = s;
}

// K9: register-resident tiny QR: gram-sum, chol (LDS), geqrf+org2r (regs),
//     back-solve. Lane j<16 holds column j.
__global__ __launch_bounds__(64) void k_tiny(float* __restrict__ ws, size_t mOff,
    size_t mStr){
  int ty = blockIdx.x;
  const float* Mp = ws + mOff + (size_t)ty*mStr;
  float* sOut = ws + OFF_S + ty*256;
  float* qtOut = ws + OFF_QTOP + ty*256;
  float* rgOut = ws + OFF_RG + ty*256;
  __shared__ float G[16][16];
  __shared__ float Cld[32][16];
  __shared__ float bc[4];
  __shared__ float tau[16];
  int l = threadIdx.x;
  int j = l & 15;
  for (int e = l; e < 256; e += 64){
    const float* gp = ws + OFF_GRAMP + (size_t)ty*16384 + e;
    float s = 0.f;
    for (int p = 0; p < 64; p++) s += gp[(size_t)p*256];
    G[e>>4][e&15] = s;
  }
  for (int idx = l; idx < 256; idx += 64)
    Cld[idx>>4][idx&15] = Mp[idx];
  __syncthreads();
  // cholesky (upper) in place — identical op order to rounds 1-3
  for (int k = 0; k < 16; k++){
    float dk = sqrtf(G[k][k]);
    if (l == k) G[k][k] = dk;
    else if (l > k && l < 16) G[k][l] = G[k][l] / dk;
    __syncthreads();
    if (l > k && l < 16)
      for (int jj = l; jj < 16; jj++) G[l][jj] -= G[k][l]*G[k][jj];
    __syncthreads();
  }
  // build column registers: C = [M_top ; R_B]
  float Cc[32];
  #pragma unroll
  for (int r = 0; r < 32; r++){
    if (r < 16) Cc[r] = Cld[r][j];
    else Cc[r] = (j >= r - 16) ? G[r-16][j] : 0.f;
  }
  // geqrf (same arithmetic order as LDS version)
  #pragma unroll
  for (int i = 0; i < 16; i++){
    if (l == i){
      float alpha = Cc[i];
      float ssum = 0.f;
      #pragma unroll
      for (int r = i+1; r < 32; r++) ssum += Cc[r]*Cc[r];
      float xn = sqrtf(ssum);
      float beta, tv, sc;
      if (xn == 0.f){ tv = 0.f; beta = alpha; sc = 1.f; }
      else {
        beta = -copysignf(lapy2f(alpha, xn), alpha);
        tv = (beta - alpha)/beta;
        sc = 1.f/(alpha - beta);
        #pragma unroll
        for (int r = i+1; r < 32; r++) Cc[r] *= sc;
      }
      Cc[i] = beta;
      bc[0] = beta; bc[1] = tv;
      tau[i] = tv;
      #pragma unroll
      for (int r = i; r < 32; r++) Cld[r][i] = Cc[r];
    }
    __syncthreads();
    float tv = bc[1];
    if (tv != 0.f && l < 16 && j > i){
      float w = Cc[i];
      #pragma unroll
      for (int r = i+1; r < 32; r++) w += Cld[r][i]*Cc[r];
      w *= tv;
      Cc[i] -= w;
      #pragma unroll
      for (int r = i+1; r < 32; r++) Cc[r] -= w*Cld[r][i];
    }
    __syncthreads();
  }
  // org2r (no barriers needed: Cld/tau now read-only)
  float Qc[32];
  #pragma unroll
  for (int r = 0; r < 32; r++) Qc[r] = 0.f;
  #pragma unroll
  for (int i = 15; i >= 0; i--){
    float tv = tau[i];
    if (i < 15 && l < 16 && j > i){
      float w = Qc[i];
      #pragma unroll
      for (int r = i+1; r < 32; r++) w += Cld[r][i]*Qc[r];
      w *= tv;
      Qc[i] -= w;
      #pragma unroll
      for (int r = i+1; r < 32; r++) Qc[r] -= w*Cld[r][i];
    }
    if (l == i){
      #pragma unroll
      for (int r = 0; r < 32; r++){
        if (r < i) Qc[r] = 0.f;
        else if (r == i) Qc[r] = 1.f - tv;
        else Qc[r] = -tv * Cld[r][i];
      }
    }
  }
  // back-solve S = R_B^{-1} * Q_bot
  float Sc[16];
  if (l < 16){
    #pragma unroll
    for (int i2 = 15; i2 >= 0; i2--){
      float v = Qc[16 + i2];
      #pragma unroll
      for (int k2 = i2+1; k2 < 16; k2++) v -= G[i2][k2]*Sc[k2];
      Sc[i2] = v / G[i2][i2];
    }
    #pragma unroll
    for (int r = 0; r < 16; r++){
      rgOut[r*16 + j] = (j >= r) ? Cc[r] : 0.f;
      sOut[r*16 + j] = Sc[r];
      qtOut[r*16 + j] = Qc[r];
    }
  }
}

__global__ __launch_bounds__(256) void k_applyq(float* __restrict__ ws, size_t mOff,
    size_t mStr, size_t oOff, size_t oStr, int nrows, int wN, int wT){
  int ty = blockIdx.y;
  const float* Mp = ws + mOff + (size_t)ty*mStr;
  const float* sP = ws + OFF_S + ty*256;
  const float* qtP = ws + OFF_QTOP + ty*256;
  float* oP = ws + oOff + (size_t)ty*oStr;
  __shared__ float Ss[16][16], Qt[16][16];
  int t = threadIdx.x;
  Ss[t>>4][t&15] = sP[t];
  Qt[t>>4][t&15] = qtP[t];
  __syncthreads();
  int row = blockIdx.x*256 + t;
  if (row >= nrows) return;
  float o[16];
  if (row < 16){
    #pragma unroll
    for (int j = 0; j < 16; j++) o[j] = Qt[row][j];
  } else {
    float mv[16];
    #pragma unroll
    for (int q = 0; q < 4; q++){
      float4 v = ((const float4*)(Mp + (size_t)row*16))[q];
      mv[q*4] = v.x; mv[q*4+1] = v.y; mv[q*4+2] = v.z; mv[q*4+3] = v.w;
    }
    #pragma unroll
    for (int j = 0; j < 16; j++){
      float sacc = 0.f;
      #pragma unroll
      for (int i = 0; i < 16; i++) sacc = fmaf(mv[i], Ss[i][j], sacc);
      o[j] = sacc;
    }
  }
  if (wN){
    #pragma unroll
    for (int q = 0; q < 4; q++){
      float4 v; v.x = o[q*4]; v.y = o[q*4+1]; v.z = o[q*4+2]; v.w = o[q*4+3];
      ((float4*)(oP + (size_t)row*16))[q] = v;
    }
  }
  if (wT){
    #pragma unroll
    for (int j = 0; j < 16; j++) oP[(size_t)j*4096 + row] = o[j];
  }
}

// ===========================================================================
// K11: gesdd tail. gebd2 (LDS) -> bdsqr (REGISTERS, lane=VT column) -> ormbr.
// ===========================================================================
__global__ __launch_bounds__(64) void k_chain(float* __restrict__ ws){
  int ty = blockIdx.x;
  const float* rg = ws + OFF_RG + ty*256;
  float* vtlOut = ws + OFF_VTL + ty*256;
  const int n = 16;
  __shared__ float A[16][16];
  __shared__ float VTm[16][16];
  __shared__ float d_[16], e_[16], tauq[16], taup[16];
  int l = threadIdx.x;
  for (int idx = l; idx < 256; idx += 64){
    int r = idx >> 4, c = idx & 15;
    A[r][c] = (r >= c) ? rg[c*16 + r] : 0.f;   // L = Rg^T
  }
  __syncthreads();
  // ---- gebd2 (unchanged) ----
  for (int i = 0; i < n; i++){
    {
      float alpha = A[i][i];
      float ssum = 0.f;
      for (int r = i+1; r < n; r++) ssum += A[r][i]*A[r][i];
      float xn = sqrtf(ssum);
      float beta, tv;
      if (n - i <= 1 || xn == 0.f){ tv = 0.f; beta = alpha; }
      else {
        beta = -copysignf(lapy2f(alpha, xn), alpha);
        tv = (beta - alpha)/beta;
        float sc = 1.f/(alpha - beta);
        if (l > i && l < n) A[l][i] *= sc;
      }
      if (l == 0){ d_[i] = beta; tauq[i] = tv; }
      __syncthreads();
      if (tv != 0.f && l > i && l < n){
        int jj = l;
        float w = A[i][jj];
        for (int r = i+1; r < n; r++) w += A[r][i]*A[r][jj];
        w *= tv;
        A[i][jj] -= w;
        for (int r = i+1; r < n; r++) A[r][jj] -= w*A[r][i];
      }
      __syncthreads();
    }
    if (i < n-1){
      float alpha = A[i][i+1];
      float ssum = 0.f;
      for (int c = i+2; c < n; c++) ssum += A[i][c]*A[i][c];
      float xn = sqrtf(ssum);
      float beta, tp;
      if (n - i - 1 <= 1 || xn == 0.f){ tp = 0.f; beta = alpha; }
      else {
        beta = -copysignf(lapy2f(alpha, xn), alpha);
        tp = (beta - alpha)/beta;
        float sc = 1.f/(alpha - beta);
        if (l >= i+2 && l < n) A[i][l] *= sc;
      }
      if (l == 0){ e_[i] = beta; taup[i] = tp; }
      __syncthreads();
      if (tp != 0.f && l > i && l < n){
        int r = l;
        float w = A[r][i+1];
        for (int c = i+2; c < n; c++) w += A[i][c]*A[r][c];
        w *= tp;
        A[r][i+1] -= w;
        for (int c = i+2; c < n; c++) A[r][c] -= w*A[i][c];
      }
      __syncthreads();
    } else {
      if (l == 0) taup[i] = 0.f;
      __syncthreads();
    }
  }
  // ---- bdsqr: all state in registers, wave-uniform control flow ----
  float D[16], E[16], vt[16];
  #pragma unroll
  for (int k = 0; k < 16; k++){
    D[k] = d_[k];
    E[k] = (k < 15) ? e_[k] : 0.f;
    vt[k] = (k == l) ? 1.f : 0.f;
  }
  auto getD = [&](int i)->float{ float r = D[0];
    #pragma unroll
    for (int k = 1; k < 16; k++) if (i == k) r = D[k];
    return r; };
  auto setD = [&](int i, float v){
    #pragma unroll
    for (int k = 0; k < 16; k++) if (i == k) D[k] = v; };
  auto getE = [&](int i)->float{ float r = E[0];
    #pragma unroll
    for (int k = 1; k < 16; k++) if (i == k) r = E[k];
    return r; };
  auto setE = [&](int i, float v){
    #pragma unroll
    for (int k = 0; k < 16; k++) if (i == k) E[k] = v; };
  auto getVt = [&](int i)->float{ float r = vt[0];
    #pragma unroll
    for (int k = 1; k < 16; k++) if (i == k) r = vt[k];
    return r; };
  auto setVt = [&](int i, float v){
    #pragma unroll
    for (int k = 0; k < 16; k++) if (i == k) vt[k] = v; };

  const float eps = 5.9604645e-08f;
  const float unfl = 1.17549435e-38f;
  const float tol = 10.f*eps;
  float sminoa = fabsf(D[0]);
  if (sminoa != 0.f){
    float mu = sminoa;
    #pragma unroll
    for (int i = 1; i < 16; i++){
      mu = fabsf(D[i])*(mu/(mu + fabsf(E[i-1])));
      sminoa = fminf(sminoa, mu);
    }
  }
  sminoa = sminoa / sqrtf((float)n);
  float thresh = fmaxf(tol*sminoa, (float)(6*n*n)*unfl);
  int maxit = 6*n*n;
  int iter = 0, oldll = -1, oldm = -1, mm = n, idir = 0;
  while (true){
    if (mm <= 1) break;
    if (iter > maxit) break;
    float smaxw = fabsf(getD(mm-1));
    int llv = 1; bool split = false;
    {
      bool done = false;
      #pragma unroll
      for (int c = 14; c >= 0; c--){
        if (c <= mm-2 && !done){
          if (fabsf(E[c]) <= thresh){ split = true; llv = c+1; done = true; }
          else smaxw = fmaxf(smaxw, fmaxf(fabsf(D[c]), fabsf(E[c])));
        }
      }
    }
    if (split){
      setE(llv-1, 0.f);
      if (llv == mm-1){ mm = mm - 1; continue; }
      llv = llv + 1;
    }
    if (llv == mm-1){
      float sigmn, sigmx, sinr, cosr, sinl, cosl;
      slasv2_(getD(mm-2), getE(mm-2), getD(mm-1), sigmn, sigmx, sinr, cosr, sinl, cosl);
      setD(mm-2, sigmx); setE(mm-2, 0.f); setD(mm-1, sigmn);
      float t1 = getVt(mm-2), t2 = getVt(mm-1);
      setVt(mm-2, cosr*t1 + sinr*t2);
      setVt(mm-1, cosr*t2 - sinr*t1);
      mm -= 2;
      continue;
    }
    if (llv > oldm || mm < oldll)
      idir = (fabsf(getD(llv-1)) >= fabsf(getD(mm-1))) ? 1 : 2;
    bool deflated = false;
    float sminl = 0.f;
    if (idir == 1){
      if (fabsf(getE(mm-2)) <= tol*fabsf(getD(mm-1))){ setE(mm-2, 0.f); continue; }
      float mu = fabsf(getD(llv-1)); sminl = mu;
      #pragma unroll
      for (int c = 0; c < 15; c++){
        if (c >= llv-1 && c <= mm-2 && !deflated){
          if (fabsf(E[c]) <= tol*mu){ E[c] = 0.f; deflated = true; }
          else {
            mu = fabsf(D[c+1])*(mu/(mu + fabsf(E[c])));
            sminl = fminf(sminl, mu);
          }
        }
      }
    } else {
      if (fabsf(getE(llv-1)) <= tol*fabsf(getD(llv-1))){ setE(llv-1, 0.f); continue; }
      float mu = fabsf(getD(mm-1)); sminl = mu;
      #pragma unroll
      for (int c = 14; c >= 0; c--){
        if (c >= llv-1 && c <= mm-2 && !deflated){
          if (fabsf(E[c]) <= tol*mu){ E[c] = 0.f; deflated = true; }
          else {
            mu = fabsf(D[c])*(mu/(mu + fabsf(E[c])));
            sminl = fminf(sminl, mu);
          }
        }
      }
    }
    if (deflated) continue;
    oldll = llv; oldm = mm;
    float shift = 0.f, rdum;
    if (!((float)n*tol*(sminl/smaxw) <= fmaxf(eps, 0.01f*tol))){
      float sll;
      if (idir == 1){ sll = fabsf(getD(llv-1)); slas2_(getD(mm-2), getE(mm-2), getD(mm-1), shift, rdum); }
      else          { sll = fabsf(getD(mm-1));  slas2_(getD(llv-1), getE(llv-1), getD(llv), shift, rdum); }
      if (sll > 0.f){ float q = shift/sll; if (q*q < eps) shift = 0.f; }
    }
    iter += mm - llv;
    if (shift == 0.f){
      if (idir == 1){
        float cs = 1.f, oldcs = 1.f, sn = 0.f, oldsn = 0.f, rr, dnew;
        #pragma unroll
        for (int i0 = 0; i0 < 15; i0++){
          if (i0 >= llv-1 && i0 <= mm-2){
            slartg_(D[i0]*cs, E[i0], cs, sn, rr);
            if (i0 > llv-1) E[i0-1 < 0 ? 0 : i0-1] = oldsn*rr;
            slartg_(oldcs*rr, D[i0+1]*sn, oldcs, oldsn, dnew);
            D[i0] = dnew;
            if (cs != 1.f || sn != 0.f){
              float t1 = vt[i0], t2 = vt[i0+1];
              vt[i0+1] = cs*t2 - sn*t1;
              vt[i0]   = sn*t2 + cs*t1;
            }
          }
        }
        float h = getD(mm-1)*cs;
        setD(mm-1, h*oldcs);
        float hv = h*oldsn;
        setE(mm-2, (fabsf(hv) <= thresh) ? 0.f : hv);
      } else {
        float cs = 1.f, oldcs = 1.f, sn = 0.f, oldsn = 0.f, rr, dnew;
        #pragma unroll
        for (int i0 = 15; i0 >= 1; i0--){
          if (i0 >= llv && i0 <= mm-1){
            slartg_(D[i0]*cs, E[i0-1], cs, sn, rr);
            if (i0 < mm-1) E[i0] = oldsn*rr;
            slartg_(oldcs*rr, D[i0-1]*sn, oldcs, oldsn, dnew);
            D[i0] = dnew;
            float cR = oldcs, sR = -oldsn;
            if (cR != 1.f || sR != 0.f){
              float t1 = vt[i0-1], t2 = vt[i0];
              vt[i0]   = cR*t2 - sR*t1;
              vt[i0-1] = sR*t2 + cR*t1;
            }
          }
        }
        float h = getD(llv-1)*cs;
        setD(llv-1, h*oldcs);
        float hv = h*oldsn;
        setE(llv-1, (fabsf(hv) <= thresh) ? 0.f : hv);
      }
    } else {
      if (idir == 1){
        float dl = getD(llv-1);
        float ff = (fabsf(dl) - shift)*(copysignf(1.f, dl) + shift/dl);
        float gg = getE(llv-1);
        float cosr, sinr, cosl, sinl, rr;
        #pragma unroll
        for (int i0 = 0; i0 < 15; i0++){
          if (i0 >= llv-1 && i0 <= mm-2){
            slartg_(ff, gg, cosr, sinr, rr);
            if (i0 > llv-1) E[i0-1 < 0 ? 0 : i0-1] = rr;
            float di = D[i0], ei = E[i0];
            ff = cosr*di + sinr*ei;
            E[i0] = cosr*ei - sinr*di;
            gg = sinr*D[i0+1];
            D[i0+1] = cosr*D[i0+1];
            slartg_(ff, gg, cosl, sinl, rr);
            D[i0] = rr;
            float ei2 = E[i0], dip = D[i0+1];
            ff = cosl*ei2 + sinl*dip;
            D[i0+1] = cosl*dip - sinl*ei2;
            if (i0 < mm-2){
              gg = sinl*E[i0+1];
              E[i0+1] = cosl*E[i0+1];
            }
            if (cosr != 1.f || sinr != 0.f){
              float t1 = vt[i0], t2 = vt[i0+1];
              vt[i0+1] = cosr*t2 - sinr*t1;
              vt[i0]   = sinr*t2 + cosr*t1;
            }
          }
        }
        setE(mm-2, (fabsf(ff) <= thresh) ? 0.f : ff);
      } else {
        float dm = getD(mm-1);
        float ff = (fabsf(dm) - shift)*(copysignf(1.f, dm) + shift/dm);
        float gg = getE(mm-2);
        float cosr, sinr, cosl, sinl, rr;
        #pragma unroll
        for (int i0 = 15; i0 >= 1; i0--){
          if (i0 >= llv && i0 <= mm-1){
            slartg_(ff, gg, cosr, sinr, rr);
            if (i0 < mm-1) E[i0] = rr;
            float di = D[i0], eim = E[i0-1];
            ff = cosr*di + sinr*eim;
            E[i0-1] = cosr*eim - sinr*di;
            gg = sinr*D[i0-1];
            D[i0-1] = cosr*D[i0-1];
            slartg_(ff, gg, cosl, sinl, rr);
            D[i0] = rr;
            float eim2 = E[i0-1], dim = D[i0-1];
            ff = cosl*eim2 + sinl*dim;
            D[i0-1] = cosl*dim - sinl*eim2;
            if (i0 > llv){
              gg = sinl*E[i0-2 < 0 ? 0 : i0-2];
              E[i0-2 < 0 ? 0 : i0-2] = cosl*E[i0-2 < 0 ? 0 : i0-2];
            }
            float cR = cosr, sR = -sinr;
            if (cR != 1.f || sR != 0.f){
              float t1 = vt[i0-1], t2 = vt[i0];
              vt[i0]   = cR*t2 - sR*t1;
              vt[i0-1] = sR*t2 + cR*t1;
            }
          }
        }
        setE(llv-1, (fabsf(ff) <= thresh) ? 0.f : ff);
      }
    }
  }
  // make positive
  #pragma unroll
  for (int k = 0; k < 16; k++){
    if (D[k] < 0.f){ D[k] = -D[k]; vt[k] = -vt[k]; }
  }
  // sort decreasing (selection, same tie-breaks as LAPACK slasrt-path in bdsqr)
  #pragma unroll
  for (int i = 1; i <= 15; i++){
    int isub = 1; float smn = D[0];
    #pragma unroll
    for (int jj = 2; jj <= 16; jj++){
      if (jj <= 16 + 1 - i){
        if (D[jj-1] <= smn){ isub = jj; smn = D[jj-1]; }
      }
    }
    if (isub != 16 + 1 - i){
      setD(isub - 1, D[16 - i]);
      D[16 - i] = smn;
      float tmp = getVt(isub - 1);
      setVt(isub - 1, vt[16 - i]);
      vt[16 - i] = tmp;
    }
  }
  // dump VT to LDS for row-wise ormbr
  if (l < 16){
    #pragma unroll
    for (int r = 0; r < 16; r++) VTm[r][l] = vt[r];
  }
  __syncthreads();
  // ormbr('P','R','T'): VT := VT * G(n-1)...G(1)
  for (int i = n-2; i >= 0; i--){
    float tp = taup[i];
    if (tp != 0.f && l < 16){
      int r = l;
      float w = VTm[r][i+1];
      for (int c = i+2; c < n; c++) w += VTm[r][c]*A[i][c];
      w *= tp;
      VTm[r][i+1] -= w;
      for (int c = i+2; c < n; c++) VTm[r][c] -= w*A[i][c];
    }
    __syncthreads();
  }
  for (int idx = l; idx < 256; idx += 64) vtlOut[idx] = VTm[idx>>4][idx&15];
}

// K12: R = Qqr * VT_L^T ; Rinv = R^T
__global__ __launch_bounds__(256) void k_rout(float* __restrict__ ws, float* __restrict__ out){
  int ty = blockIdx.y;
  const float* Qq = ws + OFF_QQR + (size_t)ty*65536;
  const float* vtl = ws + OFF_VTL + ty*256;
  long long Roff  = ty ? OUT_R2  : OUT_R1;
  long long RIoff = ty ? OUT_RI2 : OUT_RI1;
  __shared__ float V[16][16];
  int t = threadIdx.x;
  V[t>>4][t&15] = vtl[t];
  __syncthreads();
  int row = blockIdx.x*256 + t;
  float mv[16];
  #pragma unroll
  for (int q = 0; q < 4; q++){
    float4 v = ((const float4*)(Qq + (size_t)row*16))[q];
    mv[q*4] = v.x; mv[q*4+1] = v.y; mv[q*4+2] = v.z; mv[q*4+3] = v.w;
  }
  #pragma unroll
  for (int j = 0; j < 16; j++){
    float s = 0.f;
    #pragma unroll
    for (int i = 0; i < 16; i++) s = fmaf(mv[i], V[j][i], s);
    out[Roff + (long long)row*16 + j] = s;
    out[RIoff + (long long)j*4096 + row] = s;
  }
}

// ===========================================================================
extern "C" void kernel_launch(void* const* d_in, const int* in_sizes, int n_in,
                              void* d_out, int out_size, void* d_ws, size_t ws_size,
                              hipStream_t stream){
  const float* x1 = (const float*)d_in[0];
  const float* x2 = (const float*)d_in[1];
  float* out = (float*)d_out;
  float* ws = (float*)d_ws;
  (void)in_sizes; (void)n_in; (void)out_size; (void)ws_size;

  hipMemsetAsync(d_ws, 0, ZERO_FLOATS*sizeof(float), stream);

  k_had<<<dim3(1024), 256, 0, stream>>>(x1, x2, out, ws);
  k_select<<<dim3(2), 64, 0, stream>>>(ws);
  k_hist_fb<<<dim3(512), 256, 0, stream>>>(x1, x2, ws);      // early-exit (fallback)
  k_coarse_red<<<dim3(16, 2), 256, 0, stream>>>(ws);          // early-exit (fallback)
  k_coarse_scan<<<dim3(2), 256, 0, stream>>>(ws);             // early-exit (fallback)
  k_fine_fb<<<dim3(1024, 2), 256, 0, stream>>>(x1, x2, ws);   // early-exit (fallback)
  k_seg_sum<<<dim3(1024, 2), 256, 0, stream>>>(ws);
  k_fine_scan2<<<dim3(2), 256, 0, stream>>>(ws, out);

  uint32_t a0, a1, b0, b1;
  h_threefry(0u, 42u, 0u, 0u, a0, a1);
  h_threefry(0u, 42u, 0u, 1u, b0, b1);
  k_omega<<<dim3(256, 2), 256, 0, stream>>>(a0, a1, b0, b1, ws);

  // QR1
  k_atype<<<dim3(512, 2), 256, 0, stream>>>(x1, x2, ws, OFF_OMT);
  k_gramP<<<dim3(64, 2), 256, 0, stream>>>(ws, OFF_BIGY, 131072);
  k_tiny<<<dim3(2), 64, 0, stream>>>(ws, OFF_BIGY, 131072);
  k_applyq<<<dim3(32, 2), 256, 0, stream>>>(ws, OFF_BIGY, 131072, OFF_BIGQ, 131072, 8192, 1, 0);
  // QR2
  k_btype<<<dim3(256, 2), 256, 0, stream>>>(x1, x2, ws);
  k_bredgram<<<dim3(64, 2), 256, 0, stream>>>(ws);
  k_tiny<<<dim3(2), 64, 0, stream>>>(ws, OFF_TMAT, 65536);
  k_applyq<<<dim3(16, 2), 256, 0, stream>>>(ws, OFF_TMAT, 65536, OFF_ZT, 65536, 4096, 0, 1);
  // QR3
  k_atype<<<dim3(512, 2), 256, 0, stream>>>(x1, x2, ws, OFF_ZT);
  k_gramP<<<dim3(64, 2), 256, 0, stream>>>(ws, OFF_BIGY, 131072);
  k_tiny<<<dim3(2), 64, 0, stream>>>(ws, OFF_BIGY, 131072);
  k_applyq<<<dim3(32, 2), 256, 0, stream>>>(ws, OFF_BIGY, 131072, OFF_BIGQ, 131072, 8192, 1, 0);
  // QR4
  k_btype<<<dim3(256, 2), 256, 0, stream>>>(x1, x2, ws);
  k_bredgram<<<dim3(64, 2), 256, 0, stream>>>(ws);
  k_tiny<<<dim3(2), 64, 0, stream>>>(ws, OFF_TMAT, 65536);
  k_applyq<<<dim3(16, 2), 256, 0, stream>>>(ws, OFF_TMAT, 65536, OFF_ZT, 65536, 4096, 0, 1);
  // QR5
  k_atype<<<dim3(512, 2), 256, 0, stream>>>(x1, x2, ws, OFF_ZT);
  k_gramP<<<dim3(64, 2), 256, 0, stream>>>(ws, OFF_BIGY, 131072);
  k_tiny<<<dim3(2), 64, 0, stream>>>(ws, OFF_BIGY, 131072);
  k_applyq<<<dim3(32, 2), 256, 0, stream>>>(ws, OFF_BIGY, 131072, OFF_BIGQ, 131072, 8192, 1, 0);
  // QR6
  k_btype<<<dim3(256, 2), 256, 0, stream>>>(x1, x2, ws);
  k_bredgram<<<dim3(64, 2), 256, 0, stream>>>(ws);
  k_tiny<<<dim3(2), 64, 0, stream>>>(ws, OFF_TMAT, 65536);
  k_applyq<<<dim3(16, 2), 256, 0, stream>>>(ws, OFF_TMAT, 65536, OFF_QQR, 65536, 4096, 1, 0);

  k_chain<<<dim3(2), 64, 0, stream>>>(ws);
  k_rout<<<dim3(16, 2), 256, 0, stream>>>(ws, out);
}

// Round 2
// 1705.489 us; speedup vs baseline: 1.0870x; 1.0870x over previous
//
#include <hip/hip_runtime.h>
#include <cstdint>
#include <cstddef>

// ============================================================================
// EfficientMemoryHadamard — round 5.
//  R4 post-mortem: k_had was bound by ~2.7M device-scope global atomics for the
//  speculative fine hist (2.9 atomics/cycle == measured 382us wall).
//  R5: two-level window select. k_had builds a 2048-bin LDS window hist
//  (dd>>10) + per-block partial flush (plain stores) + register below-window
//  counters. k_red/k_wselect reduce+scan. k_fine re-streams x once, histogram
//  only the selected 1024-value sub-bin (~650 hits/tensor) into LDS, ~650
//  global atomics total. Exact same selection semantics (order stat KSEL).
// Verified assumption stack (rounds 1-4 PASSED, absmax 0.1245):
//  A1: jax threefry_partitionable; A2: quantile = order stat 33218888;
//  A3: gesdd tail gelqf->gebd2->bdsqr->ormbr; A4: LAPACK>=3.10 slartg.
// ============================================================================

#define DEV __device__ __forceinline__

typedef float nfloat4 __attribute__((ext_vector_type(4)));

constexpr long long NTOT = 33554432LL;
constexpr unsigned long long KSEL = 33218888ULL;
constexpr uint32_t WLO = 0x40100000u;   // |x| = 2.25; window [2.25, 2.75)

constexpr long long OUT_T1  = 33554432LL;
constexpr long long OUT_R1  = 33554433LL;
constexpr long long OUT_RI1 = 33619969LL;
constexpr long long OUT_T2  = 33685505LL;
constexpr long long OUT_R2  = 33685506LL;
constexpr long long OUT_RI2 = 33751042LL;

// ---- workspace layout (float units) ----
constexpr size_t OFF_WPART  = 0;         // 1024 blocks x 4096 u32 partials = 16MB
constexpr size_t OFF_BPART  = 0;         // alias: 2*16*65536 floats (after quantile)
constexpr size_t OFF_FB     = 4194304;   // 2 x 1M u32 fallback fine hist (zeroed)
constexpr size_t OFF_CNT    = 6291456;   // 2 u32 below-window counters (zeroed)
constexpr size_t OFF_GF     = 6291472;   // 2*1024 u32 fine window hist (zeroed)
constexpr size_t ZERO_BASE  = OFF_FB;    // memset [OFF_FB, OFF_GF+2048)
constexpr size_t ZERO_FLOATS= 2099216;
constexpr size_t OFF_CHIST  = 6291456;   // fallback alias: 512*2*2048 u32 partials
constexpr size_t OFF_COARSE = 8388608;   // 2*2048 u32 (window hist, then fb coarse)
constexpr size_t OFF_SEGS   = 8392704;   // 2*1024 u32
constexpr size_t OFF_SELR   = 8394752;   // 2*4 ints (bin, rank, valid)
constexpr size_t OFF_TSEL   = 8394768;   // 2 floats (+pad)
constexpr size_t OFF_OMT    = 8394784;   // 2*65536
constexpr size_t OFF_BIGY   = 8525856;   // 2*131072
constexpr size_t OFF_BIGQ   = 8788000;   // 2*131072
constexpr size_t OFF_ZT     = 9050144;   // 2*65536
constexpr size_t OFF_QQR    = 9181216;   // 2*65536
constexpr size_t OFF_TMAT   = 9312288;   // 2*65536
constexpr size_t OFF_GRAMP  = 9443360;   // 2*64*256
constexpr size_t OFF_S      = 9476128;   // 2*256
constexpr size_t OFF_QTOP   = 9476640;   // 2*256
constexpr size_t OFF_RG     = 9477152;   // 2*256
constexpr size_t OFF_VTL    = 9477664;   // 2*256
// total 9478176 floats ~= 37.9 MB (unchanged)

// ---------------------------------------------------------------------------
#define TFR(a,b,r) { a += b; b = (b << r) | (b >> (32 - r)); b ^= a; }

DEV void d_threefry(uint32_t k0, uint32_t k1, uint32_t x0, uint32_t x1,
                    uint32_t& o0, uint32_t& o1){
  uint32_t ks2 = k0 ^ k1 ^ 0x1BD11BDAu;
  x0 += k0; x1 += k1;
  TFR(x0,x1,13) TFR(x0,x1,15) TFR(x0,x1,26) TFR(x0,x1,6)
  x0 += k1; x1 += ks2 + 1u;
  TFR(x0,x1,17) TFR(x0,x1,29) TFR(x0,x1,16) TFR(x0,x1,24)
  x0 += ks2; x1 += k0 + 2u;
  TFR(x0,x1,13) TFR(x0,x1,15) TFR(x0,x1,26) TFR(x0,x1,6)
  x0 += k0; x1 += k1 + 3u;
  TFR(x0,x1,17) TFR(x0,x1,29) TFR(x0,x1,16) TFR(x0,x1,24)
  x0 += k1; x1 += ks2 + 4u;
  TFR(x0,x1,13) TFR(x0,x1,15) TFR(x0,x1,26) TFR(x0,x1,6)
  x0 += ks2; x1 += k0 + 5u;
  o0 = x0; o1 = x1;
}

static void h_threefry(uint32_t k0, uint32_t k1, uint32_t x0, uint32_t x1,
                       uint32_t& o0, uint32_t& o1){
  uint32_t ks2 = k0 ^ k1 ^ 0x1BD11BDAu;
  x0 += k0; x1 += k1;
  TFR(x0,x1,13) TFR(x0,x1,15) TFR(x0,x1,26) TFR(x0,x1,6)
  x0 += k1; x1 += ks2 + 1u;
  TFR(x0,x1,17) TFR(x0,x1,29) TFR(x0,x1,16) TFR(x0,x1,24)
  x0 += ks2; x1 += k0 + 2u;
  TFR(x0,x1,13) TFR(x0,x1,15) TFR(x0,x1,26) TFR(x0,x1,6)
  x0 += k0; x1 += k1 + 3u;
  TFR(x0,x1,17) TFR(x0,x1,29) TFR(x0,x1,16) TFR(x0,x1,24)
  x0 += k1; x1 += ks2 + 4u;
  TFR(x0,x1,13) TFR(x0,x1,15) TFR(x0,x1,26) TFR(x0,x1,6)
  x0 += ks2; x1 += k0 + 5u;
  o0 = x0; o1 = x1;
}

DEV float erfinv_f32(float x){
  float w = -log1pf(-x*x);
  float p;
  if (w < 5.0f){
    w -= 2.5f;
    p = 2.81022636e-08f;
    p = fmaf(p, w, 3.43273939e-07f);
    p = fmaf(p, w, -3.5233877e-06f);
    p = fmaf(p, w, -4.39150654e-06f);
    p = fmaf(p, w, 0.00021858087f);
    p = fmaf(p, w, -0.00125372503f);
    p = fmaf(p, w, -0.00417768164f);
    p = fmaf(p, w, 0.246640727f);
    p = fmaf(p, w, 1.50140941f);
  } else {
    w = sqrtf(w) - 3.0f;
    p = -0.000200214257f;
    p = fmaf(p, w, 0.000100950558f);
    p = fmaf(p, w, 0.00134934322f);
    p = fmaf(p, w, -0.00367342844f);
    p = fmaf(p, w, 0.00573950773f);
    p = fmaf(p, w, -0.0076224613f);
    p = fmaf(p, w, 0.00943887047f);
    p = fmaf(p, w, 1.00167406f);
    p = fmaf(p, w, 2.83297682f);
  }
  return p * x;
}

DEV float lapy2f(float x, float y){
  float xa = fabsf(x), ya = fabsf(y);
  float w = fmaxf(xa, ya), z = fminf(xa, ya);
  if (z == 0.f) return w;
  float q = z / w;
  return w * sqrtf(1.f + q*q);
}

DEV void slartg_(float f, float g, float& c, float& s, float& r){
  if (g == 0.f){ c = 1.f; s = 0.f; r = f; }
  else if (f == 0.f){ c = 0.f; s = copysignf(1.f, g); r = fabsf(g); }
  else {
    float d = sqrtf(f*f + g*g);
    c = fabsf(f) / d;
    r = copysignf(d, f);
    s = g / r;
  }
}

DEV void slas2_(float f, float g, float h, float& ssmin, float& ssmax){
  float fa = fabsf(f), ga = fabsf(g), ha = fabsf(h);
  float fhmn = fminf(fa, ha), fhmx = fmaxf(fa, ha);
  if (fhmn == 0.f){
    ssmin = 0.f;
    if (fhmx == 0.f) ssmax = ga;
    else {
      float mx = fmaxf(fhmx, ga), mn = fminf(fhmx, ga);
      float q = mn/mx;
      ssmax = mx*sqrtf(1.f + q*q);
    }
  } else {
    if (ga < fhmx){
      float as_ = 1.f + fhmn/fhmx;
      float at_ = (fhmx - fhmn)/fhmx;
      float au = ga/fhmx; au = au*au;
      float cc = 2.f/(sqrtf(as_*as_ + au) + sqrtf(at_*at_ + au));
      ssmin = fhmn*cc; ssmax = fhmx/cc;
    } else {
      float au = fhmx/ga;
      if (au == 0.f){ ssmin = (fhmn*fhmx)/ga; ssmax = ga; }
      else {
        float as_ = 1.f + fhmn/fhmx;
        float at_ = (fhmx - fhmn)/fhmx;
        float q1 = as_*au, q2 = at_*au;
        float cc = 1.f/(sqrtf(1.f + q1*q1) + sqrtf(1.f + q2*q2));
        ssmin = (fhmn*cc)*au; ssmin = ssmin + ssmin;
        ssmax = ga/(cc + cc);
      }
    }
  }
}

DEV void slasv2_(float f, float g, float h, float& ssmin, float& ssmax,
                 float& snr, float& csr, float& snl, float& csl){
  const float eps = 5.9604645e-08f;
  float ft = f, fa = fabsf(f), ht = h, ha = fabsf(h);
  int pmax = 1;
  bool swp = (ha > fa);
  if (swp){ pmax = 3; float t; t=ft; ft=ht; ht=t; t=fa; fa=ha; ha=t; }
  float gt = g, ga = fabsf(g);
  float clt = 0.f, crt = 0.f, slt = 0.f, srt = 0.f;
  if (ga == 0.f){ ssmin = ha; ssmax = fa; clt = 1.f; crt = 1.f; slt = 0.f; srt = 0.f; }
  else {
    bool gasmal = true;
    if (ga > fa){
      pmax = 2;
      if ((fa/ga) < eps){
        gasmal = false;
        ssmax = ga;
        if (ha > 1.f) ssmin = fa/(ga/ha); else ssmin = (fa/ga)*ha;
        clt = 1.f; slt = ht/gt; srt = 1.f; crt = ft/gt;
      }
    }
    if (gasmal){
      float dd = fa - ha;
      float L = (dd == fa) ? 1.f : dd/fa;
      float Mv = gt/ft;
      float T = 2.f - L;
      float MM = Mv*Mv, TT = T*T;
      float Sv = sqrtf(TT + MM);
      float Rv = (L == 0.f) ? fabsf(Mv) : sqrtf(L*L + MM);
      float Av = 0.5f*(Sv + Rv);
      ssmin = ha/Av; ssmax = fa*Av;
      float Tv;
      if (MM == 0.f){
        if (L == 0.f) Tv = copysignf(2.f, ft)*copysignf(1.f, gt);
        else Tv = gt/copysignf(dd, ft) + Mv/T;
      } else {
        Tv = (Mv/(Sv + T) + Mv/(Rv + L))*(1.f + Av);
      }
      float Lv = sqrtf(Tv*Tv + 4.f);
      crt = 2.f/Lv; srt = Tv/Lv;
      clt = (crt + srt*Mv)/Av;
      slt = (ht/ft)*srt/Av;
    }
  }
  if (swp){ csl = srt; snl = crt; csr = slt; snr = clt; }
  else    { csl = clt; snl = slt; csr = crt; snr = srt; }
  float tsign = 1.f;
  if (pmax == 1) tsign = copysignf(1.f, csr)*copysignf(1.f, csl)*copysignf(1.f, f);
  if (pmax == 2) tsign = copysignf(1.f, snr)*copysignf(1.f, csl)*copysignf(1.f, g);
  if (pmax == 3) tsign = copysignf(1.f, snr)*copysignf(1.f, snl)*copysignf(1.f, h);
  ssmax = copysignf(ssmax, tsign);
  ssmin = copysignf(ssmin, tsign*copysignf(1.f, f)*copysignf(1.f, h));
}

// ===========================================================================
// K1 (r5): hadamard + 2048-bin LDS window hist (dd>>10) + per-block partial
// flush + register below-window counters. NO per-element global atomics.
// ===========================================================================
__global__ __launch_bounds__(256) void k_had(const float* __restrict__ x1,
    const float* __restrict__ x2, float* __restrict__ out, float* __restrict__ ws){
  __shared__ uint32_t wh[2][2048];
  for (int i = threadIdx.x; i < 4096; i += 256) (&wh[0][0])[i] = 0u;
  __syncthreads();
  uint32_t* cnt = (uint32_t*)(ws + OFF_CNT);
  const float4* a4 = (const float4*)x1;
  const float4* b4 = (const float4*)x2;
  nfloat4* o4 = (nfloat4*)out;
  uint32_t cb1 = 0, cb2 = 0;
  long long n4 = NTOT/4;
  long long stride = (long long)gridDim.x * 256;
  for (long long i = (long long)blockIdx.x*256 + threadIdx.x; i < n4; i += stride){
    float4 a = a4[i], b = b4[i];
    nfloat4 o;
    o.x = a.x*b.x; o.y = a.y*b.y; o.z = a.z*b.z; o.w = a.w*b.w;
    __builtin_nontemporal_store(o, &o4[i]);
    uint32_t u, dd;
    u = __float_as_uint(a.x)&0x7fffffffu; cb1 += (u < WLO); dd = u - WLO;
    if (dd < 0x200000u) atomicAdd(&wh[0][dd>>10], 1u);
    u = __float_as_uint(a.y)&0x7fffffffu; cb1 += (u < WLO); dd = u - WLO;
    if (dd < 0x200000u) atomicAdd(&wh[0][dd>>10], 1u);
    u = __float_as_uint(a.z)&0x7fffffffu; cb1 += (u < WLO); dd = u - WLO;
    if (dd < 0x200000u) atomicAdd(&wh[0][dd>>10], 1u);
    u = __float_as_uint(a.w)&0x7fffffffu; cb1 += (u < WLO); dd = u - WLO;
    if (dd < 0x200000u) atomicAdd(&wh[0][dd>>10], 1u);
    u = __float_as_uint(b.x)&0x7fffffffu; cb2 += (u < WLO); dd = u - WLO;
    if (dd < 0x200000u) atomicAdd(&wh[1][dd>>10], 1u);
    u = __float_as_uint(b.y)&0x7fffffffu; cb2 += (u < WLO); dd = u - WLO;
    if (dd < 0x200000u) atomicAdd(&wh[1][dd>>10], 1u);
    u = __float_as_uint(b.z)&0x7fffffffu; cb2 += (u < WLO); dd = u - WLO;
    if (dd < 0x200000u) atomicAdd(&wh[1][dd>>10], 1u);
    u = __float_as_uint(b.w)&0x7fffffffu; cb2 += (u < WLO); dd = u - WLO;
    if (dd < 0x200000u) atomicAdd(&wh[1][dd>>10], 1u);
  }
  __syncthreads();
  uint32_t* wp = (uint32_t*)(ws + OFF_WPART) + (size_t)blockIdx.x*4096;
  for (int i = threadIdx.x; i < 4096; i += 256) wp[i] = (&wh[0][0])[i];
  #pragma unroll
  for (int off = 32; off > 0; off >>= 1){
    cb1 += __shfl_xor(cb1, off, 64);
    cb2 += __shfl_xor(cb2, off, 64);
  }
  if ((threadIdx.x & 63) == 0){
    atomicAdd(&cnt[0], cb1);
    atomicAdd(&cnt[1], cb2);
  }
}

// K1b: reduce 1024 partial window hists -> H[ty][2048] at OFF_COARSE.
__global__ __launch_bounds__(1024) void k_red(float* __restrict__ ws){
  int ty = blockIdx.y;
  const uint32_t* wp = (const uint32_t*)(ws + OFF_WPART);
  uint32_t* H = (uint32_t*)(ws + OFF_COARSE) + ty*2048;
  int t = threadIdx.x;
  int bin = blockIdx.x*256 + (t & 255);
  int pq = t >> 8;   // 0..3
  uint32_t s = 0;
  for (int p = pq*256; p < pq*256 + 256; p++)
    s += wp[(size_t)p*4096 + (size_t)ty*2048 + bin];
  __shared__ uint32_t sh[1024];
  sh[t] = s;
  __syncthreads();
  if (t < 256) H[bin] = sh[t] + sh[t+256] + sh[t+512] + sh[t+768];
}

// K1c: scan window hist, locate sub-bin (1024 fine values) + rank within it.
__global__ __launch_bounds__(256) void k_wselect(float* __restrict__ ws){
  int ty = blockIdx.x;
  const uint32_t* H = (const uint32_t*)(ws + OFF_COARSE) + ty*2048;
  const uint32_t* cnt = (const uint32_t*)(ws + OFF_CNT);
  int* selr = (int*)(ws + OFF_SELR) + ty*4;
  __shared__ unsigned long long ps[256];
  unsigned long long s = 0;
  for (int j = 0; j < 8; j++) s += H[threadIdx.x*8 + j];
  ps[threadIdx.x] = s;
  __syncthreads();
  if (threadIdx.x == 0){
    unsigned long long K = KSEL, cum = cnt[ty];
    int valid = 0, sbin = 0, rank = 0;
    if (K >= cum){
      int g = 0;
      for (; g < 256; g++){ if (cum + ps[g] > K) break; cum += ps[g]; }
      if (g < 256){
        for (int j = 0; j < 8; j++){
          uint32_t c = H[g*8 + j];
          if (cum + c > K){ sbin = g*8 + j; rank = (int)(K - cum); valid = 1; break; }
          cum += c;
        }
      }
    }
    selr[0] = sbin; selr[1] = rank; selr[2] = valid;
  }
}

// K1d: re-stream x, histogram only the selected 1024-value sub-bin (LDS),
// flush ~650 nonzero bins total via global atomics.
__global__ __launch_bounds__(256) void k_fine(const float* __restrict__ x1,
    const float* __restrict__ x2, float* __restrict__ ws){
  int ty = blockIdx.y;
  const int* selr = (const int*)(ws + OFF_SELR) + ty*4;
  if (!selr[2]) return;
  uint32_t g = (uint32_t)selr[0];
  __shared__ uint32_t lh[1024];
  for (int i = threadIdx.x; i < 1024; i += 256) lh[i] = 0u;
  __syncthreads();
  const float4* x4 = (const float4*)(ty ? x2 : x1);
  long long n4 = NTOT/4;
  long long stride = (long long)gridDim.x * 256;
  for (long long i = (long long)blockIdx.x*256 + threadIdx.x; i < n4; i += stride){
    float4 a = x4[i];
    uint32_t dd;
    dd = (__float_as_uint(a.x)&0x7fffffffu) - WLO;
    if ((dd>>10) == g) atomicAdd(&lh[dd & 1023u], 1u);
    dd = (__float_as_uint(a.y)&0x7fffffffu) - WLO;
    if ((dd>>10) == g) atomicAdd(&lh[dd & 1023u], 1u);
    dd = (__float_as_uint(a.z)&0x7fffffffu) - WLO;
    if ((dd>>10) == g) atomicAdd(&lh[dd & 1023u], 1u);
    dd = (__float_as_uint(a.w)&0x7fffffffu) - WLO;
    if ((dd>>10) == g) atomicAdd(&lh[dd & 1023u], 1u);
  }
  __syncthreads();
  uint32_t* gf = (uint32_t*)(ws + OFF_GF) + (size_t)ty*1024;
  for (int i = threadIdx.x; i < 1024; i += 256){
    uint32_t v = lh[i];
    if (v) atomicAdd(&gf[i], v);
  }
}

// K1e: scan the 1024-bin fine hist -> exact bit threshold.
__global__ __launch_bounds__(256) void k_fine_sel(float* __restrict__ ws,
    float* __restrict__ out){
  int ty = blockIdx.x;
  const int* selr = (const int*)(ws + OFF_SELR) + ty*4;
  if (!selr[2]) return;
  const uint32_t* gf = (const uint32_t*)(ws + OFF_GF) + (size_t)ty*1024;
  __shared__ uint32_t sh[1024];
  __shared__ uint32_t ps[256];
  int t = threadIdx.x;
  for (int k = 0; k < 4; k++) sh[k*256 + t] = gf[k*256 + t];
  __syncthreads();
  ps[t] = sh[4*t] + sh[4*t+1] + sh[4*t+2] + sh[4*t+3];
  __syncthreads();
  if (t == 0){
    uint32_t K = (uint32_t)selr[1];
    uint32_t cum = 0; int q = 0;
    for (; q < 256; q++){ if (cum + ps[q] > K) break; cum += ps[q]; }
    if (q > 255) q = 255;
    int f = q*4 + 3;
    for (int jj = 0; jj < 4; jj++){
      uint32_t c = sh[q*4 + jj];
      if (cum + c > K){ f = q*4 + jj; break; }
      cum += c;
    }
    uint32_t bits = WLO + (((uint32_t)selr[0]) << 10) + (uint32_t)f;
    float th = __uint_as_float(bits);
    ws[OFF_TSEL + ty] = th;
    out[ty ? OUT_T2 : OUT_T1] = th;
  }
}

// ---------------------------------------------------------------------------
// Fallback chain (speculation miss). All early-exit in the normal case.
// ---------------------------------------------------------------------------
__global__ __launch_bounds__(256) void k_hist_fb(const float* __restrict__ x1,
    const float* __restrict__ x2, float* __restrict__ ws){
  const int* selr = (const int*)(ws + OFF_SELR);
  if (selr[2] && selr[4 + 2]) return;
  __shared__ uint32_t lh[2][4][2048];
  for (int i = threadIdx.x; i < 2*4*2048; i += 256) (&lh[0][0][0])[i] = 0u;
  __syncthreads();
  int rep = threadIdx.x & 3;
  const float4* a4 = (const float4*)x1;
  const float4* b4 = (const float4*)x2;
  long long n4 = NTOT/4;
  long long stride = (long long)gridDim.x * 256;
  for (long long i = (long long)blockIdx.x*256 + threadIdx.x; i < n4; i += stride){
    float4 a = a4[i], b = b4[i];
    uint32_t u;
    u = __float_as_uint(a.x)&0x7fffffffu; atomicAdd(&lh[0][rep][u>>20], 1u);
    u = __float_as_uint(a.y)&0x7fffffffu; atomicAdd(&lh[0][rep][u>>20], 1u);
    u = __float_as_uint(a.z)&0x7fffffffu; atomicAdd(&lh[0][rep][u>>20], 1u);
    u = __float_as_uint(a.w)&0x7fffffffu; atomicAdd(&lh[0][rep][u>>20], 1u);
    u = __float_as_uint(b.x)&0x7fffffffu; atomicAdd(&lh[1][rep][u>>20], 1u);
    u = __float_as_uint(b.y)&0x7fffffffu; atomicAdd(&lh[1][rep][u>>20], 1u);
    u = __float_as_uint(b.z)&0x7fffffffu; atomicAdd(&lh[1][rep][u>>20], 1u);
    u = __float_as_uint(b.w)&0x7fffffffu; atomicAdd(&lh[1][rep][u>>20], 1u);
  }
  __syncthreads();
  uint32_t* ch = (uint32_t*)(ws + OFF_CHIST);
  for (int i = threadIdx.x; i < 2048; i += 256){
    uint32_t c0 = lh[0][0][i] + lh[0][1][i] + lh[0][2][i] + lh[0][3][i];
    uint32_t c1 = lh[1][0][i] + lh[1][1][i] + lh[1][2][i] + lh[1][3][i];
    ch[((size_t)blockIdx.x*2 + 0)*2048 + i] = c0;
    ch[((size_t)blockIdx.x*2 + 1)*2048 + i] = c1;
  }
}

__global__ __launch_bounds__(256) void k_coarse_red(float* __restrict__ ws){
  int ty = blockIdx.y;
  if (((const int*)(ws + OFF_SELR))[ty*4 + 2]) return;
  const uint32_t* ch = (const uint32_t*)(ws + OFF_CHIST);
  uint32_t* h = (uint32_t*)(ws + OFF_COARSE) + ty*2048;
  int bin = blockIdx.x*128 + (threadIdx.x & 127);
  int half = threadIdx.x >> 7;
  uint32_t s = 0;
  for (int p = half*256; p < half*256 + 256; p++)
    s += ch[((size_t)p*2 + ty)*2048 + bin];
  __shared__ uint32_t sh[256];
  sh[threadIdx.x] = s;
  __syncthreads();
  if (threadIdx.x < 128) h[bin] = sh[threadIdx.x] + sh[threadIdx.x + 128];
}

__global__ __launch_bounds__(256) void k_coarse_scan(float* __restrict__ ws){
  int ty = blockIdx.x;
  int* selr = (int*)(ws + OFF_SELR) + ty*4;
  if (selr[2]) return;
  const uint32_t* h = (const uint32_t*)(ws + OFF_COARSE) + ty*2048;
  __shared__ unsigned long long ps[256];
  unsigned long long s = 0;
  for (int j = 0; j < 8; j++) s += h[threadIdx.x*8 + j];
  ps[threadIdx.x] = s;
  __syncthreads();
  if (threadIdx.x == 0){
    unsigned long long cum = 0, K = KSEL;
    int g = 0;
    for (; g < 256; g++){ if (cum + ps[g] > K) break; cum += ps[g]; }
    if (g > 255) g = 255;
    int bin = 2047;
    for (int j = 0; j < 8; j++){
      uint32_t c = h[g*8 + j];
      if (cum + c > K){ bin = g*8 + j; break; }
      cum += c;
    }
    selr[0] = bin;
    selr[1] = (int)(K - cum);
  }
}

__global__ __launch_bounds__(256) void k_fine_fb(const float* __restrict__ x1,
    const float* __restrict__ x2, float* __restrict__ ws){
  int ty = blockIdx.y;
  const int* selr = (const int*)(ws + OFF_SELR) + ty*4;
  if (selr[2]) return;
  const float4* x4 = (const float4*)(ty ? x2 : x1);
  uint32_t bin = (uint32_t)selr[0];
  uint32_t* f = (uint32_t*)(ws + OFF_FB) + ((size_t)ty<<20);
  long long n4 = NTOT/4;
  long long stride = (long long)gridDim.x * 256;
  for (long long i = (long long)blockIdx.x*256 + threadIdx.x; i < n4; i += stride){
    float4 a = x4[i];
    uint32_t u;
    u = __float_as_uint(a.x)&0x7fffffffu; if ((u>>20)==bin) atomicAdd(&f[u&0xFFFFFu],1u);
    u = __float_as_uint(a.y)&0x7fffffffu; if ((u>>20)==bin) atomicAdd(&f[u&0xFFFFFu],1u);
    u = __float_as_uint(a.z)&0x7fffffffu; if ((u>>20)==bin) atomicAdd(&f[u&0xFFFFFu],1u);
    u = __float_as_uint(a.w)&0x7fffffffu; if ((u>>20)==bin) atomicAdd(&f[u&0xFFFFFu],1u);
  }
}

__global__ __launch_bounds__(256) void k_seg_sum(float* __restrict__ ws){
  int ty = blockIdx.y;
  const int* selr = (const int*)(ws + OFF_SELR) + ty*4;
  if (selr[2]) return;
  const uint32_t* f = (const uint32_t*)(ws + OFF_FB) + ((size_t)ty<<20);
  uint32_t* segs = (uint32_t*)(ws + OFF_SEGS) + ty*1024;
  uint32_t s = 0;
  int base = blockIdx.x*1024;
  for (int k = 0; k < 4; k++) s += f[base + k*256 + threadIdx.x];
  __shared__ uint32_t sh[256];
  sh[threadIdx.x] = s;
  __syncthreads();
  for (int off = 128; off > 0; off >>= 1){
    if (threadIdx.x < off) sh[threadIdx.x] += sh[threadIdx.x + off];
    __syncthreads();
  }
  if (threadIdx.x == 0) segs[blockIdx.x] = sh[0];
}

__global__ __launch_bounds__(256) void k_fine_scan2(float* __restrict__ ws, float* __restrict__ out){
  int ty = blockIdx.x;
  const int* selr = (const int*)(ws + OFF_SELR) + ty*4;
  if (selr[2]) return;
  const uint32_t* f = (const uint32_t*)(ws + OFF_FB) + ((size_t)ty<<20);
  const uint32_t* segs = (const uint32_t*)(ws + OFF_SEGS) + ty*1024;
  __shared__ uint32_t sh[1024];
  __shared__ uint32_t ps[256];
  __shared__ int gsel; __shared__ uint32_t csel;
  int t = threadIdx.x;
  uint32_t K = (uint32_t)selr[1];
  for (int k = 0; k < 4; k++) sh[k*256 + t] = segs[k*256 + t];
  __syncthreads();
  ps[t] = sh[4*t] + sh[4*t+1] + sh[4*t+2] + sh[4*t+3];
  __syncthreads();
  if (t == 0){
    uint32_t cum = 0; int q = 0;
    for (; q < 256; q++){ if (cum + ps[q] > K) break; cum += ps[q]; }
    if (q > 255) q = 255;
    int g = q*4;
    for (int j = 0; j < 4; j++){
      uint32_t c = sh[q*4 + j];
      if (cum + c > K){ g = q*4 + j; break; }
      cum += c;
      if (j == 3) g = q*4 + 3;
    }
    gsel = g; csel = cum;
  }
  __syncthreads();
  int g = gsel;
  for (int k = 0; k < 4; k++) sh[k*256 + t] = f[(size_t)g*1024 + k*256 + t];
  __syncthreads();
  ps[t] = sh[4*t] + sh[4*t+1] + sh[4*t+2] + sh[4*t+3];
  __syncthreads();
  if (t == 0){
    uint32_t cum = csel; int q = 0;
    for (; q < 256; q++){ if (cum + ps[q] > K) break; cum += ps[q]; }
    if (q > 255) q = 255;
    int j = q*4 + 3;
    for (int jj = 0; jj < 4; jj++){
      uint32_t c = sh[q*4 + jj];
      if (cum + c > K){ j = q*4 + jj; break; }
      cum += c;
    }
    uint32_t bits = (((uint32_t)selr[0])<<20) | (uint32_t)((g*1024 + j) & 0xFFFFF);
    float th = __uint_as_float(bits);
    ws[OFF_TSEL + ty] = th;
    out[ty ? OUT_T2 : OUT_T1] = th;
  }
}

__global__ __launch_bounds__(256) void k_omega(uint32_t a0, uint32_t a1,
    uint32_t b0, uint32_t b1, float* __restrict__ ws){
  int ty = blockIdx.y;
  uint32_t k0 = ty ? b0 : a0, k1 = ty ? b1 : a1;
  int i = blockIdx.x*256 + threadIdx.x;
  uint32_t o0, o1;
  d_threefry(k0, k1, 0u, (uint32_t)i, o0, o1);
  uint32_t bits = o0 ^ o1;
  float fr = __uint_as_float((bits >> 9) | 0x3f800000u) - 1.0f;
  const float lo = -0.99999994f;
  float u = fr * 2.0f + lo;
  u = fmaxf(lo, u);
  float v = 1.41421356237f * erfinv_f32(u);
  int row = i >> 4, col = i & 15;
  ws[OFF_OMT + (size_t)ty*65536 + (size_t)col*4096 + row] = v;
}

// K6: Y(8192x16) = residual(x) * W  (W^T 16x4096 in ws)
__global__ __launch_bounds__(256) void k_atype(const float* __restrict__ x1,
    const float* __restrict__ x2, float* __restrict__ ws, size_t wtOff){
  int ty = blockIdx.y;
  const float* x = ty ? x2 : x1;
  const float* wt = ws + wtOff + (size_t)ty*65536;
  float* Y = ws + OFF_BIGY + (size_t)ty*131072;
  float t = ws[OFF_TSEL + ty];
  int wave = threadIdx.x >> 6, lane = threadIdx.x & 63;
  __shared__ __align__(16) float wts[16][256];
  __shared__ float outs[16][16];
  float acc[4][16];
  #pragma unroll
  for (int r = 0; r < 4; r++)
    #pragma unroll
    for (int j = 0; j < 16; j++) acc[r][j] = 0.f;
  int rowbase = blockIdx.x*16 + wave*4;
  for (int c = 0; c < 4096; c += 256){
    __syncthreads();
    for (int idx = threadIdx.x; idx < 16*64; idx += 256){
      int j = idx >> 6, q = idx & 63;
      ((float4*)&wts[j][0])[q] = ((const float4*)(wt + (size_t)j*4096 + c))[q];
    }
    __syncthreads();
    float4 xv[4];
    #pragma unroll
    for (int rr = 0; rr < 4; rr++){
      int row = rowbase + rr;
      float4 a = ((const float4*)(x + (size_t)row*4096 + c))[lane];
      a.x = fabsf(a.x) > t ? 0.f : a.x;
      a.y = fabsf(a.y) > t ? 0.f : a.y;
      a.z = fabsf(a.z) > t ? 0.f : a.z;
      a.w = fabsf(a.w) > t ? 0.f : a.w;
      xv[rr] = a;
    }
    #pragma unroll
    for (int j = 0; j < 16; j++){
      float4 w4 = ((const float4*)&wts[j][0])[lane];
      #pragma unroll
      for (int rr = 0; rr < 4; rr++){
        acc[rr][j] = fmaf(xv[rr].x, w4.x, acc[rr][j]);
        acc[rr][j] = fmaf(xv[rr].y, w4.y, acc[rr][j]);
        acc[rr][j] = fmaf(xv[rr].z, w4.z, acc[rr][j]);
        acc[rr][j] = fmaf(xv[rr].w, w4.w, acc[rr][j]);
      }
    }
  }
  #pragma unroll
  for (int rr = 0; rr < 4; rr++)
    for (int j = 0; j < 16; j++){
      float v = acc[rr][j];
      for (int off = 32; off > 0; off >>= 1) v += __shfl_xor(v, off, 64);
      if (lane == 0) outs[wave*4 + rr][j] = v;
    }
  __syncthreads();
  int r = threadIdx.x >> 4, cc = threadIdx.x & 15;
  Y[(size_t)(blockIdx.x*16 + r)*16 + cc] = outs[r][cc];
}

__global__ __launch_bounds__(256) void k_gramP(float* __restrict__ ws, size_t mOff,
    size_t mStr){
  int ty = blockIdx.y;
  const float* M = ws + mOff + (size_t)ty*mStr;
  float* gp = ws + OFF_GRAMP + (size_t)(ty*64 + blockIdx.x)*256;
  __shared__ __align__(16) float buf[128][16];
  int t = threadIdx.x;
  for (int q = t; q < 512; q += 256)
    ((float4*)&buf[0][0])[q] = ((const float4*)(M + (size_t)blockIdx.x*2048))[q];
  __syncthreads();
  int i = t >> 4, j = t & 15;
  float s = 0.f;
  int rstart = (blockIdx.x == 0) ? 16 : 0;
  for (int r = rstart; r < 128; r++) s += buf[r][i]*buf[r][j];
  gp[t] = s;
}

__global__ __launch_bounds__(256) void k_btype(const float* __restrict__ x1,
    const float* __restrict__ x2, float* __restrict__ ws){
  int ty = blockIdx.y;
  const float* x = ty ? x2 : x1;
  const float* Q = ws + OFF_BIGQ + (size_t)ty*131072;
  float t = ws[OFF_TSEL + ty];
  int cb = blockIdx.x & 15;
  int rc = blockIdx.x >> 4;
  int c = cb*256 + threadIdx.x;
  int r0 = rc*512;
  __shared__ __align__(16) float Qs[64][16];
  float acc[16];
  #pragma unroll
  for (int j = 0; j < 16; j++) acc[j] = 0.f;
  for (int tile = 0; tile < 8; tile++){
    __syncthreads();
    ((float4*)&Qs[0][0])[threadIdx.x] =
        ((const float4*)(Q + (size_t)(r0 + tile*64)*16))[threadIdx.x];
    __syncthreads();
    const float* xp = x + (size_t)(r0 + tile*64)*4096 + c;
    #pragma unroll 4
    for (int rr = 0; rr < 64; rr++){
      float v = xp[(size_t)rr*4096];
      v = fabsf(v) > t ? 0.f : v;
      float4 qa = ((const float4*)&Qs[rr][0])[0];
      float4 qb = ((const float4*)&Qs[rr][0])[1];
      float4 qc = ((const float4*)&Qs[rr][0])[2];
      float4 qd = ((const float4*)&Qs[rr][0])[3];
      acc[ 0] = fmaf(v, qa.x, acc[ 0]);
      acc[ 1] = fmaf(v, qa.y, acc[ 1]);
      acc[ 2] = fmaf(v, qa.z, acc[ 2]);
      acc[ 3] = fmaf(v, qa.w, acc[ 3]);
      acc[ 4] = fmaf(v, qb.x, acc[ 4]);
      acc[ 5] = fmaf(v, qb.y, acc[ 5]);
      acc[ 6] = fmaf(v, qb.z, acc[ 6]);
      acc[ 7] = fmaf(v, qb.w, acc[ 7]);
      acc[ 8] = fmaf(v, qc.x, acc[ 8]);
      acc[ 9] = fmaf(v, qc.y, acc[ 9]);
      acc[10] = fmaf(v, qc.z, acc[10]);
      acc[11] = fmaf(v, qc.w, acc[11]);
      acc[12] = fmaf(v, qd.x, acc[12]);
      acc[13] = fmaf(v, qd.y, acc[13]);
      acc[14] = fmaf(v, qd.z, acc[14]);
      acc[15] = fmaf(v, qd.w, acc[15]);
    }
  }
  float* BP = ws + OFF_BPART + (((size_t)(ty*16 + rc))<<16) + (size_t)c*16;
  #pragma unroll
  for (int q = 0; q < 4; q++){
    float4 o; o.x = acc[q*4]; o.y = acc[q*4+1]; o.z = acc[q*4+2]; o.w = acc[q*4+3];
    ((float4*)BP)[q] = o;
  }
}

__global__ __launch_bounds__(256) void k_bredgram(float* __restrict__ ws){
  int ty = blockIdx.y;
  const float* BP = ws + OFF_BPART + (((size_t)ty*16)<<16);
  float* T = ws + OFF_TMAT + (size_t)ty*65536;
  float* gp = ws + OFF_GRAMP + (size_t)(ty*64 + blockIdx.x)*256;
  __shared__ float sh[64][16];
  int t = threadIdx.x;
  for (int k = 0; k < 4; k++){
    int e = blockIdx.x*1024 + k*256 + t;
    float s = 0.f;
    #pragma unroll
    for (int rc = 0; rc < 16; rc++) s += BP[((size_t)rc<<16) + e];
    T[e] = s;
    int le = k*256 + t;
    sh[le >> 4][le & 15] = s;
  }
  __syncthreads();
  int i = t >> 4, j = t & 15;
  float s = 0.f;
  int rstart = (blockIdx.x == 0) ? 16 : 0;
  for (int r = rstart; r < 64; r++) s += sh[r][i]*sh[r][j];
  gp[t] = s;
}

// K9: register-resident tiny QR: gram-sum, chol (LDS), geqrf+org2r (regs),
//     back-solve. Lane j<16 holds column j.
__global__ __launch_bounds__(64) void k_tiny(float* __restrict__ ws, size_t mOff,
    size_t mStr){
  int ty = blockIdx.x;
  const float* Mp = ws + mOff + (size_t)ty*mStr;
  float* sOut = ws + OFF_S + ty*256;
  float* qtOut = ws + OFF_QTOP + ty*256;
  float* rgOut = ws + OFF_RG + ty*256;
  __shared__ float G[16][16];
  __shared__ float Cld[32][16];
  __shared__ float bc[4];
  __shared__ float tau[16];
  int l = threadIdx.x;
  int j = l & 15;
  for (int e = l; e < 256; e += 64){
    const float* gp = ws + OFF_GRAMP + (size_t)ty*16384 + e;
    float s = 0.f;
    for (int p = 0; p < 64; p++) s += gp[(size_t)p*256];
    G[e>>4][e&15] = s;
  }
  for (int idx = l; idx < 256; idx += 64)
    Cld[idx>>4][idx&15] = Mp[idx];
  __syncthreads();
  // cholesky (upper) in place — identical op order to rounds 1-4
  for (int k = 0; k < 16; k++){
    float dk = sqrtf(G[k][k]);
    if (l == k) G[k][k] = dk;
    else if (l > k && l < 16) G[k][l] = G[k][l] / dk;
    __syncthreads();
    if (l > k && l < 16)
      for (int jj = l; jj < 16; jj++) G[l][jj] -= G[k][l]*G[k][jj];
    __syncthreads();
  }
  // build column registers: C = [M_top ; R_B]
  float Cc[32];
  #pragma unroll
  for (int r = 0; r < 32; r++){
    if (r < 16) Cc[r] = Cld[r][j];
    else Cc[r] = (j >= r - 16) ? G[r-16][j] : 0.f;
  }
  // geqrf (same arithmetic order as LDS version)
  #pragma unroll
  for (int i = 0; i < 16; i++){
    if (l == i){
      float alpha = Cc[i];
      float ssum = 0.f;
      #pragma unroll
      for (int r = i+1; r < 32; r++) ssum += Cc[r]*Cc[r];
      float xn = sqrtf(ssum);
      float beta, tv, sc;
      if (xn == 0.f){ tv = 0.f; beta = alpha; sc = 1.f; }
      else {
        beta = -copysignf(lapy2f(alpha, xn), alpha);
        tv = (beta - alpha)/beta;
        sc = 1.f/(alpha - beta);
        #pragma unroll
        for (int r = i+1; r < 32; r++) Cc[r] *= sc;
      }
      Cc[i] = beta;
      bc[0] = beta; bc[1] = tv;
      tau[i] = tv;
      #pragma unroll
      for (int r = i; r < 32; r++) Cld[r][i] = Cc[r];
    }
    __syncthreads();
    float tv = bc[1];
    if (tv != 0.f && l < 16 && j > i){
      float w = Cc[i];
      #pragma unroll
      for (int r = i+1; r < 32; r++) w += Cld[r][i]*Cc[r];
      w *= tv;
      Cc[i] -= w;
      #pragma unroll
      for (int r = i+1; r < 32; r++) Cc[r] -= w*Cld[r][i];
    }
    __syncthreads();
  }
  // org2r (no barriers needed: Cld/tau now read-only)
  float Qc[32];
  #pragma unroll
  for (int r = 0; r < 32; r++) Qc[r] = 0.f;
  #pragma unroll
  for (int i = 15; i >= 0; i--){
    float tv = tau[i];
    if (i < 15 && l < 16 && j > i){
      float w = Qc[i];
      #pragma unroll
      for (int r = i+1; r < 32; r++) w += Cld[r][i]*Qc[r];
      w *= tv;
      Qc[i] -= w;
      #pragma unroll
      for (int r = i+1; r < 32; r++) Qc[r] -= w*Cld[r][i];
    }
    if (l == i){
      #pragma unroll
      for (int r = 0; r < 32; r++){
        if (r < i) Qc[r] = 0.f;
        else if (r == i) Qc[r] = 1.f - tv;
        else Qc[r] = -tv * Cld[r][i];
      }
    }
  }
  // back-solve S = R_B^{-1} * Q_bot
  float Sc[16];
  if (l < 16){
    #pragma unroll
    for (int i2 = 15; i2 >= 0; i2--){
      float v = Qc[16 + i2];
      #pragma unroll
      for (int k2 = i2+1; k2 < 16; k2++) v -= G[i2][k2]*Sc[k2];
      Sc[i2] = v / G[i2][i2];
    }
    #pragma unroll
    for (int r = 0; r < 16; r++){
      rgOut[r*16 + j] = (j >= r) ? Cc[r] : 0.f;
      sOut[r*16 + j] = Sc[r];
      qtOut[r*16 + j] = Qc[r];
    }
  }
}

__global__ __launch_bounds__(256) void k_applyq(float* __restrict__ ws, size_t mOff,
    size_t mStr, size_t oOff, size_t oStr, int nrows, int wN, int wT){
  int ty = blockIdx.y;
  const float* Mp = ws + mOff + (size_t)ty*mStr;
  const float* sP = ws + OFF_S + ty*256;
  const float* qtP = ws + OFF_QTOP + ty*256;
  float* oP = ws + oOff + (size_t)ty*oStr;
  __shared__ float Ss[16][16], Qt[16][16];
  int t = threadIdx.x;
  Ss[t>>4][t&15] = sP[t];
  Qt[t>>4][t&15] = qtP[t];
  __syncthreads();
  int row = blockIdx.x*256 + t;
  if (row >= nrows) return;
  float o[16];
  if (row < 16){
    #pragma unroll
    for (int j = 0; j < 16; j++) o[j] = Qt[row][j];
  } else {
    float mv[16];
    #pragma unroll
    for (int q = 0; q < 4; q++){
      float4 v = ((const float4*)(Mp + (size_t)row*16))[q];
      mv[q*4] = v.x; mv[q*4+1] = v.y; mv[q*4+2] = v.z; mv[q*4+3] = v.w;
    }
    #pragma unroll
    for (int j = 0; j < 16; j++){
      float sacc = 0.f;
      #pragma unroll
      for (int i = 0; i < 16; i++) sacc = fmaf(mv[i], Ss[i][j], sacc);
      o[j] = sacc;
    }
  }
  if (wN){
    #pragma unroll
    for (int q = 0; q < 4; q++){
      float4 v; v.x = o[q*4]; v.y = o[q*4+1]; v.z = o[q*4+2]; v.w = o[q*4+3];
      ((float4*)(oP + (size_t)row*16))[q] = v;
    }
  }
  if (wT){
    #pragma unroll
    for (int j = 0; j < 16; j++) oP[(size_t)j*4096 + row] = o[j];
  }
}

// ===========================================================================
// K11: gesdd tail. gebd2 (LDS) -> bdsqr (REGISTERS, lane=VT column) -> ormbr.
// ===========================================================================
__global__ __launch_bounds__(64) void k_chain(float* __restrict__ ws){
  int ty = blockIdx.x;
  const float* rg = ws + OFF_RG + ty*256;
  float* vtlOut = ws + OFF_VTL + ty*256;
  const int n = 16;
  __shared__ float A[16][16];
  __shared__ float VTm[16][16];
  __shared__ float d_[16], e_[16], tauq[16], taup[16];
  int l = threadIdx.x;
  for (int idx = l; idx < 256; idx += 64){
    int r = idx >> 4, c = idx & 15;
    A[r][c] = (r >= c) ? rg[c*16 + r] : 0.f;   // L = Rg^T
  }
  __syncthreads();
  // ---- gebd2 (unchanged) ----
  for (int i = 0; i < n; i++){
    {
      float alpha = A[i][i];
      float ssum = 0.f;
      for (int r = i+1; r < n; r++) ssum += A[r][i]*A[r][i];
      float xn = sqrtf(ssum);
      float beta, tv;
      if (n - i <= 1 || xn == 0.f){ tv = 0.f; beta = alpha; }
      else {
        beta = -copysignf(lapy2f(alpha, xn), alpha);
        tv = (beta - alpha)/beta;
        float sc = 1.f/(alpha - beta);
        if (l > i && l < n) A[l][i] *= sc;
      }
      if (l == 0){ d_[i] = beta; tauq[i] = tv; }
      __syncthreads();
      if (tv != 0.f && l > i && l < n){
        int jj = l;
        float w = A[i][jj];
        for (int r = i+1; r < n; r++) w += A[r][i]*A[r][jj];
        w *= tv;
        A[i][jj] -= w;
        for (int r = i+1; r < n; r++) A[r][jj] -= w*A[r][i];
      }
      __syncthreads();
    }
    if (i < n-1){
      float alpha = A[i][i+1];
      float ssum = 0.f;
      for (int c = i+2; c < n; c++) ssum += A[i][c]*A[i][c];
      float xn = sqrtf(ssum);
      float beta, tp;
      if (n - i - 1 <= 1 || xn == 0.f){ tp = 0.f; beta = alpha; }
      else {
        beta = -copysignf(lapy2f(alpha, xn), alpha);
        tp = (beta - alpha)/beta;
        float sc = 1.f/(alpha - beta);
        if (l >= i+2 && l < n) A[i][l] *= sc;
      }
      if (l == 0){ e_[i] = beta; taup[i] = tp; }
      __syncthreads();
      if (tp != 0.f && l > i && l < n){
        int r = l;
        float w = A[r][i+1];
        for (int c = i+2; c < n; c++) w += A[i][c]*A[r][c];
        w *= tp;
        A[r][i+1] -= w;
        for (int c = i+2; c < n; c++) A[r][c] -= w*A[i][c];
      }
      __syncthreads();
    } else {
      if (l == 0) taup[i] = 0.f;
      __syncthreads();
    }
  }
  // ---- bdsqr: all state in registers, wave-uniform control flow ----
  float D[16], E[16], vt[16];
  #pragma unroll
  for (int k = 0; k < 16; k++){
    D[k] = d_[k];
    E[k] = (k < 15) ? e_[k] : 0.f;
    vt[k] = (k == l) ? 1.f : 0.f;
  }
  auto getD = [&](int i)->float{ float r = D[0];
    #pragma unroll
    for (int k = 1; k < 16; k++) if (i == k) r = D[k];
    return r; };
  auto setD = [&](int i, float v){
    #pragma unroll
    for (int k = 0; k < 16; k++) if (i == k) D[k] = v; };
  auto getE = [&](int i)->float{ float r = E[0];
    #pragma unroll
    for (int k = 1; k < 16; k++) if (i == k) r = E[k];
    return r; };
  auto setE = [&](int i, float v){
    #pragma unroll
    for (int k = 0; k < 16; k++) if (i == k) E[k] = v; };
  auto getVt = [&](int i)->float{ float r = vt[0];
    #pragma unroll
    for (int k = 1; k < 16; k++) if (i == k) r = vt[k];
    return r; };
  auto setVt = [&](int i, float v){
    #pragma unroll
    for (int k = 0; k < 16; k++) if (i == k) vt[k] = v; };

  const float eps = 5.9604645e-08f;
  const float unfl = 1.17549435e-38f;
  const float tol = 10.f*eps;
  float sminoa = fabsf(D[0]);
  if (sminoa != 0.f){
    float mu = sminoa;
    #pragma unroll
    for (int i = 1; i < 16; i++){
      mu = fabsf(D[i])*(mu/(mu + fabsf(E[i-1])));
      sminoa = fminf(sminoa, mu);
    }
  }
  sminoa = sminoa / sqrtf((float)n);
  float thresh = fmaxf(tol*sminoa, (float)(6*n*n)*unfl);
  int maxit = 6*n*n;
  int iter = 0, oldll = -1, oldm = -1, mm = n, idir = 0;
  while (true){
    if (mm <= 1) break;
    if (iter > maxit) break;
    float smaxw = fabsf(getD(mm-1));
    int llv = 1; bool split = false;
    {
      bool done = false;
      #pragma unroll
      for (int c = 14; c >= 0; c--){
        if (c <= mm-2 && !done){
          if (fabsf(E[c]) <= thresh){ split = true; llv = c+1; done = true; }
          else smaxw = fmaxf(smaxw, fmaxf(fabsf(D[c]), fabsf(E[c])));
        }
      }
    }
    if (split){
      setE(llv-1, 0.f);
      if (llv == mm-1){ mm = mm - 1; continue; }
      llv = llv + 1;
    }
    if (llv == mm-1){
      float sigmn, sigmx, sinr, cosr, sinl, cosl;
      slasv2_(getD(mm-2), getE(mm-2), getD(mm-1), sigmn, sigmx, sinr, cosr, sinl, cosl);
      setD(mm-2, sigmx); setE(mm-2, 0.f); setD(mm-1, sigmn);
      float t1 = getVt(mm-2), t2 = getVt(mm-1);
      setVt(mm-2, cosr*t1 + sinr*t2);
      setVt(mm-1, cosr*t2 - sinr*t1);
      mm -= 2;
      continue;
    }
    if (llv > oldm || mm < oldll)
      idir = (fabsf(getD(llv-1)) >= fabsf(getD(mm-1))) ? 1 : 2;
    bool deflated = false;
    float sminl = 0.f;
    if (idir == 1){
      if (fabsf(getE(mm-2)) <= tol*fabsf(getD(mm-1))){ setE(mm-2, 0.f); continue; }
      float mu = fabsf(getD(llv-1)); sminl = mu;
      #pragma unroll
      for (int c = 0; c < 15; c++){
        if (c >= llv-1 && c <= mm-2 && !deflated){
          if (fabsf(E[c]) <= tol*mu){ E[c] = 0.f; deflated = true; }
          else {
            mu = fabsf(D[c+1])*(mu/(mu + fabsf(E[c])));
            sminl = fminf(sminl, mu);
          }
        }
      }
    } else {
      if (fabsf(getE(llv-1)) <= tol*fabsf(getD(llv-1))){ setE(llv-1, 0.f); continue; }
      float mu = fabsf(getD(mm-1)); sminl = mu;
      #pragma unroll
      for (int c = 14; c >= 0; c--){
        if (c >= llv-1 && c <= mm-2 && !deflated){
          if (fabsf(E[c]) <= tol*mu){ E[c] = 0.f; deflated = true; }
          else {
            mu = fabsf(D[c])*(mu/(mu + fabsf(E[c])));
            sminl = fminf(sminl, mu);
          }
        }
      }
    }
    if (deflated) continue;
    oldll = llv; oldm = mm;
    float shift = 0.f, rdum;
    if (!((float)n*tol*(sminl/smaxw) <= fmaxf(eps, 0.01f*tol))){
      float sll;
      if (idir == 1){ sll = fabsf(getD(llv-1)); slas2_(getD(mm-2), getE(mm-2), getD(mm-1), shift, rdum); }
      else          { sll = fabsf(getD(mm-1));  slas2_(getD(llv-1), getE(llv-1), getD(llv), shift, rdum); }
      if (sll > 0.f){ float q = shift/sll; if (q*q < eps) shift = 0.f; }
    }
    iter += mm - llv;
    if (shift == 0.f){
      if (idir == 1){
        float cs = 1.f, oldcs = 1.f, sn = 0.f, oldsn = 0.f, rr, dnew;
        #pragma unroll
        for (int i0 = 0; i0 < 15; i0++){
          if (i0 >= llv-1 && i0 <= mm-2){
            slartg_(D[i0]*cs, E[i0], cs, sn, rr);
            if (i0 > llv-1) E[i0-1 < 0 ? 0 : i0-1] = oldsn*rr;
            slartg_(oldcs*rr, D[i0+1]*sn, oldcs, oldsn, dnew);
            D[i0] = dnew;
            if (cs != 1.f || sn != 0.f){
              float t1 = vt[i0], t2 = vt[i0+1];
              vt[i0+1] = cs*t2 - sn*t1;
              vt[i0]   = sn*t2 + cs*t1;
            }
          }
        }
        float h = getD(mm-1)*cs;
        setD(mm-1, h*oldcs);
        float hv = h*oldsn;
        setE(mm-2, (fabsf(hv) <= thresh) ? 0.f : hv);
      } else {
        float cs = 1.f, oldcs = 1.f, sn = 0.f, oldsn = 0.f, rr, dnew;
        #pragma unroll
        for (int i0 = 15; i0 >= 1; i0--){
          if (i0 >= llv && i0 <= mm-1){
            slartg_(D[i0]*cs, E[i0-1], cs, sn, rr);
            if (i0 < mm-1) E[i0] = oldsn*rr;
            slartg_(oldcs*rr, D[i0-1]*sn, oldcs, oldsn, dnew);
            D[i0] = dnew;
            float cR = oldcs, sR = -oldsn;
            if (cR != 1.f || sR != 0.f){
              float t1 = vt[i0-1], t2 = vt[i0];
              vt[i0]   = cR*t2 - sR*t1;
              vt[i0-1] = sR*t2 + cR*t1;
            }
          }
        }
        float h = getD(llv-1)*cs;
        setD(llv-1, h*oldcs);
        float hv = h*oldsn;
        setE(llv-1, (fabsf(hv) <= thresh) ? 0.f : hv);
      }
    } else {
      if (idir == 1){
        float dl = getD(llv-1);
        float ff = (fabsf(dl) - shift)*(copysignf(1.f, dl) + shift/dl);
        float gg = getE(llv-1);
        float cosr, sinr, cosl, sinl, rr;
        #pragma unroll
        for (int i0 = 0; i0 < 15; i0++){
          if (i0 >= llv-1 && i0 <= mm-2){
            slartg_(ff, gg, cosr, sinr, rr);
            if (i0 > llv-1) E[i0-1 < 0 ? 0 : i0-1] = rr;
            float di = D[i0], ei = E[i0];
            ff = cosr*di + sinr*ei;
            E[i0] = cosr*ei - sinr*di;
            gg = sinr*D[i0+1];
            D[i0+1] = cosr*D[i0+1];
            slartg_(ff, gg, cosl, sinl, rr);
            D[i0] = rr;
            float ei2 = E[i0], dip = D[i0+1];
            ff = cosl*ei2 + sinl*dip;
            D[i0+1] = cosl*dip - sinl*ei2;
            if (i0 < mm-2){
              gg = sinl*E[i0+1];
              E[i0+1] = cosl*E[i0+1];
            }
            if (cosr != 1.f || sinr != 0.f){
              float t1 = vt[i0], t2 = vt[i0+1];
              vt[i0+1] = cosr*t2 - sinr*t1;
              vt[i0]   = sinr*t2 + cosr*t1;
            }
          }
        }
        setE(mm-2, (fabsf(ff) <= thresh) ? 0.f : ff);
      } else {
        float dm = getD(mm-1);
        float ff = (fabsf(dm) - shift)*(copysignf(1.f, dm) + shift/dm);
        float gg = getE(mm-2);
        float cosr, sinr, cosl, sinl, rr;
        #pragma unroll
        for (int i0 = 15; i0 >= 1; i0--){
          if (i0 >= llv && i0 <= mm-1){
            slartg_(ff, gg, cosr, sinr, rr);
            if (i0 < mm-1) E[i0] = rr;
            float di = D[i0], eim = E[i0-1];
            ff = cosr*di + sinr*eim;
            E[i0-1] = cosr*eim - sinr*di;
            gg = sinr*D[i0-1];
            D[i0-1] = cosr*D[i0-1];
            slartg_(ff, gg, cosl, sinl, rr);
            D[i0] = rr;
            float eim2 = E[i0-1], dim = D[i0-1];
            ff = cosl*eim2 + sinl*dim;
            D[i0-1] = cosl*dim - sinl*eim2;
            if (i0 > llv){
              gg = sinl*E[i0-2 < 0 ? 0 : i0-2];
              E[i0-2 < 0 ? 0 : i0-2] = cosl*E[i0-2 < 0 ? 0 : i0-2];
            }
            float cR = cosr, sR = -sinr;
            if (cR != 1.f || sR != 0.f){
              float t1 = vt[i0-1], t2 = vt[i0];
              vt[i0]   = cR*t2 - sR*t1;
              vt[i0-1] = sR*t2 + cR*t1;
            }
          }
        }
        setE(llv-1, (fabsf(ff) <= thresh) ? 0.f : ff);
      }
    }
  }
  // make positive
  #pragma unroll
  for (int k = 0; k < 16; k++){
    if (D[k] < 0.f){ D[k] = -D[k]; vt[k] = -vt[k]; }
  }
  // sort decreasing (selection, same tie-breaks as LAPACK slasrt-path in bdsqr)
  #pragma unroll
  for (int i = 1; i <= 15; i++){
    int isub = 1; float smn = D[0];
    #pragma unroll
    for (int jj = 2; jj <= 16; jj++){
      if (jj <= 16 + 1 - i){
        if (D[jj-1] <= smn){ isub = jj; smn = D[jj-1]; }
      }
    }
    if (isub != 16 + 1 - i){
      setD(isub - 1, D[16 - i]);
      D[16 - i] = smn;
      float tmp = getVt(isub - 1);
      setVt(isub - 1, vt[16 - i]);
      vt[16 - i] = tmp;
    }
  }
  // dump VT to LDS for row-wise ormbr
  if (l < 16){
    #pragma unroll
    for (int r = 0; r < 16; r++) VTm[r][l] = vt[r];
  }
  __syncthreads();
  // ormbr('P','R','T'): VT := VT * G(n-1)...G(1)
  for (int i = n-2; i >= 0; i--){
    float tp = taup[i];
    if (tp != 0.f && l < 16){
      int r = l;
      float w = VTm[r][i+1];
      for (int c = i+2; c < n; c++) w += VTm[r][c]*A[i][c];
      w *= tp;
      VTm[r][i+1] -= w;
      for (int c = i+2; c < n; c++) VTm[r][c] -= w*A[i][c];
    }
    __syncthreads();
  }
  for (int idx = l; idx < 256; idx += 64) vtlOut[idx] = VTm[idx>>4][idx&15];
}

// K12: R = Qqr * VT_L^T ; Rinv = R^T
__global__ __launch_bounds__(256) void k_rout(float* __restrict__ ws, float* __restrict__ out){
  int ty = blockIdx.y;
  const float* Qq = ws + OFF_QQR + (size_t)ty*65536;
  const float* vtl = ws + OFF_VTL + ty*256;
  long long Roff  = ty ? OUT_R2  : OUT_R1;
  long long RIoff = ty ? OUT_RI2 : OUT_RI1;
  __shared__ float V[16][16];
  int t = threadIdx.x;
  V[t>>4][t&15] = vtl[t];
  __syncthreads();
  int row = blockIdx.x*256 + t;
  float mv[16];
  #pragma unroll
  for (int q = 0; q < 4; q++){
    float4 v = ((const float4*)(Qq + (size_t)row*16))[q];
    mv[q*4] = v.x; mv[q*4+1] = v.y; mv[q*4+2] = v.z; mv[q*4+3] = v.w;
  }
  #pragma unroll
  for (int j = 0; j < 16; j++){
    float s = 0.f;
    #pragma unroll
    for (int i = 0; i < 16; i++) s = fmaf(mv[i], V[j][i], s);
    out[Roff + (long long)row*16 + j] = s;
    out[RIoff + (long long)j*4096 + row] = s;
  }
}

// ===========================================================================
extern "C" void kernel_launch(void* const* d_in, const int* in_sizes, int n_in,
                              void* d_out, int out_size, void* d_ws, size_t ws_size,
                              hipStream_t stream){
  const float* x1 = (const float*)d_in[0];
  const float* x2 = (const float*)d_in[1];
  float* out = (float*)d_out;
  float* ws = (float*)d_ws;
  (void)in_sizes; (void)n_in; (void)out_size; (void)ws_size;

  hipMemsetAsync(ws + ZERO_BASE, 0, ZERO_FLOATS*sizeof(float), stream);

  k_had<<<dim3(1024), 256, 0, stream>>>(x1, x2, out, ws);
  k_red<<<dim3(8, 2), 1024, 0, stream>>>(ws);
  k_wselect<<<dim3(2), 256, 0, stream>>>(ws);
  k_fine<<<dim3(1024, 2), 256, 0, stream>>>(x1, x2, ws);
  k_fine_sel<<<dim3(2), 256, 0, stream>>>(ws, out);
  // fallback chain (all early-exit when speculation valid)
  k_hist_fb<<<dim3(512), 256, 0, stream>>>(x1, x2, ws);
  k_coarse_red<<<dim3(16, 2), 256, 0, stream>>>(ws);
  k_coarse_scan<<<dim3(2), 256, 0, stream>>>(ws);
  k_fine_fb<<<dim3(1024, 2), 256, 0, stream>>>(x1, x2, ws);
  k_seg_sum<<<dim3(1024, 2), 256, 0, stream>>>(ws);
  k_fine_scan2<<<dim3(2), 256, 0, stream>>>(ws, out);

  uint32_t a0, a1, b0, b1;
  h_threefry(0u, 42u, 0u, 0u, a0, a1);
  h_threefry(0u, 42u, 0u, 1u, b0, b1);
  k_omega<<<dim3(256, 2), 256, 0, stream>>>(a0, a1, b0, b1, ws);

  // QR1
  k_atype<<<dim3(512, 2), 256, 0, stream>>>(x1, x2, ws, OFF_OMT);
  k_gramP<<<dim3(64, 2), 256, 0, stream>>>(ws, OFF_BIGY, 131072);
  k_tiny<<<dim3(2), 64, 0, stream>>>(ws, OFF_BIGY, 131072);
  k_applyq<<<dim3(32, 2), 256, 0, stream>>>(ws, OFF_BIGY, 131072, OFF_BIGQ, 131072, 8192, 1, 0);
  // QR2
  k_btype<<<dim3(256, 2), 256, 0, stream>>>(x1, x2, ws);
  k_bredgram<<<dim3(64, 2), 256, 0, stream>>>(ws);
  k_tiny<<<dim3(2), 64, 0, stream>>>(ws, OFF_TMAT, 65536);
  k_applyq<<<dim3(16, 2), 256, 0, stream>>>(ws, OFF_TMAT, 65536, OFF_ZT, 65536, 4096, 0, 1);
  // QR3
  k_atype<<<dim3(512, 2), 256, 0, stream>>>(x1, x2, ws, OFF_ZT);
  k_gramP<<<dim3(64, 2), 256, 0, stream>>>(ws, OFF_BIGY, 131072);
  k_tiny<<<dim3(2), 64, 0, stream>>>(ws, OFF_BIGY, 131072);
  k_applyq<<<dim3(32, 2), 256, 0, stream>>>(ws, OFF_BIGY, 131072, OFF_BIGQ, 131072, 8192, 1, 0);
  // QR4
  k_btype<<<dim3(256, 2), 256, 0, stream>>>(x1, x2, ws);
  k_bredgram<<<dim3(64, 2), 256, 0, stream>>>(ws);
  k_tiny<<<dim3(2), 64, 0, stream>>>(ws, OFF_TMAT, 65536);
  k_applyq<<<dim3(16, 2), 256, 0, stream>>>(ws, OFF_TMAT, 65536, OFF_ZT, 65536, 4096, 0, 1);
  // QR5
  k_atype<<<dim3(512, 2), 256, 0, stream>>>(x1, x2, ws, OFF_ZT);
  k_gramP<<<dim3(64, 2), 256, 0, stream>>>(ws, OFF_BIGY, 131072);
  k_tiny<<<dim3(2), 64, 0, stream>>>(ws, OFF_BIGY, 131072);
  k_applyq<<<dim3(32, 2), 256, 0, stream>>>(ws, OFF_BIGY, 131072, OFF_BIGQ, 131072, 8192, 1, 0);
  // QR6
  k_btype<<<dim3(256, 2), 256, 0, stream>>>(x1, x2, ws);
  k_bredgram<<<dim3(64, 2), 256, 0, stream>>>(ws);
  k_tiny<<<dim3(2), 64, 0, stream>>>(ws, OFF_TMAT, 65536);
  k_applyq<<<dim3(16, 2), 256, 0, stream>>>(ws, OFF_TMAT, 65536, OFF_QQR, 65536, 4096, 1, 0);

  k_chain<<<dim3(2), 64, 0, stream>>>(ws);
  k_rout<<<dim3(16, 2), 256, 0, stream>>>(ws, out);
}

// Round 3
// 1643.487 us; speedup vs baseline: 1.1280x; 1.0377x over previous
//
#include <hip/hip_runtime.h>
#include <cstdint>
#include <cstddef>

// ============================================================================
// EfficientMemoryHadamard — round 6.
//  R5 post-mortem: quantile path fixed (k_had out of top-5). New bottleneck:
//  k_chain 307us (2-block serial bdsqr, VALUBusy 0.065% -> pure latency on
//  IEEE div/sqrt chains). R6: fast rcp/sqrt (v_rcp_f32/v_sqrt_f32) in the
//  serial tiny kernels ONLY (k_tiny, k_chain + their helpers). ~1ulp change;
//  streaming kernels and quantile semantics byte-identical.
// Verified assumption stack (rounds 1-5 PASSED, absmax 0.1245):
//  A1: jax threefry_partitionable; A2: quantile = order stat 33218888;
//  A3: gesdd tail gelqf->gebd2->bdsqr->ormbr; A4: LAPACK>=3.10 slartg.
// ============================================================================

#define DEV __device__ __forceinline__

typedef float nfloat4 __attribute__((ext_vector_type(4)));

constexpr long long NTOT = 33554432LL;
constexpr unsigned long long KSEL = 33218888ULL;
constexpr uint32_t WLO = 0x40100000u;   // |x| = 2.25; window [2.25, 2.75)

constexpr long long OUT_T1  = 33554432LL;
constexpr long long OUT_R1  = 33554433LL;
constexpr long long OUT_RI1 = 33619969LL;
constexpr long long OUT_T2  = 33685505LL;
constexpr long long OUT_R2  = 33685506LL;
constexpr long long OUT_RI2 = 33751042LL;

// ---- workspace layout (float units) ----
constexpr size_t OFF_WPART  = 0;         // 1024 blocks x 4096 u32 partials = 16MB
constexpr size_t OFF_BPART  = 0;         // alias: 2*16*65536 floats (after quantile)
constexpr size_t OFF_FB     = 4194304;   // 2 x 1M u32 fallback fine hist (zeroed)
constexpr size_t OFF_CNT    = 6291456;   // 2 u32 below-window counters (zeroed)
constexpr size_t OFF_GF     = 6291472;   // 2*1024 u32 fine window hist (zeroed)
constexpr size_t ZERO_BASE  = OFF_FB;    // memset [OFF_FB, OFF_GF+2048)
constexpr size_t ZERO_FLOATS= 2099216;
constexpr size_t OFF_CHIST  = 6291456;   // fallback alias: 512*2*2048 u32 partials
constexpr size_t OFF_COARSE = 8388608;   // 2*2048 u32 (window hist, then fb coarse)
constexpr size_t OFF_SEGS   = 8392704;   // 2*1024 u32
constexpr size_t OFF_SELR   = 8394752;   // 2*4 ints (bin, rank, valid)
constexpr size_t OFF_TSEL   = 8394768;   // 2 floats (+pad)
constexpr size_t OFF_OMT    = 8394784;   // 2*65536
constexpr size_t OFF_BIGY   = 8525856;   // 2*131072
constexpr size_t OFF_BIGQ   = 8788000;   // 2*131072
constexpr size_t OFF_ZT     = 9050144;   // 2*65536
constexpr size_t OFF_QQR    = 9181216;   // 2*65536
constexpr size_t OFF_TMAT   = 9312288;   // 2*65536
constexpr size_t OFF_GRAMP  = 9443360;   // 2*64*256
constexpr size_t OFF_S      = 9476128;   // 2*256
constexpr size_t OFF_QTOP   = 9476640;   // 2*256
constexpr size_t OFF_RG     = 9477152;   // 2*256
constexpr size_t OFF_VTL    = 9477664;   // 2*256
// total 9478176 floats ~= 37.9 MB (unchanged)

// ---------------------------------------------------------------------------
// fast scalar ops for the serial (latency-bound) tiny kernels only
DEV float frcp_(float x){ return __builtin_amdgcn_rcpf(x); }
DEV float fdivf_(float a, float b){ return a * __builtin_amdgcn_rcpf(b); }
DEV float fsqrtf_(float x){ return __builtin_amdgcn_sqrtf(x); }

// ---------------------------------------------------------------------------
#define TFR(a,b,r) { a += b; b = (b << r) | (b >> (32 - r)); b ^= a; }

DEV void d_threefry(uint32_t k0, uint32_t k1, uint32_t x0, uint32_t x1,
                    uint32_t& o0, uint32_t& o1){
  uint32_t ks2 = k0 ^ k1 ^ 0x1BD11BDAu;
  x0 += k0; x1 += k1;
  TFR(x0,x1,13) TFR(x0,x1,15) TFR(x0,x1,26) TFR(x0,x1,6)
  x0 += k1; x1 += ks2 + 1u;
  TFR(x0,x1,17) TFR(x0,x1,29) TFR(x0,x1,16) TFR(x0,x1,24)
  x0 += ks2; x1 += k0 + 2u;
  TFR(x0,x1,13) TFR(x0,x1,15) TFR(x0,x1,26) TFR(x0,x1,6)
  x0 += k0; x1 += k1 + 3u;
  TFR(x0,x1,17) TFR(x0,x1,29) TFR(x0,x1,16) TFR(x0,x1,24)
  x0 += k1; x1 += ks2 + 4u;
  TFR(x0,x1,13) TFR(x0,x1,15) TFR(x0,x1,26) TFR(x0,x1,6)
  x0 += ks2; x1 += k0 + 5u;
  o0 = x0; o1 = x1;
}

static void h_threefry(uint32_t k0, uint32_t k1, uint32_t x0, uint32_t x1,
                       uint32_t& o0, uint32_t& o1){
  uint32_t ks2 = k0 ^ k1 ^ 0x1BD11BDAu;
  x0 += k0; x1 += k1;
  TFR(x0,x1,13) TFR(x0,x1,15) TFR(x0,x1,26) TFR(x0,x1,6)
  x0 += k1; x1 += ks2 + 1u;
  TFR(x0,x1,17) TFR(x0,x1,29) TFR(x0,x1,16) TFR(x0,x1,24)
  x0 += ks2; x1 += k0 + 2u;
  TFR(x0,x1,13) TFR(x0,x1,15) TFR(x0,x1,26) TFR(x0,x1,6)
  x0 += k0; x1 += k1 + 3u;
  TFR(x0,x1,17) TFR(x0,x1,29) TFR(x0,x1,16) TFR(x0,x1,24)
  x0 += k1; x1 += ks2 + 4u;
  TFR(x0,x1,13) TFR(x0,x1,15) TFR(x0,x1,26) TFR(x0,x1,6)
  x0 += ks2; x1 += k0 + 5u;
  o0 = x0; o1 = x1;
}

DEV float erfinv_f32(float x){
  float w = -log1pf(-x*x);
  float p;
  if (w < 5.0f){
    w -= 2.5f;
    p = 2.81022636e-08f;
    p = fmaf(p, w, 3.43273939e-07f);
    p = fmaf(p, w, -3.5233877e-06f);
    p = fmaf(p, w, -4.39150654e-06f);
    p = fmaf(p, w, 0.00021858087f);
    p = fmaf(p, w, -0.00125372503f);
    p = fmaf(p, w, -0.00417768164f);
    p = fmaf(p, w, 0.246640727f);
    p = fmaf(p, w, 1.50140941f);
  } else {
    w = sqrtf(w) - 3.0f;
    p = -0.000200214257f;
    p = fmaf(p, w, 0.000100950558f);
    p = fmaf(p, w, 0.00134934322f);
    p = fmaf(p, w, -0.00367342844f);
    p = fmaf(p, w, 0.00573950773f);
    p = fmaf(p, w, -0.0076224613f);
    p = fmaf(p, w, 0.00943887047f);
    p = fmaf(p, w, 1.00167406f);
    p = fmaf(p, w, 2.83297682f);
  }
  return p * x;
}

// fast lapy2 — only used by serial tiny kernels (k_tiny / k_chain)
DEV float lapy2f(float x, float y){
  float xa = fabsf(x), ya = fabsf(y);
  float w = fmaxf(xa, ya), z = fminf(xa, ya);
  if (z == 0.f) return w;
  float q = z * frcp_(w);
  return w * fsqrtf_(1.f + q*q);
}

DEV void slartg_(float f, float g, float& c, float& s, float& r){
  if (g == 0.f){ c = 1.f; s = 0.f; r = f; }
  else if (f == 0.f){ c = 0.f; s = copysignf(1.f, g); r = fabsf(g); }
  else {
    float d = fsqrtf_(f*f + g*g);
    float rd = frcp_(d);
    c = fabsf(f) * rd;
    r = copysignf(d, f);
    s = g * copysignf(rd, f);   // == g / copysign(d, f)
  }
}

DEV void slas2_(float f, float g, float h, float& ssmin, float& ssmax){
  float fa = fabsf(f), ga = fabsf(g), ha = fabsf(h);
  float fhmn = fminf(fa, ha), fhmx = fmaxf(fa, ha);
  if (fhmn == 0.f){
    ssmin = 0.f;
    if (fhmx == 0.f) ssmax = ga;
    else {
      float mx = fmaxf(fhmx, ga), mn = fminf(fhmx, ga);
      float q = mn * frcp_(mx);
      ssmax = mx*fsqrtf_(1.f + q*q);
    }
  } else {
    if (ga < fhmx){
      float rmx = frcp_(fhmx);
      float as_ = 1.f + fhmn*rmx;
      float at_ = (fhmx - fhmn)*rmx;
      float au = ga*rmx; au = au*au;
      float cc = 2.f * frcp_(fsqrtf_(as_*as_ + au) + fsqrtf_(at_*at_ + au));
      ssmin = fhmn*cc; ssmax = fhmx*frcp_(cc);
    } else {
      float au = fhmx * frcp_(ga);
      if (au == 0.f){ ssmin = (fhmn*fhmx)*frcp_(ga); ssmax = ga; }
      else {
        float rmx = frcp_(fhmx);
        float as_ = 1.f + fhmn*rmx;
        float at_ = (fhmx - fhmn)*rmx;
        float q1 = as_*au, q2 = at_*au;
        float cc = frcp_(fsqrtf_(1.f + q1*q1) + fsqrtf_(1.f + q2*q2));
        ssmin = (fhmn*cc)*au; ssmin = ssmin + ssmin;
        ssmax = ga*frcp_(cc + cc);
      }
    }
  }
}

DEV void slasv2_(float f, float g, float h, float& ssmin, float& ssmax,
                 float& snr, float& csr, float& snl, float& csl){
  const float eps = 5.9604645e-08f;
  float ft = f, fa = fabsf(f), ht = h, ha = fabsf(h);
  int pmax = 1;
  bool swp = (ha > fa);
  if (swp){ pmax = 3; float t; t=ft; ft=ht; ht=t; t=fa; fa=ha; ha=t; }
  float gt = g, ga = fabsf(g);
  float clt = 0.f, crt = 0.f, slt = 0.f, srt = 0.f;
  if (ga == 0.f){ ssmin = ha; ssmax = fa; clt = 1.f; crt = 1.f; slt = 0.f; srt = 0.f; }
  else {
    bool gasmal = true;
    if (ga > fa){
      pmax = 2;
      if ((fa*frcp_(ga)) < eps){
        gasmal = false;
        ssmax = ga;
        if (ha > 1.f) ssmin = fa*frcp_(ga*frcp_(ha)); else ssmin = (fa*frcp_(ga))*ha;
        clt = 1.f; slt = ht*frcp_(gt); srt = 1.f; crt = ft*frcp_(gt);
      }
    }
    if (gasmal){
      float dd = fa - ha;
      float rfa = frcp_(fa);
      float L = (dd == fa) ? 1.f : dd*rfa;
      float Mv = gt*frcp_(ft);
      float T = 2.f - L;
      float MM = Mv*Mv, TT = T*T;
      float Sv = fsqrtf_(TT + MM);
      float Rv = (L == 0.f) ? fabsf(Mv) : fsqrtf_(L*L + MM);
      float Av = 0.5f*(Sv + Rv);
      float rAv = frcp_(Av);
      ssmin = ha*rAv; ssmax = fa*Av;
      float Tv;
      if (MM == 0.f){
        if (L == 0.f) Tv = copysignf(2.f, ft)*copysignf(1.f, gt);
        else Tv = gt*frcp_(copysignf(dd, ft)) + Mv*frcp_(T);
      } else {
        Tv = (Mv*frcp_(Sv + T) + Mv*frcp_(Rv + L))*(1.f + Av);
      }
      float Lv = fsqrtf_(Tv*Tv + 4.f);
      float rLv = frcp_(Lv);
      crt = 2.f*rLv; srt = Tv*rLv;
      clt = (crt + srt*Mv)*rAv;
      slt = (ht*frcp_(ft))*srt*rAv;
    }
  }
  if (swp){ csl = srt; snl = crt; csr = slt; snr = clt; }
  else    { csl = clt; snl = slt; csr = crt; snr = srt; }
  float tsign = 1.f;
  if (pmax == 1) tsign = copysignf(1.f, csr)*copysignf(1.f, csl)*copysignf(1.f, f);
  if (pmax == 2) tsign = copysignf(1.f, snr)*copysignf(1.f, csl)*copysignf(1.f, g);
  if (pmax == 3) tsign = copysignf(1.f, snr)*copysignf(1.f, snl)*copysignf(1.f, h);
  ssmax = copysignf(ssmax, tsign);
  ssmin = copysignf(ssmin, tsign*copysignf(1.f, f)*copysignf(1.f, h));
}

// ===========================================================================
// K1 (r5): hadamard + 2048-bin LDS window hist (dd>>10) + per-block partial
// flush + register below-window counters. NO per-element global atomics.
// ===========================================================================
__global__ __launch_bounds__(256) void k_had(const float* __restrict__ x1,
    const float* __restrict__ x2, float* __restrict__ out, float* __restrict__ ws){
  __shared__ uint32_t wh[2][2048];
  for (int i = threadIdx.x; i < 4096; i += 256) (&wh[0][0])[i] = 0u;
  __syncthreads();
  uint32_t* cnt = (uint32_t*)(ws + OFF_CNT);
  const float4* a4 = (const float4*)x1;
  const float4* b4 = (const float4*)x2;
  nfloat4* o4 = (nfloat4*)out;
  uint32_t cb1 = 0, cb2 = 0;
  long long n4 = NTOT/4;
  long long stride = (long long)gridDim.x * 256;
  for (long long i = (long long)blockIdx.x*256 + threadIdx.x; i < n4; i += stride){
    float4 a = a4[i], b = b4[i];
    nfloat4 o;
    o.x = a.x*b.x; o.y = a.y*b.y; o.z = a.z*b.z; o.w = a.w*b.w;
    __builtin_nontemporal_store(o, &o4[i]);
    uint32_t u, dd;
    u = __float_as_uint(a.x)&0x7fffffffu; cb1 += (u < WLO); dd = u - WLO;
    if (dd < 0x200000u) atomicAdd(&wh[0][dd>>10], 1u);
    u = __float_as_uint(a.y)&0x7fffffffu; cb1 += (u < WLO); dd = u - WLO;
    if (dd < 0x200000u) atomicAdd(&wh[0][dd>>10], 1u);
    u = __float_as_uint(a.z)&0x7fffffffu; cb1 += (u < WLO); dd = u - WLO;
    if (dd < 0x200000u) atomicAdd(&wh[0][dd>>10], 1u);
    u = __float_as_uint(a.w)&0x7fffffffu; cb1 += (u < WLO); dd = u - WLO;
    if (dd < 0x200000u) atomicAdd(&wh[0][dd>>10], 1u);
    u = __float_as_uint(b.x)&0x7fffffffu; cb2 += (u < WLO); dd = u - WLO;
    if (dd < 0x200000u) atomicAdd(&wh[1][dd>>10], 1u);
    u = __float_as_uint(b.y)&0x7fffffffu; cb2 += (u < WLO); dd = u - WLO;
    if (dd < 0x200000u) atomicAdd(&wh[1][dd>>10], 1u);
    u = __float_as_uint(b.z)&0x7fffffffu; cb2 += (u < WLO); dd = u - WLO;
    if (dd < 0x200000u) atomicAdd(&wh[1][dd>>10], 1u);
    u = __float_as_uint(b.w)&0x7fffffffu; cb2 += (u < WLO); dd = u - WLO;
    if (dd < 0x200000u) atomicAdd(&wh[1][dd>>10], 1u);
  }
  __syncthreads();
  uint32_t* wp = (uint32_t*)(ws + OFF_WPART) + (size_t)blockIdx.x*4096;
  for (int i = threadIdx.x; i < 4096; i += 256) wp[i] = (&wh[0][0])[i];
  #pragma unroll
  for (int off = 32; off > 0; off >>= 1){
    cb1 += __shfl_xor(cb1, off, 64);
    cb2 += __shfl_xor(cb2, off, 64);
  }
  if ((threadIdx.x & 63) == 0){
    atomicAdd(&cnt[0], cb1);
    atomicAdd(&cnt[1], cb2);
  }
}

// K1b: reduce 1024 partial window hists -> H[ty][2048] at OFF_COARSE.
__global__ __launch_bounds__(1024) void k_red(float* __restrict__ ws){
  int ty = blockIdx.y;
  const uint32_t* wp = (const uint32_t*)(ws + OFF_WPART);
  uint32_t* H = (uint32_t*)(ws + OFF_COARSE) + ty*2048;
  int t = threadIdx.x;
  int bin = blockIdx.x*256 + (t & 255);
  int pq = t >> 8;   // 0..3
  uint32_t s = 0;
  for (int p = pq*256; p < pq*256 + 256; p++)
    s += wp[(size_t)p*4096 + (size_t)ty*2048 + bin];
  __shared__ uint32_t sh[1024];
  sh[t] = s;
  __syncthreads();
  if (t < 256) H[bin] = sh[t] + sh[t+256] + sh[t+512] + sh[t+768];
}

// K1c: scan window hist, locate sub-bin (1024 fine values) + rank within it.
__global__ __launch_bounds__(256) void k_wselect(float* __restrict__ ws){
  int ty = blockIdx.x;
  const uint32_t* H = (const uint32_t*)(ws + OFF_COARSE) + ty*2048;
  const uint32_t* cnt = (const uint32_t*)(ws + OFF_CNT);
  int* selr = (int*)(ws + OFF_SELR) + ty*4;
  __shared__ unsigned long long ps[256];
  unsigned long long s = 0;
  for (int j = 0; j < 8; j++) s += H[threadIdx.x*8 + j];
  ps[threadIdx.x] = s;
  __syncthreads();
  if (threadIdx.x == 0){
    unsigned long long K = KSEL, cum = cnt[ty];
    int valid = 0, sbin = 0, rank = 0;
    if (K >= cum){
      int g = 0;
      for (; g < 256; g++){ if (cum + ps[g] > K) break; cum += ps[g]; }
      if (g < 256){
        for (int j = 0; j < 8; j++){
          uint32_t c = H[g*8 + j];
          if (cum + c > K){ sbin = g*8 + j; rank = (int)(K - cum); valid = 1; break; }
          cum += c;
        }
      }
    }
    selr[0] = sbin; selr[1] = rank; selr[2] = valid;
  }
}

// K1d: re-stream x, histogram only the selected 1024-value sub-bin (LDS),
// flush ~650 nonzero bins total via global atomics.
__global__ __launch_bounds__(256) void k_fine(const float* __restrict__ x1,
    const float* __restrict__ x2, float* __restrict__ ws){
  int ty = blockIdx.y;
  const int* selr = (const int*)(ws + OFF_SELR) + ty*4;
  if (!selr[2]) return;
  uint32_t g = (uint32_t)selr[0];
  __shared__ uint32_t lh[1024];
  for (int i = threadIdx.x; i < 1024; i += 256) lh[i] = 0u;
  __syncthreads();
  const float4* x4 = (const float4*)(ty ? x2 : x1);
  long long n4 = NTOT/4;
  long long stride = (long long)gridDim.x * 256;
  for (long long i = (long long)blockIdx.x*256 + threadIdx.x; i < n4; i += stride){
    float4 a = x4[i];
    uint32_t dd;
    dd = (__float_as_uint(a.x)&0x7fffffffu) - WLO;
    if ((dd>>10) == g) atomicAdd(&lh[dd & 1023u], 1u);
    dd = (__float_as_uint(a.y)&0x7fffffffu) - WLO;
    if ((dd>>10) == g) atomicAdd(&lh[dd & 1023u], 1u);
    dd = (__float_as_uint(a.z)&0x7fffffffu) - WLO;
    if ((dd>>10) == g) atomicAdd(&lh[dd & 1023u], 1u);
    dd = (__float_as_uint(a.w)&0x7fffffffu) - WLO;
    if ((dd>>10) == g) atomicAdd(&lh[dd & 1023u], 1u);
  }
  __syncthreads();
  uint32_t* gf = (uint32_t*)(ws + OFF_GF) + (size_t)ty*1024;
  for (int i = threadIdx.x; i < 1024; i += 256){
    uint32_t v = lh[i];
    if (v) atomicAdd(&gf[i], v);
  }
}

// K1e: scan the 1024-bin fine hist -> exact bit threshold.
__global__ __launch_bounds__(256) void k_fine_sel(float* __restrict__ ws,
    float* __restrict__ out){
  int ty = blockIdx.x;
  const int* selr = (const int*)(ws + OFF_SELR) + ty*4;
  if (!selr[2]) return;
  const uint32_t* gf = (const uint32_t*)(ws + OFF_GF) + (size_t)ty*1024;
  __shared__ uint32_t sh[1024];
  __shared__ uint32_t ps[256];
  int t = threadIdx.x;
  for (int k = 0; k < 4; k++) sh[k*256 + t] = gf[k*256 + t];
  __syncthreads();
  ps[t] = sh[4*t] + sh[4*t+1] + sh[4*t+2] + sh[4*t+3];
  __syncthreads();
  if (t == 0){
    uint32_t K = (uint32_t)selr[1];
    uint32_t cum = 0; int q = 0;
    for (; q < 256; q++){ if (cum + ps[q] > K) break; cum += ps[q]; }
    if (q > 255) q = 255;
    int f = q*4 + 3;
    for (int jj = 0; jj < 4; jj++){
      uint32_t c = sh[q*4 + jj];
      if (cum + c > K){ f = q*4 + jj; break; }
      cum += c;
    }
    uint32_t bits = WLO + (((uint32_t)selr[0]) << 10) + (uint32_t)f;
    float th = __uint_as_float(bits);
    ws[OFF_TSEL + ty] = th;
    out[ty ? OUT_T2 : OUT_T1] = th;
  }
}

// ---------------------------------------------------------------------------
// Fallback chain (speculation miss). All early-exit in the normal case.
// ---------------------------------------------------------------------------
__global__ __launch_bounds__(256) void k_hist_fb(const float* __restrict__ x1,
    const float* __restrict__ x2, float* __restrict__ ws){
  const int* selr = (const int*)(ws + OFF_SELR);
  if (selr[2] && selr[4 + 2]) return;
  __shared__ uint32_t lh[2][4][2048];
  for (int i = threadIdx.x; i < 2*4*2048; i += 256) (&lh[0][0][0])[i] = 0u;
  __syncthreads();
  int rep = threadIdx.x & 3;
  const float4* a4 = (const float4*)x1;
  const float4* b4 = (const float4*)x2;
  long long n4 = NTOT/4;
  long long stride = (long long)gridDim.x * 256;
  for (long long i = (long long)blockIdx.x*256 + threadIdx.x; i < n4; i += stride){
    float4 a = a4[i], b = b4[i];
    uint32_t u;
    u = __float_as_uint(a.x)&0x7fffffffu; atomicAdd(&lh[0][rep][u>>20], 1u);
    u = __float_as_uint(a.y)&0x7fffffffu; atomicAdd(&lh[0][rep][u>>20], 1u);
    u = __float_as_uint(a.z)&0x7fffffffu; atomicAdd(&lh[0][rep][u>>20], 1u);
    u = __float_as_uint(a.w)&0x7fffffffu; atomicAdd(&lh[0][rep][u>>20], 1u);
    u = __float_as_uint(b.x)&0x7fffffffu; atomicAdd(&lh[1][rep][u>>20], 1u);
    u = __float_as_uint(b.y)&0x7fffffffu; atomicAdd(&lh[1][rep][u>>20], 1u);
    u = __float_as_uint(b.z)&0x7fffffffu; atomicAdd(&lh[1][rep][u>>20], 1u);
    u = __float_as_uint(b.w)&0x7fffffffu; atomicAdd(&lh[1][rep][u>>20], 1u);
  }
  __syncthreads();
  uint32_t* ch = (uint32_t*)(ws + OFF_CHIST);
  for (int i = threadIdx.x; i < 2048; i += 256){
    uint32_t c0 = lh[0][0][i] + lh[0][1][i] + lh[0][2][i] + lh[0][3][i];
    uint32_t c1 = lh[1][0][i] + lh[1][1][i] + lh[1][2][i] + lh[1][3][i];
    ch[((size_t)blockIdx.x*2 + 0)*2048 + i] = c0;
    ch[((size_t)blockIdx.x*2 + 1)*2048 + i] = c1;
  }
}

__global__ __launch_bounds__(256) void k_coarse_red(float* __restrict__ ws){
  int ty = blockIdx.y;
  if (((const int*)(ws + OFF_SELR))[ty*4 + 2]) return;
  const uint32_t* ch = (const uint32_t*)(ws + OFF_CHIST);
  uint32_t* h = (uint32_t*)(ws + OFF_COARSE) + ty*2048;
  int bin = blockIdx.x*128 + (threadIdx.x & 127);
  int half = threadIdx.x >> 7;
  uint32_t s = 0;
  for (int p = half*256; p < half*256 + 256; p++)
    s += ch[((size_t)p*2 + ty)*2048 + bin];
  __shared__ uint32_t sh[256];
  sh[threadIdx.x] = s;
  __syncthreads();
  if (threadIdx.x < 128) h[bin] = sh[threadIdx.x] + sh[threadIdx.x + 128];
}

__global__ __launch_bounds__(256) void k_coarse_scan(float* __restrict__ ws){
  int ty = blockIdx.x;
  int* selr = (int*)(ws + OFF_SELR) + ty*4;
  if (selr[2]) return;
  const uint32_t* h = (const uint32_t*)(ws + OFF_COARSE) + ty*2048;
  __shared__ unsigned long long ps[256];
  unsigned long long s = 0;
  for (int j = 0; j < 8; j++) s += h[threadIdx.x*8 + j];
  ps[threadIdx.x] = s;
  __syncthreads();
  if (threadIdx.x == 0){
    unsigned long long cum = 0, K = KSEL;
    int g = 0;
    for (; g < 256; g++){ if (cum + ps[g] > K) break; cum += ps[g]; }
    if (g > 255) g = 255;
    int bin = 2047;
    for (int j = 0; j < 8; j++){
      uint32_t c = h[g*8 + j];
      if (cum + c > K){ bin = g*8 + j; break; }
      cum += c;
    }
    selr[0] = bin;
    selr[1] = (int)(K - cum);
  }
}

__global__ __launch_bounds__(256) void k_fine_fb(const float* __restrict__ x1,
    const float* __restrict__ x2, float* __restrict__ ws){
  int ty = blockIdx.y;
  const int* selr = (const int*)(ws + OFF_SELR) + ty*4;
  if (selr[2]) return;
  const float4* x4 = (const float4*)(ty ? x2 : x1);
  uint32_t bin = (uint32_t)selr[0];
  uint32_t* f = (uint32_t*)(ws + OFF_FB) + ((size_t)ty<<20);
  long long n4 = NTOT/4;
  long long stride = (long long)gridDim.x * 256;
  for (long long i = (long long)blockIdx.x*256 + threadIdx.x; i < n4; i += stride){
    float4 a = x4[i];
    uint32_t u;
    u = __float_as_uint(a.x)&0x7fffffffu; if ((u>>20)==bin) atomicAdd(&f[u&0xFFFFFu],1u);
    u = __float_as_uint(a.y)&0x7fffffffu; if ((u>>20)==bin) atomicAdd(&f[u&0xFFFFFu],1u);
    u = __float_as_uint(a.z)&0x7fffffffu; if ((u>>20)==bin) atomicAdd(&f[u&0xFFFFFu],1u);
    u = __float_as_uint(a.w)&0x7fffffffu; if ((u>>20)==bin) atomicAdd(&f[u&0xFFFFFu],1u);
  }
}

__global__ __launch_bounds__(256) void k_seg_sum(float* __restrict__ ws){
  int ty = blockIdx.y;
  const int* selr = (const int*)(ws + OFF_SELR) + ty*4;
  if (selr[2]) return;
  const uint32_t* f = (const uint32_t*)(ws + OFF_FB) + ((size_t)ty<<20);
  uint32_t* segs = (uint32_t*)(ws + OFF_SEGS) + ty*1024;
  uint32_t s = 0;
  int base = blockIdx.x*1024;
  for (int k = 0; k < 4; k++) s += f[base + k*256 + threadIdx.x];
  __shared__ uint32_t sh[256];
  sh[threadIdx.x] = s;
  __syncthreads();
  for (int off = 128; off > 0; off >>= 1){
    if (threadIdx.x < off) sh[threadIdx.x] += sh[threadIdx.x + off];
    __syncthreads();
  }
  if (threadIdx.x == 0) segs[blockIdx.x] = sh[0];
}

__global__ __launch_bounds__(256) void k_fine_scan2(float* __restrict__ ws, float* __restrict__ out){
  int ty = blockIdx.x;
  const int* selr = (const int*)(ws + OFF_SELR) + ty*4;
  if (selr[2]) return;
  const uint32_t* f = (const uint32_t*)(ws + OFF_FB) + ((size_t)ty<<20);
  const uint32_t* segs = (const uint32_t*)(ws + OFF_SEGS) + ty*1024;
  __shared__ uint32_t sh[1024];
  __shared__ uint32_t ps[256];
  __shared__ int gsel; __shared__ uint32_t csel;
  int t = threadIdx.x;
  uint32_t K = (uint32_t)selr[1];
  for (int k = 0; k < 4; k++) sh[k*256 + t] = segs[k*256 + t];
  __syncthreads();
  ps[t] = sh[4*t] + sh[4*t+1] + sh[4*t+2] + sh[4*t+3];
  __syncthreads();
  if (t == 0){
    uint32_t cum = 0; int q = 0;
    for (; q < 256; q++){ if (cum + ps[q] > K) break; cum += ps[q]; }
    if (q > 255) q = 255;
    int g = q*4;
    for (int j = 0; j < 4; j++){
      uint32_t c = sh[q*4 + j];
      if (cum + c > K){ g = q*4 + j; break; }
      cum += c;
      if (j == 3) g = q*4 + 3;
    }
    gsel = g; csel = cum;
  }
  __syncthreads();
  int g = gsel;
  for (int k = 0; k < 4; k++) sh[k*256 + t] = f[(size_t)g*1024 + k*256 + t];
  __syncthreads();
  ps[t] = sh[4*t] + sh[4*t+1] + sh[4*t+2] + sh[4*t+3];
  __syncthreads();
  if (t == 0){
    uint32_t cum = csel; int q = 0;
    for (; q < 256; q++){ if (cum + ps[q] > K) break; cum += ps[q]; }
    if (q > 255) q = 255;
    int j = q*4 + 3;
    for (int jj = 0; jj < 4; jj++){
      uint32_t c = sh[q*4 + jj];
      if (cum + c > K){ j = q*4 + jj; break; }
      cum += c;
    }
    uint32_t bits = (((uint32_t)selr[0])<<20) | (uint32_t)((g*1024 + j) & 0xFFFFF);
    float th = __uint_as_float(bits);
    ws[OFF_TSEL + ty] = th;
    out[ty ? OUT_T2 : OUT_T1] = th;
  }
}

__global__ __launch_bounds__(256) void k_omega(uint32_t a0, uint32_t a1,
    uint32_t b0, uint32_t b1, float* __restrict__ ws){
  int ty = blockIdx.y;
  uint32_t k0 = ty ? b0 : a0, k1 = ty ? b1 : a1;
  int i = blockIdx.x*256 + threadIdx.x;
  uint32_t o0, o1;
  d_threefry(k0, k1, 0u, (uint32_t)i, o0, o1);
  uint32_t bits = o0 ^ o1;
  float fr = __uint_as_float((bits >> 9) | 0x3f800000u) - 1.0f;
  const float lo = -0.99999994f;
  float u = fr * 2.0f + lo;
  u = fmaxf(lo, u);
  float v = 1.41421356237f * erfinv_f32(u);
  int row = i >> 4, col = i & 15;
  ws[OFF_OMT + (size_t)ty*65536 + (size_t)col*4096 + row] = v;
}

// K6: Y(8192x16) = residual(x) * W  (W^T 16x4096 in ws)
__global__ __launch_bounds__(256) void k_atype(const float* __restrict__ x1,
    const float* __restrict__ x2, float* __restrict__ ws, size_t wtOff){
  int ty = blockIdx.y;
  const float* x = ty ? x2 : x1;
  const float* wt = ws + wtOff + (size_t)ty*65536;
  float* Y = ws + OFF_BIGY + (size_t)ty*131072;
  float t = ws[OFF_TSEL + ty];
  int wave = threadIdx.x >> 6, lane = threadIdx.x & 63;
  __shared__ __align__(16) float wts[16][256];
  __shared__ float outs[16][16];
  float acc[4][16];
  #pragma unroll
  for (int r = 0; r < 4; r++)
    #pragma unroll
    for (int j = 0; j < 16; j++) acc[r][j] = 0.f;
  int rowbase = blockIdx.x*16 + wave*4;
  for (int c = 0; c < 4096; c += 256){
    __syncthreads();
    for (int idx = threadIdx.x; idx < 16*64; idx += 256){
      int j = idx >> 6, q = idx & 63;
      ((float4*)&wts[j][0])[q] = ((const float4*)(wt + (size_t)j*4096 + c))[q];
    }
    __syncthreads();
    float4 xv[4];
    #pragma unroll
    for (int rr = 0; rr < 4; rr++){
      int row = rowbase + rr;
      float4 a = ((const float4*)(x + (size_t)row*4096 + c))[lane];
      a.x = fabsf(a.x) > t ? 0.f : a.x;
      a.y = fabsf(a.y) > t ? 0.f : a.y;
      a.z = fabsf(a.z) > t ? 0.f : a.z;
      a.w = fabsf(a.w) > t ? 0.f : a.w;
      xv[rr] = a;
    }
    #pragma unroll
    for (int j = 0; j < 16; j++){
      float4 w4 = ((const float4*)&wts[j][0])[lane];
      #pragma unroll
      for (int rr = 0; rr < 4; rr++){
        acc[rr][j] = fmaf(xv[rr].x, w4.x, acc[rr][j]);
        acc[rr][j] = fmaf(xv[rr].y, w4.y, acc[rr][j]);
        acc[rr][j] = fmaf(xv[rr].z, w4.z, acc[rr][j]);
        acc[rr][j] = fmaf(xv[rr].w, w4.w, acc[rr][j]);
      }
    }
  }
  #pragma unroll
  for (int rr = 0; rr < 4; rr++)
    for (int j = 0; j < 16; j++){
      float v = acc[rr][j];
      for (int off = 32; off > 0; off >>= 1) v += __shfl_xor(v, off, 64);
      if (lane == 0) outs[wave*4 + rr][j] = v;
    }
  __syncthreads();
  int r = threadIdx.x >> 4, cc = threadIdx.x & 15;
  Y[(size_t)(blockIdx.x*16 + r)*16 + cc] = outs[r][cc];
}

__global__ __launch_bounds__(256) void k_gramP(float* __restrict__ ws, size_t mOff,
    size_t mStr){
  int ty = blockIdx.y;
  const float* M = ws + mOff + (size_t)ty*mStr;
  float* gp = ws + OFF_GRAMP + (size_t)(ty*64 + blockIdx.x)*256;
  __shared__ __align__(16) float buf[128][16];
  int t = threadIdx.x;
  for (int q = t; q < 512; q += 256)
    ((float4*)&buf[0][0])[q] = ((const float4*)(M + (size_t)blockIdx.x*2048))[q];
  __syncthreads();
  int i = t >> 4, j = t & 15;
  float s = 0.f;
  int rstart = (blockIdx.x == 0) ? 16 : 0;
  for (int r = rstart; r < 128; r++) s += buf[r][i]*buf[r][j];
  gp[t] = s;
}

__global__ __launch_bounds__(256) void k_btype(const float* __restrict__ x1,
    const float* __restrict__ x2, float* __restrict__ ws){
  int ty = blockIdx.y;
  const float* x = ty ? x2 : x1;
  const float* Q = ws + OFF_BIGQ + (size_t)ty*131072;
  float t = ws[OFF_TSEL + ty];
  int cb = blockIdx.x & 15;
  int rc = blockIdx.x >> 4;
  int c = cb*256 + threadIdx.x;
  int r0 = rc*512;
  __shared__ __align__(16) float Qs[64][16];
  float acc[16];
  #pragma unroll
  for (int j = 0; j < 16; j++) acc[j] = 0.f;
  for (int tile = 0; tile < 8; tile++){
    __syncthreads();
    ((float4*)&Qs[0][0])[threadIdx.x] =
        ((const float4*)(Q + (size_t)(r0 + tile*64)*16))[threadIdx.x];
    __syncthreads();
    const float* xp = x + (size_t)(r0 + tile*64)*4096 + c;
    #pragma unroll 4
    for (int rr = 0; rr < 64; rr++){
      float v = xp[(size_t)rr*4096];
      v = fabsf(v) > t ? 0.f : v;
      float4 qa = ((const float4*)&Qs[rr][0])[0];
      float4 qb = ((const float4*)&Qs[rr][0])[1];
      float4 qc = ((const float4*)&Qs[rr][0])[2];
      float4 qd = ((const float4*)&Qs[rr][0])[3];
      acc[ 0] = fmaf(v, qa.x, acc[ 0]);
      acc[ 1] = fmaf(v, qa.y, acc[ 1]);
      acc[ 2] = fmaf(v, qa.z, acc[ 2]);
      acc[ 3] = fmaf(v, qa.w, acc[ 3]);
      acc[ 4] = fmaf(v, qb.x, acc[ 4]);
      acc[ 5] = fmaf(v, qb.y, acc[ 5]);
      acc[ 6] = fmaf(v, qb.z, acc[ 6]);
      acc[ 7] = fmaf(v, qb.w, acc[ 7]);
      acc[ 8] = fmaf(v, qc.x, acc[ 8]);
      acc[ 9] = fmaf(v, qc.y, acc[ 9]);
      acc[10] = fmaf(v, qc.z, acc[10]);
      acc[11] = fmaf(v, qc.w, acc[11]);
      acc[12] = fmaf(v, qd.x, acc[12]);
      acc[13] = fmaf(v, qd.y, acc[13]);
      acc[14] = fmaf(v, qd.z, acc[14]);
      acc[15] = fmaf(v, qd.w, acc[15]);
    }
  }
  float* BP = ws + OFF_BPART + (((size_t)(ty*16 + rc))<<16) + (size_t)c*16;
  #pragma unroll
  for (int q = 0; q < 4; q++){
    float4 o; o.x = acc[q*4]; o.y = acc[q*4+1]; o.z = acc[q*4+2]; o.w = acc[q*4+3];
    ((float4*)BP)[q] = o;
  }
}

__global__ __launch_bounds__(256) void k_bredgram(float* __restrict__ ws){
  int ty = blockIdx.y;
  const float* BP = ws + OFF_BPART + (((size_t)ty*16)<<16);
  float* T = ws + OFF_TMAT + (size_t)ty*65536;
  float* gp = ws + OFF_GRAMP + (size_t)(ty*64 + blockIdx.x)*256;
  __shared__ float sh[64][16];
  int t = threadIdx.x;
  for (int k = 0; k < 4; k++){
    int e = blockIdx.x*1024 + k*256 + t;
    float s = 0.f;
    #pragma unroll
    for (int rc = 0; rc < 16; rc++) s += BP[((size_t)rc<<16) + e];
    T[e] = s;
    int le = k*256 + t;
    sh[le >> 4][le & 15] = s;
  }
  __syncthreads();
  int i = t >> 4, j = t & 15;
  float s = 0.f;
  int rstart = (blockIdx.x == 0) ? 16 : 0;
  for (int r = rstart; r < 64; r++) s += sh[r][i]*sh[r][j];
  gp[t] = s;
}

// K9: register-resident tiny QR: gram-sum, chol (LDS), geqrf+org2r (regs),
//     back-solve. Lane j<16 holds column j.  (r6: fast rcp/sqrt)
__global__ __launch_bounds__(64) void k_tiny(float* __restrict__ ws, size_t mOff,
    size_t mStr){
  int ty = blockIdx.x;
  const float* Mp = ws + mOff + (size_t)ty*mStr;
  float* sOut = ws + OFF_S + ty*256;
  float* qtOut = ws + OFF_QTOP + ty*256;
  float* rgOut = ws + OFF_RG + ty*256;
  __shared__ float G[16][16];
  __shared__ float Cld[32][16];
  __shared__ float bc[4];
  __shared__ float tau[16];
  int l = threadIdx.x;
  int j = l & 15;
  for (int e = l; e < 256; e += 64){
    const float* gp = ws + OFF_GRAMP + (size_t)ty*16384 + e;
    float s = 0.f;
    for (int p = 0; p < 64; p++) s += gp[(size_t)p*256];
    G[e>>4][e&15] = s;
  }
  for (int idx = l; idx < 256; idx += 64)
    Cld[idx>>4][idx&15] = Mp[idx];
  __syncthreads();
  // cholesky (upper) in place — fast rcp/sqrt
  for (int k = 0; k < 16; k++){
    float dk = fsqrtf_(G[k][k]);
    float rdk = frcp_(dk);
    if (l == k) G[k][k] = dk;
    else if (l > k && l < 16) G[k][l] = G[k][l] * rdk;
    __syncthreads();
    if (l > k && l < 16)
      for (int jj = l; jj < 16; jj++) G[l][jj] -= G[k][l]*G[k][jj];
    __syncthreads();
  }
  // build column registers: C = [M_top ; R_B]
  float Cc[32];
  #pragma unroll
  for (int r = 0; r < 32; r++){
    if (r < 16) Cc[r] = Cld[r][j];
    else Cc[r] = (j >= r - 16) ? G[r-16][j] : 0.f;
  }
  // geqrf (fast rcp/sqrt, same op order)
  #pragma unroll
  for (int i = 0; i < 16; i++){
    if (l == i){
      float alpha = Cc[i];
      float ssum = 0.f;
      #pragma unroll
      for (int r = i+1; r < 32; r++) ssum += Cc[r]*Cc[r];
      float xn = fsqrtf_(ssum);
      float beta, tv, sc;
      if (xn == 0.f){ tv = 0.f; beta = alpha; sc = 1.f; }
      else {
        beta = -copysignf(lapy2f(alpha, xn), alpha);
        tv = fdivf_(beta - alpha, beta);
        sc = frcp_(alpha - beta);
        #pragma unroll
        for (int r = i+1; r < 32; r++) Cc[r] *= sc;
      }
      Cc[i] = beta;
      bc[0] = beta; bc[1] = tv;
      tau[i] = tv;
      #pragma unroll
      for (int r = i; r < 32; r++) Cld[r][i] = Cc[r];
    }
    __syncthreads();
    float tv = bc[1];
    if (tv != 0.f && l < 16 && j > i){
      float w = Cc[i];
      #pragma unroll
      for (int r = i+1; r < 32; r++) w += Cld[r][i]*Cc[r];
      w *= tv;
      Cc[i] -= w;
      #pragma unroll
      for (int r = i+1; r < 32; r++) Cc[r] -= w*Cld[r][i];
    }
    __syncthreads();
  }
  // org2r (no barriers needed: Cld/tau now read-only)
  float Qc[32];
  #pragma unroll
  for (int r = 0; r < 32; r++) Qc[r] = 0.f;
  #pragma unroll
  for (int i = 15; i >= 0; i--){
    float tv = tau[i];
    if (i < 15 && l < 16 && j > i){
      float w = Qc[i];
      #pragma unroll
      for (int r = i+1; r < 32; r++) w += Cld[r][i]*Qc[r];
      w *= tv;
      Qc[i] -= w;
      #pragma unroll
      for (int r = i+1; r < 32; r++) Qc[r] -= w*Cld[r][i];
    }
    if (l == i){
      #pragma unroll
      for (int r = 0; r < 32; r++){
        if (r < i) Qc[r] = 0.f;
        else if (r == i) Qc[r] = 1.f - tv;
        else Qc[r] = -tv * Cld[r][i];
      }
    }
  }
  // back-solve S = R_B^{-1} * Q_bot
  float Sc[16];
  if (l < 16){
    #pragma unroll
    for (int i2 = 15; i2 >= 0; i2--){
      float v = Qc[16 + i2];
      #pragma unroll
      for (int k2 = i2+1; k2 < 16; k2++) v -= G[i2][k2]*Sc[k2];
      Sc[i2] = v * frcp_(G[i2][i2]);
    }
    #pragma unroll
    for (int r = 0; r < 16; r++){
      rgOut[r*16 + j] = (j >= r) ? Cc[r] : 0.f;
      sOut[r*16 + j] = Sc[r];
      qtOut[r*16 + j] = Qc[r];
    }
  }
}

__global__ __launch_bounds__(256) void k_applyq(float* __restrict__ ws, size_t mOff,
    size_t mStr, size_t oOff, size_t oStr, int nrows, int wN, int wT){
  int ty = blockIdx.y;
  const float* Mp = ws + mOff + (size_t)ty*mStr;
  const float* sP = ws + OFF_S + ty*256;
  const float* qtP = ws + OFF_QTOP + ty*256;
  float* oP = ws + oOff + (size_t)ty*oStr;
  __shared__ float Ss[16][16], Qt[16][16];
  int t = threadIdx.x;
  Ss[t>>4][t&15] = sP[t];
  Qt[t>>4][t&15] = qtP[t];
  __syncthreads();
  int row = blockIdx.x*256 + t;
  if (row >= nrows) return;
  float o[16];
  if (row < 16){
    #pragma unroll
    for (int j = 0; j < 16; j++) o[j] = Qt[row][j];
  } else {
    float mv[16];
    #pragma unroll
    for (int q = 0; q < 4; q++){
      float4 v = ((const float4*)(Mp + (size_t)row*16))[q];
      mv[q*4] = v.x; mv[q*4+1] = v.y; mv[q*4+2] = v.z; mv[q*4+3] = v.w;
    }
    #pragma unroll
    for (int j = 0; j < 16; j++){
      float sacc = 0.f;
      #pragma unroll
      for (int i = 0; i < 16; i++) sacc = fmaf(mv[i], Ss[i][j], sacc);
      o[j] = sacc;
    }
  }
  if (wN){
    #pragma unroll
    for (int q = 0; q < 4; q++){
      float4 v; v.x = o[q*4]; v.y = o[q*4+1]; v.z = o[q*4+2]; v.w = o[q*4+3];
      ((float4*)(oP + (size_t)row*16))[q] = v;
    }
  }
  if (wT){
    #pragma unroll
    for (int j = 0; j < 16; j++) oP[(size_t)j*4096 + row] = o[j];
  }
}

// ===========================================================================
// K11: gesdd tail. gebd2 (LDS) -> bdsqr (REGISTERS, lane=VT column) -> ormbr.
// r6: fast rcp/sqrt throughout (latency-bound serial chain).
// ===========================================================================
__global__ __launch_bounds__(64) void k_chain(float* __restrict__ ws){
  int ty = blockIdx.x;
  const float* rg = ws + OFF_RG + ty*256;
  float* vtlOut = ws + OFF_VTL + ty*256;
  const int n = 16;
  __shared__ float A[16][16];
  __shared__ float VTm[16][16];
  __shared__ float d_[16], e_[16], tauq[16], taup[16];
  int l = threadIdx.x;
  for (int idx = l; idx < 256; idx += 64){
    int r = idx >> 4, c = idx & 15;
    A[r][c] = (r >= c) ? rg[c*16 + r] : 0.f;   // L = Rg^T
  }
  __syncthreads();
  // ---- gebd2 (fast rcp/sqrt) ----
  for (int i = 0; i < n; i++){
    {
      float alpha = A[i][i];
      float ssum = 0.f;
      for (int r = i+1; r < n; r++) ssum += A[r][i]*A[r][i];
      float xn = fsqrtf_(ssum);
      float beta, tv;
      if (n - i <= 1 || xn == 0.f){ tv = 0.f; beta = alpha; }
      else {
        beta = -copysignf(lapy2f(alpha, xn), alpha);
        tv = fdivf_(beta - alpha, beta);
        float sc = frcp_(alpha - beta);
        if (l > i && l < n) A[l][i] *= sc;
      }
      if (l == 0){ d_[i] = beta; tauq[i] = tv; }
      __syncthreads();
      if (tv != 0.f && l > i && l < n){
        int jj = l;
        float w = A[i][jj];
        for (int r = i+1; r < n; r++) w += A[r][i]*A[r][jj];
        w *= tv;
        A[i][jj] -= w;
        for (int r = i+1; r < n; r++) A[r][jj] -= w*A[r][i];
      }
      __syncthreads();
    }
    if (i < n-1){
      float alpha = A[i][i+1];
      float ssum = 0.f;
      for (int c = i+2; c < n; c++) ssum += A[i][c]*A[i][c];
      float xn = fsqrtf_(ssum);
      float beta, tp;
      if (n - i - 1 <= 1 || xn == 0.f){ tp = 0.f; beta = alpha; }
      else {
        beta = -copysignf(lapy2f(alpha, xn), alpha);
        tp = fdivf_(beta - alpha, beta);
        float sc = frcp_(alpha - beta);
        if (l >= i+2 && l < n) A[i][l] *= sc;
      }
      if (l == 0){ e_[i] = beta; taup[i] = tp; }
      __syncthreads();
      if (tp != 0.f && l > i && l < n){
        int r = l;
        float w = A[r][i+1];
        for (int c = i+2; c < n; c++) w += A[i][c]*A[r][c];
        w *= tp;
        A[r][i+1] -= w;
        for (int c = i+2; c < n; c++) A[r][c] -= w*A[i][c];
      }
      __syncthreads();
    } else {
      if (l == 0) taup[i] = 0.f;
      __syncthreads();
    }
  }
  // ---- bdsqr: all state in registers, wave-uniform control flow ----
  float D[16], E[16], vt[16];
  #pragma unroll
  for (int k = 0; k < 16; k++){
    D[k] = d_[k];
    E[k] = (k < 15) ? e_[k] : 0.f;
    vt[k] = (k == l) ? 1.f : 0.f;
  }
  auto getD = [&](int i)->float{ float r = D[0];
    #pragma unroll
    for (int k = 1; k < 16; k++) if (i == k) r = D[k];
    return r; };
  auto setD = [&](int i, float v){
    #pragma unroll
    for (int k = 0; k < 16; k++) if (i == k) D[k] = v; };
  auto getE = [&](int i)->float{ float r = E[0];
    #pragma unroll
    for (int k = 1; k < 16; k++) if (i == k) r = E[k];
    return r; };
  auto setE = [&](int i, float v){
    #pragma unroll
    for (int k = 0; k < 16; k++) if (i == k) E[k] = v; };
  auto getVt = [&](int i)->float{ float r = vt[0];
    #pragma unroll
    for (int k = 1; k < 16; k++) if (i == k) r = vt[k];
    return r; };
  auto setVt = [&](int i, float v){
    #pragma unroll
    for (int k = 0; k < 16; k++) if (i == k) vt[k] = v; };

  const float eps = 5.9604645e-08f;
  const float unfl = 1.17549435e-38f;
  const float tol = 10.f*eps;
  float sminoa = fabsf(D[0]);
  if (sminoa != 0.f){
    float mu = sminoa;
    #pragma unroll
    for (int i = 1; i < 16; i++){
      mu = fabsf(D[i])*fdivf_(mu, mu + fabsf(E[i-1]));
      sminoa = fminf(sminoa, mu);
    }
  }
  sminoa = sminoa * 0.25f;   // == / sqrtf(16)
  float thresh = fmaxf(tol*sminoa, (float)(6*n*n)*unfl);
  int maxit = 6*n*n;
  int iter = 0, oldll = -1, oldm = -1, mm = n, idir = 0;
  while (true){
    if (mm <= 1) break;
    if (iter > maxit) break;
    float smaxw = fabsf(getD(mm-1));
    int llv = 1; bool split = false;
    {
      bool done = false;
      #pragma unroll
      for (int c = 14; c >= 0; c--){
        if (c <= mm-2 && !done){
          if (fabsf(E[c]) <= thresh){ split = true; llv = c+1; done = true; }
          else smaxw = fmaxf(smaxw, fmaxf(fabsf(D[c]), fabsf(E[c])));
        }
      }
    }
    if (split){
      setE(llv-1, 0.f);
      if (llv == mm-1){ mm = mm - 1; continue; }
      llv = llv + 1;
    }
    if (llv == mm-1){
      float sigmn, sigmx, sinr, cosr, sinl, cosl;
      slasv2_(getD(mm-2), getE(mm-2), getD(mm-1), sigmn, sigmx, sinr, cosr, sinl, cosl);
      setD(mm-2, sigmx); setE(mm-2, 0.f); setD(mm-1, sigmn);
      float t1 = getVt(mm-2), t2 = getVt(mm-1);
      setVt(mm-2, cosr*t1 + sinr*t2);
      setVt(mm-1, cosr*t2 - sinr*t1);
      mm -= 2;
      continue;
    }
    if (llv > oldm || mm < oldll)
      idir = (fabsf(getD(llv-1)) >= fabsf(getD(mm-1))) ? 1 : 2;
    bool deflated = false;
    float sminl = 0.f;
    if (idir == 1){
      if (fabsf(getE(mm-2)) <= tol*fabsf(getD(mm-1))){ setE(mm-2, 0.f); continue; }
      float mu = fabsf(getD(llv-1)); sminl = mu;
      #pragma unroll
      for (int c = 0; c < 15; c++){
        if (c >= llv-1 && c <= mm-2 && !deflated){
          if (fabsf(E[c]) <= tol*mu){ E[c] = 0.f; deflated = true; }
          else {
            mu = fabsf(D[c+1])*fdivf_(mu, mu + fabsf(E[c]));
            sminl = fminf(sminl, mu);
          }
        }
      }
    } else {
      if (fabsf(getE(llv-1)) <= tol*fabsf(getD(llv-1))){ setE(llv-1, 0.f); continue; }
      float mu = fabsf(getD(mm-1)); sminl = mu;
      #pragma unroll
      for (int c = 14; c >= 0; c--){
        if (c >= llv-1 && c <= mm-2 && !deflated){
          if (fabsf(E[c]) <= tol*mu){ E[c] = 0.f; deflated = true; }
          else {
            mu = fabsf(D[c])*fdivf_(mu, mu + fabsf(E[c]));
            sminl = fminf(sminl, mu);
          }
        }
      }
    }
    if (deflated) continue;
    oldll = llv; oldm = mm;
    float shift = 0.f, rdum;
    if (!((float)n*tol*fdivf_(sminl, smaxw) <= fmaxf(eps, 0.01f*tol))){
      float sll;
      if (idir == 1){ sll = fabsf(getD(llv-1)); slas2_(getD(mm-2), getE(mm-2), getD(mm-1), shift, rdum); }
      else          { sll = fabsf(getD(mm-1));  slas2_(getD(llv-1), getE(llv-1), getD(llv), shift, rdum); }
      if (sll > 0.f){ float q = fdivf_(shift, sll); if (q*q < eps) shift = 0.f; }
    }
    iter += mm - llv;
    if (shift == 0.f){
      if (idir == 1){
        float cs = 1.f, oldcs = 1.f, sn = 0.f, oldsn = 0.f, rr, dnew;
        #pragma unroll
        for (int i0 = 0; i0 < 15; i0++){
          if (i0 >= llv-1 && i0 <= mm-2){
            slartg_(D[i0]*cs, E[i0], cs, sn, rr);
            if (i0 > llv-1) E[i0-1 < 0 ? 0 : i0-1] = oldsn*rr;
            slartg_(oldcs*rr, D[i0+1]*sn, oldcs, oldsn, dnew);
            D[i0] = dnew;
            if (cs != 1.f || sn != 0.f){
              float t1 = vt[i0], t2 = vt[i0+1];
              vt[i0+1] = cs*t2 - sn*t1;
              vt[i0]   = sn*t2 + cs*t1;
            }
          }
        }
        float h = getD(mm-1)*cs;
        setD(mm-1, h*oldcs);
        float hv = h*oldsn;
        setE(mm-2, (fabsf(hv) <= thresh) ? 0.f : hv);
      } else {
        float cs = 1.f, oldcs = 1.f, sn = 0.f, oldsn = 0.f, rr, dnew;
        #pragma unroll
        for (int i0 = 15; i0 >= 1; i0--){
          if (i0 >= llv && i0 <= mm-1){
            slartg_(D[i0]*cs, E[i0-1], cs, sn, rr);
            if (i0 < mm-1) E[i0] = oldsn*rr;
            slartg_(oldcs*rr, D[i0-1]*sn, oldcs, oldsn, dnew);
            D[i0] = dnew;
            float cR = oldcs, sR = -oldsn;
            if (cR != 1.f || sR != 0.f){
              float t1 = vt[i0-1], t2 = vt[i0];
              vt[i0]   = cR*t2 - sR*t1;
              vt[i0-1] = sR*t2 + cR*t1;
            }
          }
        }
        float h = getD(llv-1)*cs;
        setD(llv-1, h*oldcs);
        float hv = h*oldsn;
        setE(llv-1, (fabsf(hv) <= thresh) ? 0.f : hv);
      }
    } else {
      if (idir == 1){
        float dl = getD(llv-1);
        float ff = (fabsf(dl) - shift)*(copysignf(1.f, dl) + fdivf_(shift, dl));
        float gg = getE(llv-1);
        float cosr, sinr, cosl, sinl, rr;
        #pragma unroll
        for (int i0 = 0; i0 < 15; i0++){
          if (i0 >= llv-1 && i0 <= mm-2){
            slartg_(ff, gg, cosr, sinr, rr);
            if (i0 > llv-1) E[i0-1 < 0 ? 0 : i0-1] = rr;
            float di = D[i0], ei = E[i0];
            ff = cosr*di + sinr*ei;
            E[i0] = cosr*ei - sinr*di;
            gg = sinr*D[i0+1];
            D[i0+1] = cosr*D[i0+1];
            slartg_(ff, gg, cosl, sinl, rr);
            D[i0] = rr;
            float ei2 = E[i0], dip = D[i0+1];
            ff = cosl*ei2 + sinl*dip;
            D[i0+1] = cosl*dip - sinl*ei2;
            if (i0 < mm-2){
              gg = sinl*E[i0+1];
              E[i0+1] = cosl*E[i0+1];
            }
            if (cosr != 1.f || sinr != 0.f){
              float t1 = vt[i0], t2 = vt[i0+1];
              vt[i0+1] = cosr*t2 - sinr*t1;
              vt[i0]   = sinr*t2 + cosr*t1;
            }
          }
        }
        setE(mm-2, (fabsf(ff) <= thresh) ? 0.f : ff);
      } else {
        float dm = getD(mm-1);
        float ff = (fabsf(dm) - shift)*(copysignf(1.f, dm) + fdivf_(shift, dm));
        float gg = getE(mm-2);
        float cosr, sinr, cosl, sinl, rr;
        #pragma unroll
        for (int i0 = 15; i0 >= 1; i0--){
          if (i0 >= llv && i0 <= mm-1){
            slartg_(ff, gg, cosr, sinr, rr);
            if (i0 < mm-1) E[i0] = rr;
            float di = D[i0], eim = E[i0-1];
            ff = cosr*di + sinr*eim;
            E[i0-1] = cosr*eim - sinr*di;
            gg = sinr*D[i0-1];
            D[i0-1] = cosr*D[i0-1];
            slartg_(ff, gg, cosl, sinl, rr);
            D[i0] = rr;
            float eim2 = E[i0-1], dim = D[i0-1];
            ff = cosl*eim2 + sinl*dim;
            D[i0-1] = cosl*dim - sinl*eim2;
            if (i0 > llv){
              gg = sinl*E[i0-2 < 0 ? 0 : i0-2];
              E[i0-2 < 0 ? 0 : i0-2] = cosl*E[i0-2 < 0 ? 0 : i0-2];
            }
            float cR = cosr, sR = -sinr;
            if (cR != 1.f || sR != 0.f){
              float t1 = vt[i0-1], t2 = vt[i0];
              vt[i0]   = cR*t2 - sR*t1;
              vt[i0-1] = sR*t2 + cR*t1;
            }
          }
        }
        setE(llv-1, (fabsf(ff) <= thresh) ? 0.f : ff);
      }
    }
  }
  // make positive
  #pragma unroll
  for (int k = 0; k < 16; k++){
    if (D[k] < 0.f){ D[k] = -D[k]; vt[k] = -vt[k]; }
  }
  // sort decreasing (selection, same tie-breaks as LAPACK slasrt-path in bdsqr)
  #pragma unroll
  for (int i = 1; i <= 15; i++){
    int isub = 1; float smn = D[0];
    #pragma unroll
    for (int jj = 2; jj <= 16; jj++){
      if (jj <= 16 + 1 - i){
        if (D[jj-1] <= smn){ isub = jj; smn = D[jj-1]; }
      }
    }
    if (isub != 16 + 1 - i){
      setD(isub - 1, D[16 - i]);
      D[16 - i] = smn;
      float tmp = getVt(isub - 1);
      setVt(isub - 1, vt[16 - i]);
      vt[16 - i] = tmp;
    }
  }
  // dump VT to LDS for row-wise ormbr
  if (l < 16){
    #pragma unroll
    for (int r = 0; r < 16; r++) VTm[r][l] = vt[r];
  }
  __syncthreads();
  // ormbr('P','R','T'): VT := VT * G(n-1)...G(1)
  for (int i = n-2; i >= 0; i--){
    float tp = taup[i];
    if (tp != 0.f && l < 16){
      int r = l;
      float w = VTm[r][i+1];
      for (int c = i+2; c < n; c++) w += VTm[r][c]*A[i][c];
      w *= tp;
      VTm[r][i+1] -= w;
      for (int c = i+2; c < n; c++) VTm[r][c] -= w*A[i][c];
    }
    __syncthreads();
  }
  for (int idx = l; idx < 256; idx += 64) vtlOut[idx] = VTm[idx>>4][idx&15];
}

// K12: R = Qqr * VT_L^T ; Rinv = R^T
__global__ __launch_bounds__(256) void k_rout(float* __restrict__ ws, float* __restrict__ out){
  int ty = blockIdx.y;
  const float* Qq = ws + OFF_QQR + (size_t)ty*65536;
  const float* vtl = ws + OFF_VTL + ty*256;
  long long Roff  = ty ? OUT_R2  : OUT_R1;
  long long RIoff = ty ? OUT_RI2 : OUT_RI1;
  __shared__ float V[16][16];
  int t = threadIdx.x;
  V[t>>4][t&15] = vtl[t];
  __syncthreads();
  int row = blockIdx.x*256 + t;
  float mv[16];
  #pragma unroll
  for (int q = 0; q < 4; q++){
    float4 v = ((const float4*)(Qq + (size_t)row*16))[q];
    mv[q*4] = v.x; mv[q*4+1] = v.y; mv[q*4+2] = v.z; mv[q*4+3] = v.w;
  }
  #pragma unroll
  for (int j = 0; j < 16; j++){
    float s = 0.f;
    #pragma unroll
    for (int i = 0; i < 16; i++) s = fmaf(mv[i], V[j][i], s);
    out[Roff + (long long)row*16 + j] = s;
    out[RIoff + (long long)j*4096 + row] = s;
  }
}

// ===========================================================================
extern "C" void kernel_launch(void* const* d_in, const int* in_sizes, int n_in,
                              void* d_out, int out_size, void* d_ws, size_t ws_size,
                              hipStream_t stream){
  const float* x1 = (const float*)d_in[0];
  const float* x2 = (const float*)d_in[1];
  float* out = (float*)d_out;
  float* ws = (float*)d_ws;
  (void)in_sizes; (void)n_in; (void)out_size; (void)ws_size;

  hipMemsetAsync(ws + ZERO_BASE, 0, ZERO_FLOATS*sizeof(float), stream);

  k_had<<<dim3(1024), 256, 0, stream>>>(x1, x2, out, ws);
  k_red<<<dim3(8, 2), 1024, 0, stream>>>(ws);
  k_wselect<<<dim3(2), 256, 0, stream>>>(ws);
  k_fine<<<dim3(1024, 2), 256, 0, stream>>>(x1, x2, ws);
  k_fine_sel<<<dim3(2), 256, 0, stream>>>(ws, out);
  // fallback chain (all early-exit when speculation valid)
  k_hist_fb<<<dim3(512), 256, 0, stream>>>(x1, x2, ws);
  k_coarse_red<<<dim3(16, 2), 256, 0, stream>>>(ws);
  k_coarse_scan<<<dim3(2), 256, 0, stream>>>(ws);
  k_fine_fb<<<dim3(1024, 2), 256, 0, stream>>>(x1, x2, ws);
  k_seg_sum<<<dim3(1024, 2), 256, 0, stream>>>(ws);
  k_fine_scan2<<<dim3(2), 256, 0, stream>>>(ws, out);

  uint32_t a0, a1, b0, b1;
  h_threefry(0u, 42u, 0u, 0u, a0, a1);
  h_threefry(0u, 42u, 0u, 1u, b0, b1);
  k_omega<<<dim3(256, 2), 256, 0, stream>>>(a0, a1, b0, b1, ws);

  // QR1
  k_atype<<<dim3(512, 2), 256, 0, stream>>>(x1, x2, ws, OFF_OMT);
  k_gramP<<<dim3(64, 2), 256, 0, stream>>>(ws, OFF_BIGY, 131072);
  k_tiny<<<dim3(2), 64, 0, stream>>>(ws, OFF_BIGY, 131072);
  k_applyq<<<dim3(32, 2), 256, 0, stream>>>(ws, OFF_BIGY, 131072, OFF_BIGQ, 131072, 8192, 1, 0);
  // QR2
  k_btype<<<dim3(256, 2), 256, 0, stream>>>(x1, x2, ws);
  k_bredgram<<<dim3(64, 2), 256, 0, stream>>>(ws);
  k_tiny<<<dim3(2), 64, 0, stream>>>(ws, OFF_TMAT, 65536);
  k_applyq<<<dim3(16, 2), 256, 0, stream>>>(ws, OFF_TMAT, 65536, OFF_ZT, 65536, 4096, 0, 1);
  // QR3
  k_atype<<<dim3(512, 2), 256, 0, stream>>>(x1, x2, ws, OFF_ZT);
  k_gramP<<<dim3(64, 2), 256, 0, stream>>>(ws, OFF_BIGY, 131072);
  k_tiny<<<dim3(2), 64, 0, stream>>>(ws, OFF_BIGY, 131072);
  k_applyq<<<dim3(32, 2), 256, 0, stream>>>(ws, OFF_BIGY, 131072, OFF_BIGQ, 131072, 8192, 1, 0);
  // QR4
  k_btype<<<dim3(256, 2), 256, 0, stream>>>(x1, x2, ws);
  k_bredgram<<<dim3(64, 2), 256, 0, stream>>>(ws);
  k_tiny<<<dim3(2), 64, 0, stream>>>(ws, OFF_TMAT, 65536);
  k_applyq<<<dim3(16, 2), 256, 0, stream>>>(ws, OFF_TMAT, 65536, OFF_ZT, 65536, 4096, 0, 1);
  // QR5
  k_atype<<<dim3(512, 2), 256, 0, stream>>>(x1, x2, ws, OFF_ZT);
  k_gramP<<<dim3(64, 2), 256, 0, stream>>>(ws, OFF_BIGY, 131072);
  k_tiny<<<dim3(2), 64, 0, stream>>>(ws, OFF_BIGY, 131072);
  k_applyq<<<dim3(32, 2), 256, 0, stream>>>(ws, OFF_BIGY, 131072, OFF_BIGQ, 131072, 8192, 1, 0);
  // QR6
  k_btype<<<dim3(256, 2), 256, 0, stream>>>(x1, x2, ws);
  k_bredgram<<<dim3(64, 2), 256, 0, stream>>>(ws);
  k_tiny<<<dim3(2), 64, 0, stream>>>(ws, OFF_TMAT, 65536);
  k_applyq<<<dim3(16, 2), 256, 0, stream>>>(ws, OFF_TMAT, 65536, OFF_QQR, 65536, 4096, 1, 0);

  k_chain<<<dim3(2), 64, 0, stream>>>(ws);
  k_rout<<<dim3(16, 2), 256, 0, stream>>>(ws, out);
}

// Round 4
// 1610.615 us; speedup vs baseline: 1.1510x; 1.0204x over previous
//
#include <hip/hip_runtime.h>
#include <cstdint>
#include <cstddef>

// ============================================================================
// EfficientMemoryHadamard — round 7.
//  R6 post-mortem: k_chain 307->231 via fast rcp/sqrt, still latency-bound:
//  exec-masked full-width sweeps + 16-deep dynamic-index select chains.
//  R7: (a) readfirstlane-hoisted scalar branches in bdsqr (skip out-of-range
//  sweep bodies), bitmask+clz split-scan, cached boundary accesses — all
//  iteration-path-preserving. (b) collapse 6 dead fallback launches into one
//  2-block k_fallback.
// Verified assumption stack (rounds 1-6 PASSED, absmax 0.1245117):
//  A1: jax threefry_partitionable; A2: quantile = order stat 33218888;
//  A3: gesdd tail gelqf->gebd2->bdsqr->ormbr; A4: LAPACK>=3.10 slartg.
// ============================================================================

#define DEV __device__ __forceinline__

typedef float nfloat4 __attribute__((ext_vector_type(4)));

constexpr long long NTOT = 33554432LL;
constexpr unsigned long long KSEL = 33218888ULL;
constexpr uint32_t WLO = 0x40100000u;   // |x| = 2.25; window [2.25, 2.75)

constexpr long long OUT_T1  = 33554432LL;
constexpr long long OUT_R1  = 33554433LL;
constexpr long long OUT_RI1 = 33619969LL;
constexpr long long OUT_T2  = 33685505LL;
constexpr long long OUT_R2  = 33685506LL;
constexpr long long OUT_RI2 = 33751042LL;

// ---- workspace layout (float units) ----
constexpr size_t OFF_WPART  = 0;         // 1024 blocks x 4096 u32 partials = 16MB
constexpr size_t OFF_BPART  = 0;         // alias: 2*16*65536 floats (after quantile)
constexpr size_t OFF_FB     = 4194304;   // 2 x 1M u32 fallback fine hist (zeroed)
constexpr size_t OFF_CNT    = 6291456;   // 2 u32 below-window counters (zeroed)
constexpr size_t OFF_GF     = 6291472;   // 2*1024 u32 fine window hist (zeroed)
constexpr size_t ZERO_BASE  = OFF_FB;    // memset [OFF_FB, OFF_GF+2048)
constexpr size_t ZERO_FLOATS= 2099216;
constexpr size_t OFF_COARSE = 8388608;   // 2*2048 u32 window hist
constexpr size_t OFF_SEGS   = 8392704;   // 2*1024 u32 (unused, kept for layout)
constexpr size_t OFF_SELR   = 8394752;   // 2*4 ints (bin, rank, valid)
constexpr size_t OFF_TSEL   = 8394768;   // 2 floats (+pad)
constexpr size_t OFF_OMT    = 8394784;   // 2*65536
constexpr size_t OFF_BIGY   = 8525856;   // 2*131072
constexpr size_t OFF_BIGQ   = 8788000;   // 2*131072
constexpr size_t OFF_ZT     = 9050144;   // 2*65536
constexpr size_t OFF_QQR    = 9181216;   // 2*65536
constexpr size_t OFF_TMAT   = 9312288;   // 2*65536
constexpr size_t OFF_GRAMP  = 9443360;   // 2*64*256
constexpr size_t OFF_S      = 9476128;   // 2*256
constexpr size_t OFF_QTOP   = 9476640;   // 2*256
constexpr size_t OFF_RG     = 9477152;   // 2*256
constexpr size_t OFF_VTL    = 9477664;   // 2*256
// total 9478176 floats ~= 37.9 MB (unchanged)

// ---------------------------------------------------------------------------
// fast scalar ops for the serial (latency-bound) tiny kernels only
DEV float frcp_(float x){ return __builtin_amdgcn_rcpf(x); }
DEV float fdivf_(float a, float b){ return a * __builtin_amdgcn_rcpf(b); }
DEV float fsqrtf_(float x){ return __builtin_amdgcn_sqrtf(x); }
DEV int rfl(int x){ return __builtin_amdgcn_readfirstlane(x); }
DEV uint32_t rflu(uint32_t x){ return (uint32_t)__builtin_amdgcn_readfirstlane((int)x); }

// ---------------------------------------------------------------------------
#define TFR(a,b,r) { a += b; b = (b << r) | (b >> (32 - r)); b ^= a; }

DEV void d_threefry(uint32_t k0, uint32_t k1, uint32_t x0, uint32_t x1,
                    uint32_t& o0, uint32_t& o1){
  uint32_t ks2 = k0 ^ k1 ^ 0x1BD11BDAu;
  x0 += k0; x1 += k1;
  TFR(x0,x1,13) TFR(x0,x1,15) TFR(x0,x1,26) TFR(x0,x1,6)
  x0 += k1; x1 += ks2 + 1u;
  TFR(x0,x1,17) TFR(x0,x1,29) TFR(x0,x1,16) TFR(x0,x1,24)
  x0 += ks2; x1 += k0 + 2u;
  TFR(x0,x1,13) TFR(x0,x1,15) TFR(x0,x1,26) TFR(x0,x1,6)
  x0 += k0; x1 += k1 + 3u;
  TFR(x0,x1,17) TFR(x0,x1,29) TFR(x0,x1,16) TFR(x0,x1,24)
  x0 += k1; x1 += ks2 + 4u;
  TFR(x0,x1,13) TFR(x0,x1,15) TFR(x0,x1,26) TFR(x0,x1,6)
  x0 += ks2; x1 += k0 + 5u;
  o0 = x0; o1 = x1;
}

static void h_threefry(uint32_t k0, uint32_t k1, uint32_t x0, uint32_t x1,
                       uint32_t& o0, uint32_t& o1){
  uint32_t ks2 = k0 ^ k1 ^ 0x1BD11BDAu;
  x0 += k0; x1 += k1;
  TFR(x0,x1,13) TFR(x0,x1,15) TFR(x0,x1,26) TFR(x0,x1,6)
  x0 += k1; x1 += ks2 + 1u;
  TFR(x0,x1,17) TFR(x0,x1,29) TFR(x0,x1,16) TFR(x0,x1,24)
  x0 += ks2; x1 += k0 + 2u;
  TFR(x0,x1,13) TFR(x0,x1,15) TFR(x0,x1,26) TFR(x0,x1,6)
  x0 += k0; x1 += k1 + 3u;
  TFR(x0,x1,17) TFR(x0,x1,29) TFR(x0,x1,16) TFR(x0,x1,24)
  x0 += k1; x1 += ks2 + 4u;
  TFR(x0,x1,13) TFR(x0,x1,15) TFR(x0,x1,26) TFR(x0,x1,6)
  x0 += ks2; x1 += k0 + 5u;
  o0 = x0; o1 = x1;
}

DEV float erfinv_f32(float x){
  float w = -log1pf(-x*x);
  float p;
  if (w < 5.0f){
    w -= 2.5f;
    p = 2.81022636e-08f;
    p = fmaf(p, w, 3.43273939e-07f);
    p = fmaf(p, w, -3.5233877e-06f);
    p = fmaf(p, w, -4.39150654e-06f);
    p = fmaf(p, w, 0.00021858087f);
    p = fmaf(p, w, -0.00125372503f);
    p = fmaf(p, w, -0.00417768164f);
    p = fmaf(p, w, 0.246640727f);
    p = fmaf(p, w, 1.50140941f);
  } else {
    w = sqrtf(w) - 3.0f;
    p = -0.000200214257f;
    p = fmaf(p, w, 0.000100950558f);
    p = fmaf(p, w, 0.00134934322f);
    p = fmaf(p, w, -0.00367342844f);
    p = fmaf(p, w, 0.00573950773f);
    p = fmaf(p, w, -0.0076224613f);
    p = fmaf(p, w, 0.00943887047f);
    p = fmaf(p, w, 1.00167406f);
    p = fmaf(p, w, 2.83297682f);
  }
  return p * x;
}

// fast lapy2 — only used by serial tiny kernels (k_tiny / k_chain)
DEV float lapy2f(float x, float y){
  float xa = fabsf(x), ya = fabsf(y);
  float w = fmaxf(xa, ya), z = fminf(xa, ya);
  if (z == 0.f) return w;
  float q = z * frcp_(w);
  return w * fsqrtf_(1.f + q*q);
}

DEV void slartg_(float f, float g, float& c, float& s, float& r){
  if (g == 0.f){ c = 1.f; s = 0.f; r = f; }
  else if (f == 0.f){ c = 0.f; s = copysignf(1.f, g); r = fabsf(g); }
  else {
    float d = fsqrtf_(f*f + g*g);
    float rd = frcp_(d);
    c = fabsf(f) * rd;
    r = copysignf(d, f);
    s = g * copysignf(rd, f);   // == g / copysign(d, f)
  }
}

DEV void slas2_(float f, float g, float h, float& ssmin, float& ssmax){
  float fa = fabsf(f), ga = fabsf(g), ha = fabsf(h);
  float fhmn = fminf(fa, ha), fhmx = fmaxf(fa, ha);
  if (fhmn == 0.f){
    ssmin = 0.f;
    if (fhmx == 0.f) ssmax = ga;
    else {
      float mx = fmaxf(fhmx, ga), mn = fminf(fhmx, ga);
      float q = mn * frcp_(mx);
      ssmax = mx*fsqrtf_(1.f + q*q);
    }
  } else {
    if (ga < fhmx){
      float rmx = frcp_(fhmx);
      float as_ = 1.f + fhmn*rmx;
      float at_ = (fhmx - fhmn)*rmx;
      float au = ga*rmx; au = au*au;
      float cc = 2.f * frcp_(fsqrtf_(as_*as_ + au) + fsqrtf_(at_*at_ + au));
      ssmin = fhmn*cc; ssmax = fhmx*frcp_(cc);
    } else {
      float au = fhmx * frcp_(ga);
      if (au == 0.f){ ssmin = (fhmn*fhmx)*frcp_(ga); ssmax = ga; }
      else {
        float rmx = frcp_(fhmx);
        float as_ = 1.f + fhmn*rmx;
        float at_ = (fhmx - fhmn)*rmx;
        float q1 = as_*au, q2 = at_*au;
        float cc = frcp_(fsqrtf_(1.f + q1*q1) + fsqrtf_(1.f + q2*q2));
        ssmin = (fhmn*cc)*au; ssmin = ssmin + ssmin;
        ssmax = ga*frcp_(cc + cc);
      }
    }
  }
}

DEV void slasv2_(float f, float g, float h, float& ssmin, float& ssmax,
                 float& snr, float& csr, float& snl, float& csl){
  const float eps = 5.9604645e-08f;
  float ft = f, fa = fabsf(f), ht = h, ha = fabsf(h);
  int pmax = 1;
  bool swp = (ha > fa);
  if (swp){ pmax = 3; float t; t=ft; ft=ht; ht=t; t=fa; fa=ha; ha=t; }
  float gt = g, ga = fabsf(g);
  float clt = 0.f, crt = 0.f, slt = 0.f, srt = 0.f;
  if (ga == 0.f){ ssmin = ha; ssmax = fa; clt = 1.f; crt = 1.f; slt = 0.f; srt = 0.f; }
  else {
    bool gasmal = true;
    if (ga > fa){
      pmax = 2;
      if ((fa*frcp_(ga)) < eps){
        gasmal = false;
        ssmax = ga;
        if (ha > 1.f) ssmin = fa*frcp_(ga*frcp_(ha)); else ssmin = (fa*frcp_(ga))*ha;
        clt = 1.f; slt = ht*frcp_(gt); srt = 1.f; crt = ft*frcp_(gt);
      }
    }
    if (gasmal){
      float dd = fa - ha;
      float rfa = frcp_(fa);
      float L = (dd == fa) ? 1.f : dd*rfa;
      float Mv = gt*frcp_(ft);
      float T = 2.f - L;
      float MM = Mv*Mv, TT = T*T;
      float Sv = fsqrtf_(TT + MM);
      float Rv = (L == 0.f) ? fabsf(Mv) : fsqrtf_(L*L + MM);
      float Av = 0.5f*(Sv + Rv);
      float rAv = frcp_(Av);
      ssmin = ha*rAv; ssmax = fa*Av;
      float Tv;
      if (MM == 0.f){
        if (L == 0.f) Tv = copysignf(2.f, ft)*copysignf(1.f, gt);
        else Tv = gt*frcp_(copysignf(dd, ft)) + Mv*frcp_(T);
      } else {
        Tv = (Mv*frcp_(Sv + T) + Mv*frcp_(Rv + L))*(1.f + Av);
      }
      float Lv = fsqrtf_(Tv*Tv + 4.f);
      float rLv = frcp_(Lv);
      crt = 2.f*rLv; srt = Tv*rLv;
      clt = (crt + srt*Mv)*rAv;
      slt = (ht*frcp_(ft))*srt*rAv;
    }
  }
  if (swp){ csl = srt; snl = crt; csr = slt; snr = clt; }
  else    { csl = clt; snl = slt; csr = crt; snr = srt; }
  float tsign = 1.f;
  if (pmax == 1) tsign = copysignf(1.f, csr)*copysignf(1.f, csl)*copysignf(1.f, f);
  if (pmax == 2) tsign = copysignf(1.f, snr)*copysignf(1.f, csl)*copysignf(1.f, g);
  if (pmax == 3) tsign = copysignf(1.f, snr)*copysignf(1.f, snl)*copysignf(1.f, h);
  ssmax = copysignf(ssmax, tsign);
  ssmin = copysignf(ssmin, tsign*copysignf(1.f, f)*copysignf(1.f, h));
}

// ===========================================================================
// K1: hadamard + 2048-bin LDS window hist (dd>>10) + per-block partial
// flush + register below-window counters. NO per-element global atomics.
// ===========================================================================
__global__ __launch_bounds__(256) void k_had(const float* __restrict__ x1,
    const float* __restrict__ x2, float* __restrict__ out, float* __restrict__ ws){
  __shared__ uint32_t wh[2][2048];
  for (int i = threadIdx.x; i < 4096; i += 256) (&wh[0][0])[i] = 0u;
  __syncthreads();
  uint32_t* cnt = (uint32_t*)(ws + OFF_CNT);
  const float4* a4 = (const float4*)x1;
  const float4* b4 = (const float4*)x2;
  nfloat4* o4 = (nfloat4*)out;
  uint32_t cb1 = 0, cb2 = 0;
  long long n4 = NTOT/4;
  long long stride = (long long)gridDim.x * 256;
  for (long long i = (long long)blockIdx.x*256 + threadIdx.x; i < n4; i += stride){
    float4 a = a4[i], b = b4[i];
    nfloat4 o;
    o.x = a.x*b.x; o.y = a.y*b.y; o.z = a.z*b.z; o.w = a.w*b.w;
    __builtin_nontemporal_store(o, &o4[i]);
    uint32_t u, dd;
    u = __float_as_uint(a.x)&0x7fffffffu; cb1 += (u < WLO); dd = u - WLO;
    if (dd < 0x200000u) atomicAdd(&wh[0][dd>>10], 1u);
    u = __float_as_uint(a.y)&0x7fffffffu; cb1 += (u < WLO); dd = u - WLO;
    if (dd < 0x200000u) atomicAdd(&wh[0][dd>>10], 1u);
    u = __float_as_uint(a.z)&0x7fffffffu; cb1 += (u < WLO); dd = u - WLO;
    if (dd < 0x200000u) atomicAdd(&wh[0][dd>>10], 1u);
    u = __float_as_uint(a.w)&0x7fffffffu; cb1 += (u < WLO); dd = u - WLO;
    if (dd < 0x200000u) atomicAdd(&wh[0][dd>>10], 1u);
    u = __float_as_uint(b.x)&0x7fffffffu; cb2 += (u < WLO); dd = u - WLO;
    if (dd < 0x200000u) atomicAdd(&wh[1][dd>>10], 1u);
    u = __float_as_uint(b.y)&0x7fffffffu; cb2 += (u < WLO); dd = u - WLO;
    if (dd < 0x200000u) atomicAdd(&wh[1][dd>>10], 1u);
    u = __float_as_uint(b.z)&0x7fffffffu; cb2 += (u < WLO); dd = u - WLO;
    if (dd < 0x200000u) atomicAdd(&wh[1][dd>>10], 1u);
    u = __float_as_uint(b.w)&0x7fffffffu; cb2 += (u < WLO); dd = u - WLO;
    if (dd < 0x200000u) atomicAdd(&wh[1][dd>>10], 1u);
  }
  __syncthreads();
  uint32_t* wp = (uint32_t*)(ws + OFF_WPART) + (size_t)blockIdx.x*4096;
  for (int i = threadIdx.x; i < 4096; i += 256) wp[i] = (&wh[0][0])[i];
  #pragma unroll
  for (int off = 32; off > 0; off >>= 1){
    cb1 += __shfl_xor(cb1, off, 64);
    cb2 += __shfl_xor(cb2, off, 64);
  }
  if ((threadIdx.x & 63) == 0){
    atomicAdd(&cnt[0], cb1);
    atomicAdd(&cnt[1], cb2);
  }
}

// K1b: reduce 1024 partial window hists -> H[ty][2048] at OFF_COARSE.
__global__ __launch_bounds__(1024) void k_red(float* __restrict__ ws){
  int ty = blockIdx.y;
  const uint32_t* wp = (const uint32_t*)(ws + OFF_WPART);
  uint32_t* H = (uint32_t*)(ws + OFF_COARSE) + ty*2048;
  int t = threadIdx.x;
  int bin = blockIdx.x*256 + (t & 255);
  int pq = t >> 8;   // 0..3
  uint32_t s = 0;
  for (int p = pq*256; p < pq*256 + 256; p++)
    s += wp[(size_t)p*4096 + (size_t)ty*2048 + bin];
  __shared__ uint32_t sh[1024];
  sh[t] = s;
  __syncthreads();
  if (t < 256) H[bin] = sh[t] + sh[t+256] + sh[t+512] + sh[t+768];
}

// K1c: scan window hist, locate sub-bin (1024 fine values) + rank within it.
__global__ __launch_bounds__(256) void k_wselect(float* __restrict__ ws){
  int ty = blockIdx.x;
  const uint32_t* H = (const uint32_t*)(ws + OFF_COARSE) + ty*2048;
  const uint32_t* cnt = (const uint32_t*)(ws + OFF_CNT);
  int* selr = (int*)(ws + OFF_SELR) + ty*4;
  __shared__ unsigned long long ps[256];
  unsigned long long s = 0;
  for (int j = 0; j < 8; j++) s += H[threadIdx.x*8 + j];
  ps[threadIdx.x] = s;
  __syncthreads();
  if (threadIdx.x == 0){
    unsigned long long K = KSEL, cum = cnt[ty];
    int valid = 0, sbin = 0, rank = 0;
    if (K >= cum){
      int g = 0;
      for (; g < 256; g++){ if (cum + ps[g] > K) break; cum += ps[g]; }
      if (g < 256){
        for (int j = 0; j < 8; j++){
          uint32_t c = H[g*8 + j];
          if (cum + c > K){ sbin = g*8 + j; rank = (int)(K - cum); valid = 1; break; }
          cum += c;
        }
      }
    }
    selr[0] = sbin; selr[1] = rank; selr[2] = valid;
  }
}

// K1d: re-stream x, histogram only the selected 1024-value sub-bin (LDS),
// flush ~650 nonzero bins total via global atomics.
__global__ __launch_bounds__(256) void k_fine(const float* __restrict__ x1,
    const float* __restrict__ x2, float* __restrict__ ws){
  int ty = blockIdx.y;
  const int* selr = (const int*)(ws + OFF_SELR) + ty*4;
  if (!selr[2]) return;
  uint32_t g = (uint32_t)selr[0];
  __shared__ uint32_t lh[1024];
  for (int i = threadIdx.x; i < 1024; i += 256) lh[i] = 0u;
  __syncthreads();
  const float4* x4 = (const float4*)(ty ? x2 : x1);
  long long n4 = NTOT/4;
  long long stride = (long long)gridDim.x * 256;
  for (long long i = (long long)blockIdx.x*256 + threadIdx.x; i < n4; i += stride){
    float4 a = x4[i];
    uint32_t dd;
    dd = (__float_as_uint(a.x)&0x7fffffffu) - WLO;
    if ((dd>>10) == g) atomicAdd(&lh[dd & 1023u], 1u);
    dd = (__float_as_uint(a.y)&0x7fffffffu) - WLO;
    if ((dd>>10) == g) atomicAdd(&lh[dd & 1023u], 1u);
    dd = (__float_as_uint(a.z)&0x7fffffffu) - WLO;
    if ((dd>>10) == g) atomicAdd(&lh[dd & 1023u], 1u);
    dd = (__float_as_uint(a.w)&0x7fffffffu) - WLO;
    if ((dd>>10) == g) atomicAdd(&lh[dd & 1023u], 1u);
  }
  __syncthreads();
  uint32_t* gf = (uint32_t*)(ws + OFF_GF) + (size_t)ty*1024;
  for (int i = threadIdx.x; i < 1024; i += 256){
    uint32_t v = lh[i];
    if (v) atomicAdd(&gf[i], v);
  }
}

// K1e: scan the 1024-bin fine hist -> exact bit threshold.
__global__ __launch_bounds__(256) void k_fine_sel(float* __restrict__ ws,
    float* __restrict__ out){
  int ty = blockIdx.x;
  const int* selr = (const int*)(ws + OFF_SELR) + ty*4;
  if (!selr[2]) return;
  const uint32_t* gf = (const uint32_t*)(ws + OFF_GF) + (size_t)ty*1024;
  __shared__ uint32_t sh[1024];
  __shared__ uint32_t ps[256];
  int t = threadIdx.x;
  for (int k = 0; k < 4; k++) sh[k*256 + t] = gf[k*256 + t];
  __syncthreads();
  ps[t] = sh[4*t] + sh[4*t+1] + sh[4*t+2] + sh[4*t+3];
  __syncthreads();
  if (t == 0){
    uint32_t K = (uint32_t)selr[1];
    uint32_t cum = 0; int q = 0;
    for (; q < 256; q++){ if (cum + ps[q] > K) break; cum += ps[q]; }
    if (q > 255) q = 255;
    int f = q*4 + 3;
    for (int jj = 0; jj < 4; jj++){
      uint32_t c = sh[q*4 + jj];
      if (cum + c > K){ f = q*4 + jj; break; }
      cum += c;
    }
    uint32_t bits = WLO + (((uint32_t)selr[0]) << 10) + (uint32_t)f;
    float th = __uint_as_float(bits);
    ws[OFF_TSEL + ty] = th;
    out[ty ? OUT_T2 : OUT_T1] = th;
  }
}

// ---------------------------------------------------------------------------
// K1f: single-kernel exact fallback (speculation miss). Early-exits in the
// normal case — only its 2-block dispatch cost matters. Slow but correct:
// full coarse hist (u>>20, 2048 bins) -> scan -> 20-bit fine hist -> scan.
// ---------------------------------------------------------------------------
__global__ __launch_bounds__(256) void k_fallback(const float* __restrict__ x1,
    const float* __restrict__ x2, float* __restrict__ ws, float* __restrict__ out){
  int ty = blockIdx.x;
  const int* selr = (const int*)(ws + OFF_SELR) + ty*4;
  if (selr[2]) return;
  const float4* x4 = (const float4*)(ty ? x2 : x1);
  long long n4 = NTOT/4;
  __shared__ uint32_t lh[2048];
  for (int i = threadIdx.x; i < 2048; i += 256) lh[i] = 0u;
  __syncthreads();
  for (long long i = threadIdx.x; i < n4; i += 256){
    float4 a = x4[i];
    atomicAdd(&lh[(__float_as_uint(a.x)&0x7fffffffu)>>20], 1u);
    atomicAdd(&lh[(__float_as_uint(a.y)&0x7fffffffu)>>20], 1u);
    atomicAdd(&lh[(__float_as_uint(a.z)&0x7fffffffu)>>20], 1u);
    atomicAdd(&lh[(__float_as_uint(a.w)&0x7fffffffu)>>20], 1u);
  }
  __syncthreads();
  __shared__ unsigned long long ps[256];
  {
    unsigned long long s = 0;
    for (int j = 0; j < 8; j++) s += lh[threadIdx.x*8 + j];
    ps[threadIdx.x] = s;
  }
  __syncthreads();
  __shared__ int sbin; __shared__ uint32_t srank;
  if (threadIdx.x == 0){
    unsigned long long cum = 0, K = KSEL;
    int g = 0;
    for (; g < 256; g++){ if (cum + ps[g] > K) break; cum += ps[g]; }
    if (g > 255) g = 255;
    int bin = 2047;
    for (int j = 0; j < 8; j++){
      uint32_t c = lh[g*8 + j];
      if (cum + c > K){ bin = g*8 + j; break; }
      cum += c;
    }
    sbin = bin; srank = (uint32_t)(K - cum);
  }
  __syncthreads();
  uint32_t bin = (uint32_t)sbin;
  uint32_t* f = (uint32_t*)(ws + OFF_FB) + ((size_t)ty<<20);
  for (long long i = threadIdx.x; i < n4; i += 256){
    float4 a = x4[i];
    uint32_t u;
    u = __float_as_uint(a.x)&0x7fffffffu; if ((u>>20)==bin) atomicAdd(&f[u&0xFFFFFu],1u);
    u = __float_as_uint(a.y)&0x7fffffffu; if ((u>>20)==bin) atomicAdd(&f[u&0xFFFFFu],1u);
    u = __float_as_uint(a.z)&0x7fffffffu; if ((u>>20)==bin) atomicAdd(&f[u&0xFFFFFu],1u);
    u = __float_as_uint(a.w)&0x7fffffffu; if ((u>>20)==bin) atomicAdd(&f[u&0xFFFFFu],1u);
  }
  __threadfence();
  __syncthreads();
  __shared__ uint32_t segs[1024];
  for (int sgi = threadIdx.x; sgi < 1024; sgi += 256){
    uint32_t ss = 0;
    for (int j = 0; j < 1024; j++) ss += f[(size_t)sgi*1024 + j];
    segs[sgi] = ss;
  }
  __syncthreads();
  if (threadIdx.x == 0){
    uint32_t K = srank, cum = 0;
    int q = 0;
    for (; q < 256; q++){
      uint32_t pq = segs[4*q] + segs[4*q+1] + segs[4*q+2] + segs[4*q+3];
      if (cum + pq > K) break;
      cum += pq;
    }
    if (q > 255) q = 255;
    int g = q*4 + 3;
    for (int j = 0; j < 4; j++){
      uint32_t c = segs[q*4 + j];
      if (cum + c > K){ g = q*4 + j; break; }
      cum += c;
    }
    int jf = 1023;
    for (int j = 0; j < 1024; j++){
      uint32_t c = f[(size_t)g*1024 + j];
      if (cum + c > K){ jf = j; break; }
      cum += c;
    }
    uint32_t bits = (bin<<20) | (uint32_t)((g*1024 + jf) & 0xFFFFF);
    float th = __uint_as_float(bits);
    ws[OFF_TSEL + ty] = th;
    out[ty ? OUT_T2 : OUT_T1] = th;
  }
}

__global__ __launch_bounds__(256) void k_omega(uint32_t a0, uint32_t a1,
    uint32_t b0, uint32_t b1, float* __restrict__ ws){
  int ty = blockIdx.y;
  uint32_t k0 = ty ? b0 : a0, k1 = ty ? b1 : a1;
  int i = blockIdx.x*256 + threadIdx.x;
  uint32_t o0, o1;
  d_threefry(k0, k1, 0u, (uint32_t)i, o0, o1);
  uint32_t bits = o0 ^ o1;
  float fr = __uint_as_float((bits >> 9) | 0x3f800000u) - 1.0f;
  const float lo = -0.99999994f;
  float u = fr * 2.0f + lo;
  u = fmaxf(lo, u);
  float v = 1.41421356237f * erfinv_f32(u);
  int row = i >> 4, col = i & 15;
  ws[OFF_OMT + (size_t)ty*65536 + (size_t)col*4096 + row] = v;
}

// K6: Y(8192x16) = residual(x) * W  (W^T 16x4096 in ws)
__global__ __launch_bounds__(256) void k_atype(const float* __restrict__ x1,
    const float* __restrict__ x2, float* __restrict__ ws, size_t wtOff){
  int ty = blockIdx.y;
  const float* x = ty ? x2 : x1;
  const float* wt = ws + wtOff + (size_t)ty*65536;
  float* Y = ws + OFF_BIGY + (size_t)ty*131072;
  float t = ws[OFF_TSEL + ty];
  int wave = threadIdx.x >> 6, lane = threadIdx.x & 63;
  __shared__ __align__(16) float wts[16][256];
  __shared__ float outs[16][16];
  float acc[4][16];
  #pragma unroll
  for (int r = 0; r < 4; r++)
    #pragma unroll
    for (int j = 0; j < 16; j++) acc[r][j] = 0.f;
  int rowbase = blockIdx.x*16 + wave*4;
  for (int c = 0; c < 4096; c += 256){
    __syncthreads();
    for (int idx = threadIdx.x; idx < 16*64; idx += 256){
      int j = idx >> 6, q = idx & 63;
      ((float4*)&wts[j][0])[q] = ((const float4*)(wt + (size_t)j*4096 + c))[q];
    }
    __syncthreads();
    float4 xv[4];
    #pragma unroll
    for (int rr = 0; rr < 4; rr++){
      int row = rowbase + rr;
      float4 a = ((const float4*)(x + (size_t)row*4096 + c))[lane];
      a.x = fabsf(a.x) > t ? 0.f : a.x;
      a.y = fabsf(a.y) > t ? 0.f : a.y;
      a.z = fabsf(a.z) > t ? 0.f : a.z;
      a.w = fabsf(a.w) > t ? 0.f : a.w;
      xv[rr] = a;
    }
    #pragma unroll
    for (int j = 0; j < 16; j++){
      float4 w4 = ((const float4*)&wts[j][0])[lane];
      #pragma unroll
      for (int rr = 0; rr < 4; rr++){
        acc[rr][j] = fmaf(xv[rr].x, w4.x, acc[rr][j]);
        acc[rr][j] = fmaf(xv[rr].y, w4.y, acc[rr][j]);
        acc[rr][j] = fmaf(xv[rr].z, w4.z, acc[rr][j]);
        acc[rr][j] = fmaf(xv[rr].w, w4.w, acc[rr][j]);
      }
    }
  }
  #pragma unroll
  for (int rr = 0; rr < 4; rr++)
    for (int j = 0; j < 16; j++){
      float v = acc[rr][j];
      for (int off = 32; off > 0; off >>= 1) v += __shfl_xor(v, off, 64);
      if (lane == 0) outs[wave*4 + rr][j] = v;
    }
  __syncthreads();
  int r = threadIdx.x >> 4, cc = threadIdx.x & 15;
  Y[(size_t)(blockIdx.x*16 + r)*16 + cc] = outs[r][cc];
}

__global__ __launch_bounds__(256) void k_gramP(float* __restrict__ ws, size_t mOff,
    size_t mStr){
  int ty = blockIdx.y;
  const float* M = ws + mOff + (size_t)ty*mStr;
  float* gp = ws + OFF_GRAMP + (size_t)(ty*64 + blockIdx.x)*256;
  __shared__ __align__(16) float buf[128][16];
  int t = threadIdx.x;
  for (int q = t; q < 512; q += 256)
    ((float4*)&buf[0][0])[q] = ((const float4*)(M + (size_t)blockIdx.x*2048))[q];
  __syncthreads();
  int i = t >> 4, j = t & 15;
  float s = 0.f;
  int rstart = (blockIdx.x == 0) ? 16 : 0;
  for (int r = rstart; r < 128; r++) s += buf[r][i]*buf[r][j];
  gp[t] = s;
}

__global__ __launch_bounds__(256) void k_btype(const float* __restrict__ x1,
    const float* __restrict__ x2, float* __restrict__ ws){
  int ty = blockIdx.y;
  const float* x = ty ? x2 : x1;
  const float* Q = ws + OFF_BIGQ + (size_t)ty*131072;
  float t = ws[OFF_TSEL + ty];
  int cb = blockIdx.x & 15;
  int rc = blockIdx.x >> 4;
  int c = cb*256 + threadIdx.x;
  int r0 = rc*512;
  __shared__ __align__(16) float Qs[64][16];
  float acc[16];
  #pragma unroll
  for (int j = 0; j < 16; j++) acc[j] = 0.f;
  for (int tile = 0; tile < 8; tile++){
    __syncthreads();
    ((float4*)&Qs[0][0])[threadIdx.x] =
        ((const float4*)(Q + (size_t)(r0 + tile*64)*16))[threadIdx.x];
    __syncthreads();
    const float* xp = x + (size_t)(r0 + tile*64)*4096 + c;
    #pragma unroll 4
    for (int rr = 0; rr < 64; rr++){
      float v = xp[(size_t)rr*4096];
      v = fabsf(v) > t ? 0.f : v;
      float4 qa = ((const float4*)&Qs[rr][0])[0];
      float4 qb = ((const float4*)&Qs[rr][0])[1];
      float4 qc = ((const float4*)&Qs[rr][0])[2];
      float4 qd = ((const float4*)&Qs[rr][0])[3];
      acc[ 0] = fmaf(v, qa.x, acc[ 0]);
      acc[ 1] = fmaf(v, qa.y, acc[ 1]);
      acc[ 2] = fmaf(v, qa.z, acc[ 2]);
      acc[ 3] = fmaf(v, qa.w, acc[ 3]);
      acc[ 4] = fmaf(v, qb.x, acc[ 4]);
      acc[ 5] = fmaf(v, qb.y, acc[ 5]);
      acc[ 6] = fmaf(v, qb.z, acc[ 6]);
      acc[ 7] = fmaf(v, qb.w, acc[ 7]);
      acc[ 8] = fmaf(v, qc.x, acc[ 8]);
      acc[ 9] = fmaf(v, qc.y, acc[ 9]);
      acc[10] = fmaf(v, qc.z, acc[10]);
      acc[11] = fmaf(v, qc.w, acc[11]);
      acc[12] = fmaf(v, qd.x, acc[12]);
      acc[13] = fmaf(v, qd.y, acc[13]);
      acc[14] = fmaf(v, qd.z, acc[14]);
      acc[15] = fmaf(v, qd.w, acc[15]);
    }
  }
  float* BP = ws + OFF_BPART + (((size_t)(ty*16 + rc))<<16) + (size_t)c*16;
  #pragma unroll
  for (int q = 0; q < 4; q++){
    float4 o; o.x = acc[q*4]; o.y = acc[q*4+1]; o.z = acc[q*4+2]; o.w = acc[q*4+3];
    ((float4*)BP)[q] = o;
  }
}

__global__ __launch_bounds__(256) void k_bredgram(float* __restrict__ ws){
  int ty = blockIdx.y;
  const float* BP = ws + OFF_BPART + (((size_t)ty*16)<<16);
  float* T = ws + OFF_TMAT + (size_t)ty*65536;
  float* gp = ws + OFF_GRAMP + (size_t)(ty*64 + blockIdx.x)*256;
  __shared__ float sh[64][16];
  int t = threadIdx.x;
  for (int k = 0; k < 4; k++){
    int e = blockIdx.x*1024 + k*256 + t;
    float s = 0.f;
    #pragma unroll
    for (int rc = 0; rc < 16; rc++) s += BP[((size_t)rc<<16) + e];
    T[e] = s;
    int le = k*256 + t;
    sh[le >> 4][le & 15] = s;
  }
  __syncthreads();
  int i = t >> 4, j = t & 15;
  float s = 0.f;
  int rstart = (blockIdx.x == 0) ? 16 : 0;
  for (int r = rstart; r < 64; r++) s += sh[r][i]*sh[r][j];
  gp[t] = s;
}

// K9: register-resident tiny QR: gram-sum, chol (LDS), geqrf+org2r (regs),
//     back-solve. Lane j<16 holds column j.  (fast rcp/sqrt)
__global__ __launch_bounds__(64) void k_tiny(float* __restrict__ ws, size_t mOff,
    size_t mStr){
  int ty = blockIdx.x;
  const float* Mp = ws + mOff + (size_t)ty*mStr;
  float* sOut = ws + OFF_S + ty*256;
  float* qtOut = ws + OFF_QTOP + ty*256;
  float* rgOut = ws + OFF_RG + ty*256;
  __shared__ float G[16][16];
  __shared__ float Cld[32][16];
  __shared__ float bc[4];
  __shared__ float tau[16];
  int l = threadIdx.x;
  int j = l & 15;
  for (int e = l; e < 256; e += 64){
    const float* gp = ws + OFF_GRAMP + (size_t)ty*16384 + e;
    float s = 0.f;
    for (int p = 0; p < 64; p++) s += gp[(size_t)p*256];
    G[e>>4][e&15] = s;
  }
  for (int idx = l; idx < 256; idx += 64)
    Cld[idx>>4][idx&15] = Mp[idx];
  __syncthreads();
  // cholesky (upper) in place — fast rcp/sqrt
  for (int k = 0; k < 16; k++){
    float dk = fsqrtf_(G[k][k]);
    float rdk = frcp_(dk);
    if (l == k) G[k][k] = dk;
    else if (l > k && l < 16) G[k][l] = G[k][l] * rdk;
    __syncthreads();
    if (l > k && l < 16)
      for (int jj = l; jj < 16; jj++) G[l][jj] -= G[k][l]*G[k][jj];
    __syncthreads();
  }
  // build column registers: C = [M_top ; R_B]
  float Cc[32];
  #pragma unroll
  for (int r = 0; r < 32; r++){
    if (r < 16) Cc[r] = Cld[r][j];
    else Cc[r] = (j >= r - 16) ? G[r-16][j] : 0.f;
  }
  // geqrf (fast rcp/sqrt, same op order)
  #pragma unroll
  for (int i = 0; i < 16; i++){
    if (l == i){
      float alpha = Cc[i];
      float ssum = 0.f;
      #pragma unroll
      for (int r = i+1; r < 32; r++) ssum += Cc[r]*Cc[r];
      float xn = fsqrtf_(ssum);
      float beta, tv, sc;
      if (xn == 0.f){ tv = 0.f; beta = alpha; sc = 1.f; }
      else {
        beta = -copysignf(lapy2f(alpha, xn), alpha);
        tv = fdivf_(beta - alpha, beta);
        sc = frcp_(alpha - beta);
        #pragma unroll
        for (int r = i+1; r < 32; r++) Cc[r] *= sc;
      }
      Cc[i] = beta;
      bc[0] = beta; bc[1] = tv;
      tau[i] = tv;
      #pragma unroll
      for (int r = i; r < 32; r++) Cld[r][i] = Cc[r];
    }
    __syncthreads();
    float tv = bc[1];
    if (tv != 0.f && l < 16 && j > i){
      float w = Cc[i];
      #pragma unroll
      for (int r = i+1; r < 32; r++) w += Cld[r][i]*Cc[r];
      w *= tv;
      Cc[i] -= w;
      #pragma unroll
      for (int r = i+1; r < 32; r++) Cc[r] -= w*Cld[r][i];
    }
    __syncthreads();
  }
  // org2r (no barriers needed: Cld/tau now read-only)
  float Qc[32];
  #pragma unroll
  for (int r = 0; r < 32; r++) Qc[r] = 0.f;
  #pragma unroll
  for (int i = 15; i >= 0; i--){
    float tv = tau[i];
    if (i < 15 && l < 16 && j > i){
      float w = Qc[i];
      #pragma unroll
      for (int r = i+1; r < 32; r++) w += Cld[r][i]*Qc[r];
      w *= tv;
      Qc[i] -= w;
      #pragma unroll
      for (int r = i+1; r < 32; r++) Qc[r] -= w*Cld[r][i];
    }
    if (l == i){
      #pragma unroll
      for (int r = 0; r < 32; r++){
        if (r < i) Qc[r] = 0.f;
        else if (r == i) Qc[r] = 1.f - tv;
        else Qc[r] = -tv * Cld[r][i];
      }
    }
  }
  // back-solve S = R_B^{-1} * Q_bot
  float Sc[16];
  if (l < 16){
    #pragma unroll
    for (int i2 = 15; i2 >= 0; i2--){
      float v = Qc[16 + i2];
      #pragma unroll
      for (int k2 = i2+1; k2 < 16; k2++) v -= G[i2][k2]*Sc[k2];
      Sc[i2] = v * frcp_(G[i2][i2]);
    }
    #pragma unroll
    for (int r = 0; r < 16; r++){
      rgOut[r*16 + j] = (j >= r) ? Cc[r] : 0.f;
      sOut[r*16 + j] = Sc[r];
      qtOut[r*16 + j] = Qc[r];
    }
  }
}

__global__ __launch_bounds__(256) void k_applyq(float* __restrict__ ws, size_t mOff,
    size_t mStr, size_t oOff, size_t oStr, int nrows, int wN, int wT){
  int ty = blockIdx.y;
  const float* Mp = ws + mOff + (size_t)ty*mStr;
  const float* sP = ws + OFF_S + ty*256;
  const float* qtP = ws + OFF_QTOP + ty*256;
  float* oP = ws + oOff + (size_t)ty*oStr;
  __shared__ float Ss[16][16], Qt[16][16];
  int t = threadIdx.x;
  Ss[t>>4][t&15] = sP[t];
  Qt[t>>4][t&15] = qtP[t];
  __syncthreads();
  int row = blockIdx.x*256 + t;
  if (row >= nrows) return;
  float o[16];
  if (row < 16){
    #pragma unroll
    for (int j = 0; j < 16; j++) o[j] = Qt[row][j];
  } else {
    float mv[16];
    #pragma unroll
    for (int q = 0; q < 4; q++){
      float4 v = ((const float4*)(Mp + (size_t)row*16))[q];
      mv[q*4] = v.x; mv[q*4+1] = v.y; mv[q*4+2] = v.z; mv[q*4+3] = v.w;
    }
    #pragma unroll
    for (int j = 0; j < 16; j++){
      float sacc = 0.f;
      #pragma unroll
      for (int i = 0; i < 16; i++) sacc = fmaf(mv[i], Ss[i][j], sacc);
      o[j] = sacc;
    }
  }
  if (wN){
    #pragma unroll
    for (int q = 0; q < 4; q++){
      float4 v; v.x = o[q*4]; v.y = o[q*4+1]; v.z = o[q*4+2]; v.w = o[q*4+3];
      ((float4*)(oP + (size_t)row*16))[q] = v;
    }
  }
  if (wT){
    #pragma unroll
    for (int j = 0; j < 16; j++) oP[(size_t)j*4096 + row] = o[j];
  }
}

// ===========================================================================
// K11: gesdd tail. gebd2 (LDS) -> bdsqr (REGISTERS, lane=VT column) -> ormbr.
// r7: readfirstlane-scalar control flow + bitmask split-scan + boundary caches.
// Same arithmetic and iteration order as r1-r6.
// ===========================================================================
__global__ __launch_bounds__(64) void k_chain(float* __restrict__ ws){
  int ty = blockIdx.x;
  const float* rg = ws + OFF_RG + ty*256;
  float* vtlOut = ws + OFF_VTL + ty*256;
  const int n = 16;
  __shared__ float A[16][16];
  __shared__ float VTm[16][16];
  __shared__ float d_[16], e_[16], tauq[16], taup[16];
  int l = threadIdx.x;
  for (int idx = l; idx < 256; idx += 64){
    int r = idx >> 4, c = idx & 15;
    A[r][c] = (r >= c) ? rg[c*16 + r] : 0.f;   // L = Rg^T
  }
  __syncthreads();
  // ---- gebd2 (fast rcp/sqrt) ----
  for (int i = 0; i < n; i++){
    {
      float alpha = A[i][i];
      float ssum = 0.f;
      for (int r = i+1; r < n; r++) ssum += A[r][i]*A[r][i];
      float xn = fsqrtf_(ssum);
      float beta, tv;
      if (n - i <= 1 || xn == 0.f){ tv = 0.f; beta = alpha; }
      else {
        beta = -copysignf(lapy2f(alpha, xn), alpha);
        tv = fdivf_(beta - alpha, beta);
        float sc = frcp_(alpha - beta);
        if (l > i && l < n) A[l][i] *= sc;
      }
      if (l == 0){ d_[i] = beta; tauq[i] = tv; }
      __syncthreads();
      if (tv != 0.f && l > i && l < n){
        int jj = l;
        float w = A[i][jj];
        for (int r = i+1; r < n; r++) w += A[r][i]*A[r][jj];
        w *= tv;
        A[i][jj] -= w;
        for (int r = i+1; r < n; r++) A[r][jj] -= w*A[r][i];
      }
      __syncthreads();
    }
    if (i < n-1){
      float alpha = A[i][i+1];
      float ssum = 0.f;
      for (int c = i+2; c < n; c++) ssum += A[i][c]*A[i][c];
      float xn = fsqrtf_(ssum);
      float beta, tp;
      if (n - i - 1 <= 1 || xn == 0.f){ tp = 0.f; beta = alpha; }
      else {
        beta = -copysignf(lapy2f(alpha, xn), alpha);
        tp = fdivf_(beta - alpha, beta);
        float sc = frcp_(alpha - beta);
        if (l >= i+2 && l < n) A[i][l] *= sc;
      }
      if (l == 0){ e_[i] = beta; taup[i] = tp; }
      __syncthreads();
      if (tp != 0.f && l > i && l < n){
        int r = l;
        float w = A[r][i+1];
        for (int c = i+2; c < n; c++) w += A[i][c]*A[r][c];
        w *= tp;
        A[r][i+1] -= w;
        for (int c = i+2; c < n; c++) A[r][c] -= w*A[i][c];
      }
      __syncthreads();
    } else {
      if (l == 0) taup[i] = 0.f;
      __syncthreads();
    }
  }
  // ---- bdsqr: state in registers; control flow readfirstlane-scalar ----
  float D[16], E[16], vt[16];
  #pragma unroll
  for (int k = 0; k < 16; k++){
    D[k] = d_[k];
    E[k] = (k < 15) ? e_[k] : 0.f;
    vt[k] = (k == l) ? 1.f : 0.f;
  }
  auto getD = [&](int i)->float{ float r = D[0];
    #pragma unroll
    for (int k = 1; k < 16; k++) if (i == k) r = D[k];
    return r; };
  auto setD = [&](int i, float v){
    #pragma unroll
    for (int k = 0; k < 16; k++) if (i == k) D[k] = v; };
  auto getE = [&](int i)->float{ float r = E[0];
    #pragma unroll
    for (int k = 1; k < 16; k++) if (i == k) r = E[k];
    return r; };
  auto setE = [&](int i, float v){
    #pragma unroll
    for (int k = 0; k < 16; k++) if (i == k) E[k] = v; };
  auto getVt = [&](int i)->float{ float r = vt[0];
    #pragma unroll
    for (int k = 1; k < 16; k++) if (i == k) r = vt[k];
    return r; };
  auto setVt = [&](int i, float v){
    #pragma unroll
    for (int k = 0; k < 16; k++) if (i == k) vt[k] = v; };

  const float eps = 5.9604645e-08f;
  const float unfl = 1.17549435e-38f;
  const float tol = 10.f*eps;
  float sminoa = fabsf(D[0]);
  if (sminoa != 0.f){
    float mu = sminoa;
    #pragma unroll
    for (int i = 1; i < 16; i++){
      mu = fabsf(D[i])*fdivf_(mu, mu + fabsf(E[i-1]));
      sminoa = fminf(sminoa, mu);
    }
  }
  sminoa = sminoa * 0.25f;   // == / sqrtf(16)
  float thresh = fmaxf(tol*sminoa, (float)(6*n*n)*unfl);
  int maxit = 6*n*n;
  int iter = 0, oldll = -1, oldm = -1, mm = n, idir = 0;
  while (true){
    if (mm <= 1) break;
    if (iter > maxit) break;
    // ---- split scan (bitmask form; identical llv/smaxw semantics) ----
    uint32_t msk = 0u;
    #pragma unroll
    for (int c = 0; c < 15; c++) msk |= (fabsf(E[c]) <= thresh) ? (1u << c) : 0u;
    msk &= (1u << (mm-1)) - 1u;          // keep c <= mm-2  (mm >= 2 here)
    msk = rflu(msk);
    int llv, clow; bool split;
    if (msk){ int cmax = 31 - __clz((int)msk); split = true; llv = cmax + 1; clow = cmax + 1; }
    else    { split = false; llv = 1; clow = 0; }
    float dm1 = getD(mm-1);
    float smaxw = fabsf(dm1);
    #pragma unroll
    for (int c = 0; c < 15; c++)
      if (c >= clow && c <= mm-2) smaxw = fmaxf(smaxw, fmaxf(fabsf(D[c]), fabsf(E[c])));
    if (split){
      setE(llv-1, 0.f);
      if (llv == mm-1){ mm = rfl(mm - 1); continue; }
      llv = llv + 1;
    }
    // boundary caches (no D/E writes between here and the sweeps except
    // deflation-continue paths which re-enter the loop)
    float dm2 = getD(mm-2);
    float e_m2 = getE(mm-2);
    float dll = getD(llv-1);
    float e_ll = getE(llv-1);
    if (llv == mm-1){
      float sigmn, sigmx, sinr, cosr, sinl, cosl;
      slasv2_(dm2, e_m2, dm1, sigmn, sigmx, sinr, cosr, sinl, cosl);
      setD(mm-2, sigmx); setE(mm-2, 0.f); setD(mm-1, sigmn);
      float t1 = getVt(mm-2), t2 = getVt(mm-1);
      setVt(mm-2, cosr*t1 + sinr*t2);
      setVt(mm-1, cosr*t2 - sinr*t1);
      mm = rfl(mm - 2);
      continue;
    }
    if (llv > oldm || mm < oldll)
      idir = (fabsf(dll) >= fabsf(dm1)) ? 1 : 2;
    idir = rfl(idir);
    bool deflated = false;
    float sminl = 0.f;
    if (idir == 1){
      int pc = (fabsf(e_m2) <= tol*fabsf(dm1)) ? 1 : 0;
      if (rfl(pc)){ setE(mm-2, 0.f); continue; }
      float mu = fabsf(dll); sminl = mu;
      #pragma unroll
      for (int c = 0; c < 15; c++){
        if (c >= llv-1 && c <= mm-2 && !deflated){
          if (fabsf(E[c]) <= tol*mu){ E[c] = 0.f; deflated = true; }
          else {
            mu = fabsf(D[c+1])*fdivf_(mu, mu + fabsf(E[c]));
            sminl = fminf(sminl, mu);
          }
        }
      }
    } else {
      int pc = (fabsf(e_ll) <= tol*fabsf(dll)) ? 1 : 0;
      if (rfl(pc)){ setE(llv-1, 0.f); continue; }
      float mu = fabsf(dm1); sminl = mu;
      #pragma unroll
      for (int c = 14; c >= 0; c--){
        if (c >= llv-1 && c <= mm-2 && !deflated){
          if (fabsf(E[c]) <= tol*mu){ E[c] = 0.f; deflated = true; }
          else {
            mu = fabsf(D[c])*fdivf_(mu, mu + fabsf(E[c]));
            sminl = fminf(sminl, mu);
          }
        }
      }
    }
    {
      int dfl = deflated ? 1 : 0;
      if (rfl(dfl)) continue;
    }
    oldll = llv; oldm = mm;
    float shift = 0.f, rdum;
    {
      int nosh = (!((float)n*tol*fdivf_(sminl, smaxw) <= fmaxf(eps, 0.01f*tol))) ? 1 : 0;
      if (rfl(nosh)){
        float sll;
        if (idir == 1){ sll = fabsf(dll); slas2_(dm2, e_m2, dm1, shift, rdum); }
        else          { sll = fabsf(dm1); slas2_(dll, e_ll, getD(llv), shift, rdum); }
        if (sll > 0.f){ float q = fdivf_(shift, sll); if (q*q < eps) shift = 0.f; }
      }
    }
    iter += mm - llv;
    int zsh = (shift == 0.f) ? 1 : 0;
    if (rfl(zsh)){
      if (idir == 1){
        float cs = 1.f, oldcs = 1.f, sn = 0.f, oldsn = 0.f, rr, dnew;
        #pragma unroll
        for (int i0 = 0; i0 < 15; i0++){
          if (i0 >= llv-1 && i0 <= mm-2){
            slartg_(D[i0]*cs, E[i0], cs, sn, rr);
            if (i0 > llv-1) E[i0-1 < 0 ? 0 : i0-1] = oldsn*rr;
            slartg_(oldcs*rr, D[i0+1]*sn, oldcs, oldsn, dnew);
            D[i0] = dnew;
            if (cs != 1.f || sn != 0.f){
              float t1 = vt[i0], t2 = vt[i0+1];
              vt[i0+1] = cs*t2 - sn*t1;
              vt[i0]   = sn*t2 + cs*t1;
            }
          }
        }
        float h = dm1*cs;           // D[mm-1] untouched in this sweep
        setD(mm-1, h*oldcs);
        float hv = h*oldsn;
        setE(mm-2, (fabsf(hv) <= thresh) ? 0.f : hv);
      } else {
        float cs = 1.f, oldcs = 1.f, sn = 0.f, oldsn = 0.f, rr, dnew;
        #pragma unroll
        for (int i0 = 15; i0 >= 1; i0--){
          if (i0 >= llv && i0 <= mm-1){
            slartg_(D[i0]*cs, E[i0-1], cs, sn, rr);
            if (i0 < mm-1) E[i0] = oldsn*rr;
            slartg_(oldcs*rr, D[i0-1]*sn, oldcs, oldsn, dnew);
            D[i0] = dnew;
            float cR = oldcs, sR = -oldsn;
            if (cR != 1.f || sR != 0.f){
              float t1 = vt[i0-1], t2 = vt[i0];
              vt[i0]   = cR*t2 - sR*t1;
              vt[i0-1] = sR*t2 + cR*t1;
            }
          }
        }
        float h = dll*cs;           // D[llv-1] untouched in this sweep
        setD(llv-1, h*oldcs);
        float hv = h*oldsn;
        setE(llv-1, (fabsf(hv) <= thresh) ? 0.f : hv);
      }
    } else {
      if (idir == 1){
        float dl = dll;
        float ff = (fabsf(dl) - shift)*(copysignf(1.f, dl) + fdivf_(shift, dl));
        float gg = e_ll;
        float cosr, sinr, cosl, sinl, rr;
        #pragma unroll
        for (int i0 = 0; i0 < 15; i0++){
          if (i0 >= llv-1 && i0 <= mm-2){
            slartg_(ff, gg, cosr, sinr, rr);
            if (i0 > llv-1) E[i0-1 < 0 ? 0 : i0-1] = rr;
            float di = D[i0], ei = E[i0];
            ff = cosr*di + sinr*ei;
            E[i0] = cosr*ei - sinr*di;
            gg = sinr*D[i0+1];
            D[i0+1] = cosr*D[i0+1];
            slartg_(ff, gg, cosl, sinl, rr);
            D[i0] = rr;
            float ei2 = E[i0], dip = D[i0+1];
            ff = cosl*ei2 + sinl*dip;
            D[i0+1] = cosl*dip - sinl*ei2;
            if (i0 < mm-2){
              gg = sinl*E[i0+1];
              E[i0+1] = cosl*E[i0+1];
            }
            if (cosr != 1.f || sinr != 0.f){
              float t1 = vt[i0], t2 = vt[i0+1];
              vt[i0+1] = cosr*t2 - sinr*t1;
              vt[i0]   = sinr*t2 + cosr*t1;
            }
          }
        }
        setE(mm-2, (fabsf(ff) <= thresh) ? 0.f : ff);
      } else {
        float dm = dm1;
        float ff = (fabsf(dm) - shift)*(copysignf(1.f, dm) + fdivf_(shift, dm));
        float gg = e_m2;
        float cosr, sinr, cosl, sinl, rr;
        #pragma unroll
        for (int i0 = 15; i0 >= 1; i0--){
          if (i0 >= llv && i0 <= mm-1){
            slartg_(ff, gg, cosr, sinr, rr);
            if (i0 < mm-1) E[i0] = rr;
            float di = D[i0], eim = E[i0-1];
            ff = cosr*di + sinr*eim;
            E[i0-1] = cosr*eim - sinr*di;
            gg = sinr*D[i0-1];
            D[i0-1] = cosr*D[i0-1];
            slartg_(ff, gg, cosl, sinl, rr);
            D[i0] = rr;
            float eim2 = E[i0-1], dim = D[i0-1];
            ff = cosl*eim2 + sinl*dim;
            D[i0-1] = cosl*dim - sinl*eim2;
            if (i0 > llv){
              gg = sinl*E[i0-2 < 0 ? 0 : i0-2];
              E[i0-2 < 0 ? 0 : i0-2] = cosl*E[i0-2 < 0 ? 0 : i0-2];
            }
            float cR = cosr, sR = -sinr;
            if (cR != 1.f || sR != 0.f){
              float t1 = vt[i0-1], t2 = vt[i0];
              vt[i0]   = cR*t2 - sR*t1;
              vt[i0-1] = sR*t2 + cR*t1;
            }
          }
        }
        setE(llv-1, (fabsf(ff) <= thresh) ? 0.f : ff);
      }
    }
  }
  // make positive
  #pragma unroll
  for (int k = 0; k < 16; k++){
    if (D[k] < 0.f){ D[k] = -D[k]; vt[k] = -vt[k]; }
  }
  // sort decreasing (selection, same tie-breaks as LAPACK slasrt-path in bdsqr)
  #pragma unroll
  for (int i = 1; i <= 15; i++){
    int isub = 1; float smn = D[0];
    #pragma unroll
    for (int jj = 2; jj <= 16; jj++){
      if (jj <= 16 + 1 - i){
        if (D[jj-1] <= smn){ isub = jj; smn = D[jj-1]; }
      }
    }
    if (isub != 16 + 1 - i){
      setD(isub - 1, D[16 - i]);
      D[16 - i] = smn;
      float tmp = getVt(isub - 1);
      setVt(isub - 1, vt[16 - i]);
      vt[16 - i] = tmp;
    }
  }
  // dump VT to LDS for row-wise ormbr
  if (l < 16){
    #pragma unroll
    for (int r = 0; r < 16; r++) VTm[r][l] = vt[r];
  }
  __syncthreads();
  // ormbr('P','R','T'): VT := VT * G(n-1)...G(1)
  for (int i = n-2; i >= 0; i--){
    float tp = taup[i];
    if (tp != 0.f && l < 16){
      int r = l;
      float w = VTm[r][i+1];
      for (int c = i+2; c < n; c++) w += VTm[r][c]*A[i][c];
      w *= tp;
      VTm[r][i+1] -= w;
      for (int c = i+2; c < n; c++) VTm[r][c] -= w*A[i][c];
    }
    __syncthreads();
  }
  for (int idx = l; idx < 256; idx += 64) vtlOut[idx] = VTm[idx>>4][idx&15];
}

// K12: R = Qqr * VT_L^T ; Rinv = R^T
__global__ __launch_bounds__(256) void k_rout(float* __restrict__ ws, float* __restrict__ out){
  int ty = blockIdx.y;
  const float* Qq = ws + OFF_QQR + (size_t)ty*65536;
  const float* vtl = ws + OFF_VTL + ty*256;
  long long Roff  = ty ? OUT_R2  : OUT_R1;
  long long RIoff = ty ? OUT_RI2 : OUT_RI1;
  __shared__ float V[16][16];
  int t = threadIdx.x;
  V[t>>4][t&15] = vtl[t];
  __syncthreads();
  int row = blockIdx.x*256 + t;
  float mv[16];
  #pragma unroll
  for (int q = 0; q < 4; q++){
    float4 v = ((const float4*)(Qq + (size_t)row*16))[q];
    mv[q*4] = v.x; mv[q*4+1] = v.y; mv[q*4+2] = v.z; mv[q*4+3] = v.w;
  }
  #pragma unroll
  for (int j = 0; j < 16; j++){
    float s = 0.f;
    #pragma unroll
    for (int i = 0; i < 16; i++) s = fmaf(mv[i], V[j][i], s);
    out[Roff + (long long)row*16 + j] = s;
    out[RIoff + (long long)j*4096 + row] = s;
  }
}

// ===========================================================================
extern "C" void kernel_launch(void* const* d_in, const int* in_sizes, int n_in,
                              void* d_out, int out_size, void* d_ws, size_t ws_size,
                              hipStream_t stream){
  const float* x1 = (const float*)d_in[0];
  const float* x2 = (const float*)d_in[1];
  float* out = (float*)d_out;
  float* ws = (float*)d_ws;
  (void)in_sizes; (void)n_in; (void)out_size; (void)ws_size;

  hipMemsetAsync(ws + ZERO_BASE, 0, ZERO_FLOATS*sizeof(float), stream);

  k_had<<<dim3(1024), 256, 0, stream>>>(x1, x2, out, ws);
  k_red<<<dim3(8, 2), 1024, 0, stream>>>(ws);
  k_wselect<<<dim3(2), 256, 0, stream>>>(ws);
  k_fine<<<dim3(1024, 2), 256, 0, stream>>>(x1, x2, ws);
  k_fine_sel<<<dim3(2), 256, 0, stream>>>(ws, out);
  k_fallback<<<dim3(2), 256, 0, stream>>>(x1, x2, ws, out);  // early-exit normally

  uint32_t a0, a1, b0, b1;
  h_threefry(0u, 42u, 0u, 0u, a0, a1);
  h_threefry(0u, 42u, 0u, 1u, b0, b1);
  k_omega<<<dim3(256, 2), 256, 0, stream>>>(a0, a1, b0, b1, ws);

  // QR1
  k_atype<<<dim3(512, 2), 256, 0, stream>>>(x1, x2, ws, OFF_OMT);
  k_gramP<<<dim3(64, 2), 256, 0, stream>>>(ws, OFF_BIGY, 131072);
  k_tiny<<<dim3(2), 64, 0, stream>>>(ws, OFF_BIGY, 131072);
  k_applyq<<<dim3(32, 2), 256, 0, stream>>>(ws, OFF_BIGY, 131072, OFF_BIGQ, 131072, 8192, 1, 0);
  // QR2
  k_btype<<<dim3(256, 2), 256, 0, stream>>>(x1, x2, ws);
  k_bredgram<<<dim3(64, 2), 256, 0, stream>>>(ws);
  k_tiny<<<dim3(2), 64, 0, stream>>>(ws, OFF_TMAT, 65536);
  k_applyq<<<dim3(16, 2), 256, 0, stream>>>(ws, OFF_TMAT, 65536, OFF_ZT, 65536, 4096, 0, 1);
  // QR3
  k_atype<<<dim3(512, 2), 256, 0, stream>>>(x1, x2, ws, OFF_ZT);
  k_gramP<<<dim3(64, 2), 256, 0, stream>>>(ws, OFF_BIGY, 131072);
  k_tiny<<<dim3(2), 64, 0, stream>>>(ws, OFF_BIGY, 131072);
  k_applyq<<<dim3(32, 2), 256, 0, stream>>>(ws, OFF_BIGY, 131072, OFF_BIGQ, 131072, 8192, 1, 0);
  // QR4
  k_btype<<<dim3(256, 2), 256, 0, stream>>>(x1, x2, ws);
  k_bredgram<<<dim3(64, 2), 256, 0, stream>>>(ws);
  k_tiny<<<dim3(2), 64, 0, stream>>>(ws, OFF_TMAT, 65536);
  k_applyq<<<dim3(16, 2), 256, 0, stream>>>(ws, OFF_TMAT, 65536, OFF_ZT, 65536, 4096, 0, 1);
  // QR5
  k_atype<<<dim3(512, 2), 256, 0, stream>>>(x1, x2, ws, OFF_ZT);
  k_gramP<<<dim3(64, 2), 256, 0, stream>>>(ws, OFF_BIGY, 131072);
  k_tiny<<<dim3(2), 64, 0, stream>>>(ws, OFF_BIGY, 131072);
  k_applyq<<<dim3(32, 2), 256, 0, stream>>>(ws, OFF_BIGY, 131072, OFF_BIGQ, 131072, 8192, 1, 0);
  // QR6
  k_btype<<<dim3(256, 2), 256, 0, stream>>>(x1, x2, ws);
  k_bredgram<<<dim3(64, 2), 256, 0, stream>>>(ws);
  k_tiny<<<dim3(2), 64, 0, stream>>>(ws, OFF_TMAT, 65536);
  k_applyq<<<dim3(16, 2), 256, 0, stream>>>(ws, OFF_TMAT, 65536, OFF_QQR, 65536, 4096, 1, 0);

  k_chain<<<dim3(2), 64, 0, stream>>>(ws);
  k_rout<<<dim3(16, 2), 256, 0, stream>>>(ws, out);
}

// Round 6
// 1568.848 us; speedup vs baseline: 1.1817x; 1.0266x over previous
//
#include <hip/hip_runtime.h>
#include <cstdint>
#include <cstddef>

// ============================================================================
// EfficientMemoryHadamard — round 8 (retry; r8 never ran — GPU acquisition
// timeout. Resubmitted byte-identical to keep attribution clean).
//  R7 post-mortem: scalar-branch sweeps gave only 231->217; residual latency is
//  boundary getD/setD cndmask chains (8 x 64cyc/iter) + slartg sqrt->rcp chain.
//  R8: switch(readfirstlane(i)) scalar-branch accessors (bit-identical values)
//  + rsq-fused slartg. k_chain only; all other kernels identical to r7.
// Verified assumption stack (rounds 1-7 PASSED, absmax 0.1245117):
//  A1: jax threefry_partitionable; A2: quantile = order stat 33218888;
//  A3: gesdd tail gelqf->gebd2->bdsqr->ormbr; A4: LAPACK>=3.10 slartg.
// ============================================================================

#define DEV __device__ __forceinline__

typedef float nfloat4 __attribute__((ext_vector_type(4)));

constexpr long long NTOT = 33554432LL;
constexpr unsigned long long KSEL = 33218888ULL;
constexpr uint32_t WLO = 0x40100000u;   // |x| = 2.25; window [2.25, 2.75)

constexpr long long OUT_T1  = 33554432LL;
constexpr long long OUT_R1  = 33554433LL;
constexpr long long OUT_RI1 = 33619969LL;
constexpr long long OUT_T2  = 33685505LL;
constexpr long long OUT_R2  = 33685506LL;
constexpr long long OUT_RI2 = 33751042LL;

// ---- workspace layout (float units) ----
constexpr size_t OFF_WPART  = 0;         // 1024 blocks x 4096 u32 partials = 16MB
constexpr size_t OFF_BPART  = 0;         // alias: 2*16*65536 floats (after quantile)
constexpr size_t OFF_FB     = 4194304;   // 2 x 1M u32 fallback fine hist (zeroed)
constexpr size_t OFF_CNT    = 6291456;   // 2 u32 below-window counters (zeroed)
constexpr size_t OFF_GF     = 6291472;   // 2*1024 u32 fine window hist (zeroed)
constexpr size_t ZERO_BASE  = OFF_FB;    // memset [OFF_FB, OFF_GF+2048)
constexpr size_t ZERO_FLOATS= 2099216;
constexpr size_t OFF_COARSE = 8388608;   // 2*2048 u32 window hist
constexpr size_t OFF_SEGS   = 8392704;   // 2*1024 u32 (unused, kept for layout)
constexpr size_t OFF_SELR   = 8394752;   // 2*4 ints (bin, rank, valid)
constexpr size_t OFF_TSEL   = 8394768;   // 2 floats (+pad)
constexpr size_t OFF_OMT    = 8394784;   // 2*65536
constexpr size_t OFF_BIGY   = 8525856;   // 2*131072
constexpr size_t OFF_BIGQ   = 8788000;   // 2*131072
constexpr size_t OFF_ZT     = 9050144;   // 2*65536
constexpr size_t OFF_QQR    = 9181216;   // 2*65536
constexpr size_t OFF_TMAT   = 9312288;   // 2*65536
constexpr size_t OFF_GRAMP  = 9443360;   // 2*64*256
constexpr size_t OFF_S      = 9476128;   // 2*256
constexpr size_t OFF_QTOP   = 9476640;   // 2*256
constexpr size_t OFF_RG     = 9477152;   // 2*256
constexpr size_t OFF_VTL    = 9477664;   // 2*256
// total 9478176 floats ~= 37.9 MB (unchanged)

// ---------------------------------------------------------------------------
// fast scalar ops for the serial (latency-bound) tiny kernels only
DEV float frcp_(float x){ return __builtin_amdgcn_rcpf(x); }
DEV float fdivf_(float a, float b){ return a * __builtin_amdgcn_rcpf(b); }
DEV float fsqrtf_(float x){ return __builtin_amdgcn_sqrtf(x); }
DEV float frsq_(float x){ return __builtin_amdgcn_rsqf(x); }
DEV int rfl(int x){ return __builtin_amdgcn_readfirstlane(x); }
DEV uint32_t rflu(uint32_t x){ return (uint32_t)__builtin_amdgcn_readfirstlane((int)x); }

// ---------------------------------------------------------------------------
#define TFR(a,b,r) { a += b; b = (b << r) | (b >> (32 - r)); b ^= a; }

DEV void d_threefry(uint32_t k0, uint32_t k1, uint32_t x0, uint32_t x1,
                    uint32_t& o0, uint32_t& o1){
  uint32_t ks2 = k0 ^ k1 ^ 0x1BD11BDAu;
  x0 += k0; x1 += k1;
  TFR(x0,x1,13) TFR(x0,x1,15) TFR(x0,x1,26) TFR(x0,x1,6)
  x0 += k1; x1 += ks2 + 1u;
  TFR(x0,x1,17) TFR(x0,x1,29) TFR(x0,x1,16) TFR(x0,x1,24)
  x0 += ks2; x1 += k0 + 2u;
  TFR(x0,x1,13) TFR(x0,x1,15) TFR(x0,x1,26) TFR(x0,x1,6)
  x0 += k0; x1 += k1 + 3u;
  TFR(x0,x1,17) TFR(x0,x1,29) TFR(x0,x1,16) TFR(x0,x1,24)
  x0 += k1; x1 += ks2 + 4u;
  TFR(x0,x1,13) TFR(x0,x1,15) TFR(x0,x1,26) TFR(x0,x1,6)
  x0 += ks2; x1 += k0 + 5u;
  o0 = x0; o1 = x1;
}

static void h_threefry(uint32_t k0, uint32_t k1, uint32_t x0, uint32_t x1,
                       uint32_t& o0, uint32_t& o1){
  uint32_t ks2 = k0 ^ k1 ^ 0x1BD11BDAu;
  x0 += k0; x1 += k1;
  TFR(x0,x1,13) TFR(x0,x1,15) TFR(x0,x1,26) TFR(x0,x1,6)
  x0 += k1; x1 += ks2 + 1u;
  TFR(x0,x1,17) TFR(x0,x1,29) TFR(x0,x1,16) TFR(x0,x1,24)
  x0 += ks2; x1 += k0 + 2u;
  TFR(x0,x1,13) TFR(x0,x1,15) TFR(x0,x1,26) TFR(x0,x1,6)
  x0 += k0; x1 += k1 + 3u;
  TFR(x0,x1,17) TFR(x0,x1,29) TFR(x0,x1,16) TFR(x0,x1,24)
  x0 += k1; x1 += ks2 + 4u;
  TFR(x0,x1,13) TFR(x0,x1,15) TFR(x0,x1,26) TFR(x0,x1,6)
  x0 += ks2; x1 += k0 + 5u;
  o0 = x0; o1 = x1;
}

DEV float erfinv_f32(float x){
  float w = -log1pf(-x*x);
  float p;
  if (w < 5.0f){
    w -= 2.5f;
    p = 2.81022636e-08f;
    p = fmaf(p, w, 3.43273939e-07f);
    p = fmaf(p, w, -3.5233877e-06f);
    p = fmaf(p, w, -4.39150654e-06f);
    p = fmaf(p, w, 0.00021858087f);
    p = fmaf(p, w, -0.00125372503f);
    p = fmaf(p, w, -0.00417768164f);
    p = fmaf(p, w, 0.246640727f);
    p = fmaf(p, w, 1.50140941f);
  } else {
    w = sqrtf(w) - 3.0f;
    p = -0.000200214257f;
    p = fmaf(p, w, 0.000100950558f);
    p = fmaf(p, w, 0.00134934322f);
    p = fmaf(p, w, -0.00367342844f);
    p = fmaf(p, w, 0.00573950773f);
    p = fmaf(p, w, -0.0076224613f);
    p = fmaf(p, w, 0.00943887047f);
    p = fmaf(p, w, 1.00167406f);
    p = fmaf(p, w, 2.83297682f);
  }
  return p * x;
}

// fast lapy2 — only used by serial tiny kernels (k_tiny / k_chain)
DEV float lapy2f(float x, float y){
  float xa = fabsf(x), ya = fabsf(y);
  float w = fmaxf(xa, ya), z = fminf(xa, ya);
  if (z == 0.f) return w;
  float q = z * frcp_(w);
  return w * fsqrtf_(1.f + q*q);
}

// r8: rsq-fused slartg (one transcendental on the dependent chain)
DEV void slartg_(float f, float g, float& c, float& s, float& r){
  if (g == 0.f){ c = 1.f; s = 0.f; r = f; }
  else if (f == 0.f){ c = 0.f; s = copysignf(1.f, g); r = fabsf(g); }
  else {
    float d2 = fmaf(f, f, g*g);
    float rd = frsq_(d2);
    float d = d2 * rd;
    c = fabsf(f) * rd;
    r = copysignf(d, f);
    s = g * copysignf(rd, f);   // == g / copysign(d, f)
  }
}

DEV void slas2_(float f, float g, float h, float& ssmin, float& ssmax){
  float fa = fabsf(f), ga = fabsf(g), ha = fabsf(h);
  float fhmn = fminf(fa, ha), fhmx = fmaxf(fa, ha);
  if (fhmn == 0.f){
    ssmin = 0.f;
    if (fhmx == 0.f) ssmax = ga;
    else {
      float mx = fmaxf(fhmx, ga), mn = fminf(fhmx, ga);
      float q = mn * frcp_(mx);
      ssmax = mx*fsqrtf_(1.f + q*q);
    }
  } else {
    if (ga < fhmx){
      float rmx = frcp_(fhmx);
      float as_ = 1.f + fhmn*rmx;
      float at_ = (fhmx - fhmn)*rmx;
      float au = ga*rmx; au = au*au;
      float cc = 2.f * frcp_(fsqrtf_(as_*as_ + au) + fsqrtf_(at_*at_ + au));
      ssmin = fhmn*cc; ssmax = fhmx*frcp_(cc);
    } else {
      float au = fhmx * frcp_(ga);
      if (au == 0.f){ ssmin = (fhmn*fhmx)*frcp_(ga); ssmax = ga; }
      else {
        float rmx = frcp_(fhmx);
        float as_ = 1.f + fhmn*rmx;
        float at_ = (fhmx - fhmn)*rmx;
        float q1 = as_*au, q2 = at_*au;
        float cc = frcp_(fsqrtf_(1.f + q1*q1) + fsqrtf_(1.f + q2*q2));
        ssmin = (fhmn*cc)*au; ssmin = ssmin + ssmin;
        ssmax = ga*frcp_(cc + cc);
      }
    }
  }
}

DEV void slasv2_(float f, float g, float h, float& ssmin, float& ssmax,
                 float& snr, float& csr, float& snl, float& csl){
  const float eps = 5.9604645e-08f;
  float ft = f, fa = fabsf(f), ht = h, ha = fabsf(h);
  int pmax = 1;
  bool swp = (ha > fa);
  if (swp){ pmax = 3; float t; t=ft; ft=ht; ht=t; t=fa; fa=ha; ha=t; }
  float gt = g, ga = fabsf(g);
  float clt = 0.f, crt = 0.f, slt = 0.f, srt = 0.f;
  if (ga == 0.f){ ssmin = ha; ssmax = fa; clt = 1.f; crt = 1.f; slt = 0.f; srt = 0.f; }
  else {
    bool gasmal = true;
    if (ga > fa){
      pmax = 2;
      if ((fa*frcp_(ga)) < eps){
        gasmal = false;
        ssmax = ga;
        if (ha > 1.f) ssmin = fa*frcp_(ga*frcp_(ha)); else ssmin = (fa*frcp_(ga))*ha;
        clt = 1.f; slt = ht*frcp_(gt); srt = 1.f; crt = ft*frcp_(gt);
      }
    }
    if (gasmal){
      float dd = fa - ha;
      float rfa = frcp_(fa);
      float L = (dd == fa) ? 1.f : dd*rfa;
      float Mv = gt*frcp_(ft);
      float T = 2.f - L;
      float MM = Mv*Mv, TT = T*T;
      float Sv = fsqrtf_(TT + MM);
      float Rv = (L == 0.f) ? fabsf(Mv) : fsqrtf_(L*L + MM);
      float Av = 0.5f*(Sv + Rv);
      float rAv = frcp_(Av);
      ssmin = ha*rAv; ssmax = fa*Av;
      float Tv;
      if (MM == 0.f){
        if (L == 0.f) Tv = copysignf(2.f, ft)*copysignf(1.f, gt);
        else Tv = gt*frcp_(copysignf(dd, ft)) + Mv*frcp_(T);
      } else {
        Tv = (Mv*frcp_(Sv + T) + Mv*frcp_(Rv + L))*(1.f + Av);
      }
      float Lv = fsqrtf_(Tv*Tv + 4.f);
      float rLv = frcp_(Lv);
      crt = 2.f*rLv; srt = Tv*rLv;
      clt = (crt + srt*Mv)*rAv;
      slt = (ht*frcp_(ft))*srt*rAv;
    }
  }
  if (swp){ csl = srt; snl = crt; csr = slt; snr = clt; }
  else    { csl = clt; snl = slt; csr = crt; snr = srt; }
  float tsign = 1.f;
  if (pmax == 1) tsign = copysignf(1.f, csr)*copysignf(1.f, csl)*copysignf(1.f, f);
  if (pmax == 2) tsign = copysignf(1.f, snr)*copysignf(1.f, csl)*copysignf(1.f, g);
  if (pmax == 3) tsign = copysignf(1.f, snr)*copysignf(1.f, snl)*copysignf(1.f, h);
  ssmax = copysignf(ssmax, tsign);
  ssmin = copysignf(ssmin, tsign*copysignf(1.f, f)*copysignf(1.f, h));
}

// ===========================================================================
// K1: hadamard + 2048-bin LDS window hist (dd>>10) + per-block partial
// flush + register below-window counters. NO per-element global atomics.
// ===========================================================================
__global__ __launch_bounds__(256) void k_had(const float* __restrict__ x1,
    const float* __restrict__ x2, float* __restrict__ out, float* __restrict__ ws){
  __shared__ uint32_t wh[2][2048];
  for (int i = threadIdx.x; i < 4096; i += 256) (&wh[0][0])[i] = 0u;
  __syncthreads();
  uint32_t* cnt = (uint32_t*)(ws + OFF_CNT);
  const float4* a4 = (const float4*)x1;
  const float4* b4 = (const float4*)x2;
  nfloat4* o4 = (nfloat4*)out;
  uint32_t cb1 = 0, cb2 = 0;
  long long n4 = NTOT/4;
  long long stride = (long long)gridDim.x * 256;
  for (long long i = (long long)blockIdx.x*256 + threadIdx.x; i < n4; i += stride){
    float4 a = a4[i], b = b4[i];
    nfloat4 o;
    o.x = a.x*b.x; o.y = a.y*b.y; o.z = a.z*b.z; o.w = a.w*b.w;
    __builtin_nontemporal_store(o, &o4[i]);
    uint32_t u, dd;
    u = __float_as_uint(a.x)&0x7fffffffu; cb1 += (u < WLO); dd = u - WLO;
    if (dd < 0x200000u) atomicAdd(&wh[0][dd>>10], 1u);
    u = __float_as_uint(a.y)&0x7fffffffu; cb1 += (u < WLO); dd = u - WLO;
    if (dd < 0x200000u) atomicAdd(&wh[0][dd>>10], 1u);
    u = __float_as_uint(a.z)&0x7fffffffu; cb1 += (u < WLO); dd = u - WLO;
    if (dd < 0x200000u) atomicAdd(&wh[0][dd>>10], 1u);
    u = __float_as_uint(a.w)&0x7fffffffu; cb1 += (u < WLO); dd = u - WLO;
    if (dd < 0x200000u) atomicAdd(&wh[0][dd>>10], 1u);
    u = __float_as_uint(b.x)&0x7fffffffu; cb2 += (u < WLO); dd = u - WLO;
    if (dd < 0x200000u) atomicAdd(&wh[1][dd>>10], 1u);
    u = __float_as_uint(b.y)&0x7fffffffu; cb2 += (u < WLO); dd = u - WLO;
    if (dd < 0x200000u) atomicAdd(&wh[1][dd>>10], 1u);
    u = __float_as_uint(b.z)&0x7fffffffu; cb2 += (u < WLO); dd = u - WLO;
    if (dd < 0x200000u) atomicAdd(&wh[1][dd>>10], 1u);
    u = __float_as_uint(b.w)&0x7fffffffu; cb2 += (u < WLO); dd = u - WLO;
    if (dd < 0x200000u) atomicAdd(&wh[1][dd>>10], 1u);
  }
  __syncthreads();
  uint32_t* wp = (uint32_t*)(ws + OFF_WPART) + (size_t)blockIdx.x*4096;
  for (int i = threadIdx.x; i < 4096; i += 256) wp[i] = (&wh[0][0])[i];
  #pragma unroll
  for (int off = 32; off > 0; off >>= 1){
    cb1 += __shfl_xor(cb1, off, 64);
    cb2 += __shfl_xor(cb2, off, 64);
  }
  if ((threadIdx.x & 63) == 0){
    atomicAdd(&cnt[0], cb1);
    atomicAdd(&cnt[1], cb2);
  }
}

// K1b: reduce 1024 partial window hists -> H[ty][2048] at OFF_COARSE.
__global__ __launch_bounds__(1024) void k_red(float* __restrict__ ws){
  int ty = blockIdx.y;
  const uint32_t* wp = (const uint32_t*)(ws + OFF_WPART);
  uint32_t* H = (uint32_t*)(ws + OFF_COARSE) + ty*2048;
  int t = threadIdx.x;
  int bin = blockIdx.x*256 + (t & 255);
  int pq = t >> 8;   // 0..3
  uint32_t s = 0;
  for (int p = pq*256; p < pq*256 + 256; p++)
    s += wp[(size_t)p*4096 + (size_t)ty*2048 + bin];
  __shared__ uint32_t sh[1024];
  sh[t] = s;
  __syncthreads();
  if (t < 256) H[bin] = sh[t] + sh[t+256] + sh[t+512] + sh[t+768];
}

// K1c: scan window hist, locate sub-bin (1024 fine values) + rank within it.
__global__ __launch_bounds__(256) void k_wselect(float* __restrict__ ws){
  int ty = blockIdx.x;
  const uint32_t* H = (const uint32_t*)(ws + OFF_COARSE) + ty*2048;
  const uint32_t* cnt = (const uint32_t*)(ws + OFF_CNT);
  int* selr = (int*)(ws + OFF_SELR) + ty*4;
  __shared__ unsigned long long ps[256];
  unsigned long long s = 0;
  for (int j = 0; j < 8; j++) s += H[threadIdx.x*8 + j];
  ps[threadIdx.x] = s;
  __syncthreads();
  if (threadIdx.x == 0){
    unsigned long long K = KSEL, cum = cnt[ty];
    int valid = 0, sbin = 0, rank = 0;
    if (K >= cum){
      int g = 0;
      for (; g < 256; g++){ if (cum + ps[g] > K) break; cum += ps[g]; }
      if (g < 256){
        for (int j = 0; j < 8; j++){
          uint32_t c = H[g*8 + j];
          if (cum + c > K){ sbin = g*8 + j; rank = (int)(K - cum); valid = 1; break; }
          cum += c;
        }
      }
    }
    selr[0] = sbin; selr[1] = rank; selr[2] = valid;
  }
}

// K1d: re-stream x, histogram only the selected 1024-value sub-bin (LDS),
// flush ~650 nonzero bins total via global atomics.
__global__ __launch_bounds__(256) void k_fine(const float* __restrict__ x1,
    const float* __restrict__ x2, float* __restrict__ ws){
  int ty = blockIdx.y;
  const int* selr = (const int*)(ws + OFF_SELR) + ty*4;
  if (!selr[2]) return;
  uint32_t g = (uint32_t)selr[0];
  __shared__ uint32_t lh[1024];
  for (int i = threadIdx.x; i < 1024; i += 256) lh[i] = 0u;
  __syncthreads();
  const float4* x4 = (const float4*)(ty ? x2 : x1);
  long long n4 = NTOT/4;
  long long stride = (long long)gridDim.x * 256;
  for (long long i = (long long)blockIdx.x*256 + threadIdx.x; i < n4; i += stride){
    float4 a = x4[i];
    uint32_t dd;
    dd = (__float_as_uint(a.x)&0x7fffffffu) - WLO;
    if ((dd>>10) == g) atomicAdd(&lh[dd & 1023u], 1u);
    dd = (__float_as_uint(a.y)&0x7fffffffu) - WLO;
    if ((dd>>10) == g) atomicAdd(&lh[dd & 1023u], 1u);
    dd = (__float_as_uint(a.z)&0x7fffffffu) - WLO;
    if ((dd>>10) == g) atomicAdd(&lh[dd & 1023u], 1u);
    dd = (__float_as_uint(a.w)&0x7fffffffu) - WLO;
    if ((dd>>10) == g) atomicAdd(&lh[dd & 1023u], 1u);
  }
  __syncthreads();
  uint32_t* gf = (uint32_t*)(ws + OFF_GF) + (size_t)ty*1024;
  for (int i = threadIdx.x; i < 1024; i += 256){
    uint32_t v = lh[i];
    if (v) atomicAdd(&gf[i], v);
  }
}

// K1e: scan the 1024-bin fine hist -> exact bit threshold.
__global__ __launch_bounds__(256) void k_fine_sel(float* __restrict__ ws,
    float* __restrict__ out){
  int ty = blockIdx.x;
  const int* selr = (const int*)(ws + OFF_SELR) + ty*4;
  if (!selr[2]) return;
  const uint32_t* gf = (const uint32_t*)(ws + OFF_GF) + (size_t)ty*1024;
  __shared__ uint32_t sh[1024];
  __shared__ uint32_t ps[256];
  int t = threadIdx.x;
  for (int k = 0; k < 4; k++) sh[k*256 + t] = gf[k*256 + t];
  __syncthreads();
  ps[t] = sh[4*t] + sh[4*t+1] + sh[4*t+2] + sh[4*t+3];
  __syncthreads();
  if (t == 0){
    uint32_t K = (uint32_t)selr[1];
    uint32_t cum = 0; int q = 0;
    for (; q < 256; q++){ if (cum + ps[q] > K) break; cum += ps[q]; }
    if (q > 255) q = 255;
    int f = q*4 + 3;
    for (int jj = 0; jj < 4; jj++){
      uint32_t c = sh[q*4 + jj];
      if (cum + c > K){ f = q*4 + jj; break; }
      cum += c;
    }
    uint32_t bits = WLO + (((uint32_t)selr[0]) << 10) + (uint32_t)f;
    float th = __uint_as_float(bits);
    ws[OFF_TSEL + ty] = th;
    out[ty ? OUT_T2 : OUT_T1] = th;
  }
}

// ---------------------------------------------------------------------------
// K1f: single-kernel exact fallback (speculation miss). Early-exits in the
// normal case.
// ---------------------------------------------------------------------------
__global__ __launch_bounds__(256) void k_fallback(const float* __restrict__ x1,
    const float* __restrict__ x2, float* __restrict__ ws, float* __restrict__ out){
  int ty = blockIdx.x;
  const int* selr = (const int*)(ws + OFF_SELR) + ty*4;
  if (selr[2]) return;
  const float4* x4 = (const float4*)(ty ? x2 : x1);
  long long n4 = NTOT/4;
  __shared__ uint32_t lh[2048];
  for (int i = threadIdx.x; i < 2048; i += 256) lh[i] = 0u;
  __syncthreads();
  for (long long i = threadIdx.x; i < n4; i += 256){
    float4 a = x4[i];
    atomicAdd(&lh[(__float_as_uint(a.x)&0x7fffffffu)>>20], 1u);
    atomicAdd(&lh[(__float_as_uint(a.y)&0x7fffffffu)>>20], 1u);
    atomicAdd(&lh[(__float_as_uint(a.z)&0x7fffffffu)>>20], 1u);
    atomicAdd(&lh[(__float_as_uint(a.w)&0x7fffffffu)>>20], 1u);
  }
  __syncthreads();
  __shared__ unsigned long long ps[256];
  {
    unsigned long long s = 0;
    for (int j = 0; j < 8; j++) s += lh[threadIdx.x*8 + j];
    ps[threadIdx.x] = s;
  }
  __syncthreads();
  __shared__ int sbin; __shared__ uint32_t srank;
  if (threadIdx.x == 0){
    unsigned long long cum = 0, K = KSEL;
    int g = 0;
    for (; g < 256; g++){ if (cum + ps[g] > K) break; cum += ps[g]; }
    if (g > 255) g = 255;
    int bin = 2047;
    for (int j = 0; j < 8; j++){
      uint32_t c = lh[g*8 + j];
      if (cum + c > K){ bin = g*8 + j; break; }
      cum += c;
    }
    sbin = bin; srank = (uint32_t)(K - cum);
  }
  __syncthreads();
  uint32_t bin = (uint32_t)sbin;
  uint32_t* f = (uint32_t*)(ws + OFF_FB) + ((size_t)ty<<20);
  for (long long i = threadIdx.x; i < n4; i += 256){
    float4 a = x4[i];
    uint32_t u;
    u = __float_as_uint(a.x)&0x7fffffffu; if ((u>>20)==bin) atomicAdd(&f[u&0xFFFFFu],1u);
    u = __float_as_uint(a.y)&0x7fffffffu; if ((u>>20)==bin) atomicAdd(&f[u&0xFFFFFu],1u);
    u = __float_as_uint(a.z)&0x7fffffffu; if ((u>>20)==bin) atomicAdd(&f[u&0xFFFFFu],1u);
    u = __float_as_uint(a.w)&0x7fffffffu; if ((u>>20)==bin) atomicAdd(&f[u&0xFFFFFu],1u);
  }
  __threadfence();
  __syncthreads();
  __shared__ uint32_t segs[1024];
  for (int sgi = threadIdx.x; sgi < 1024; sgi += 256){
    uint32_t ss = 0;
    for (int j = 0; j < 1024; j++) ss += f[(size_t)sgi*1024 + j];
    segs[sgi] = ss;
  }
  __syncthreads();
  if (threadIdx.x == 0){
    uint32_t K = srank, cum = 0;
    int q = 0;
    for (; q < 256; q++){
      uint32_t pq = segs[4*q] + segs[4*q+1] + segs[4*q+2] + segs[4*q+3];
      if (cum + pq > K) break;
      cum += pq;
    }
    if (q > 255) q = 255;
    int g = q*4 + 3;
    for (int j = 0; j < 4; j++){
      uint32_t c = segs[q*4 + j];
      if (cum + c > K){ g = q*4 + j; break; }
      cum += c;
    }
    int jf = 1023;
    for (int j = 0; j < 1024; j++){
      uint32_t c = f[(size_t)g*1024 + j];
      if (cum + c > K){ jf = j; break; }
      cum += c;
    }
    uint32_t bits = (bin<<20) | (uint32_t)((g*1024 + jf) & 0xFFFFF);
    float th = __uint_as_float(bits);
    ws[OFF_TSEL + ty] = th;
    out[ty ? OUT_T2 : OUT_T1] = th;
  }
}

__global__ __launch_bounds__(256) void k_omega(uint32_t a0, uint32_t a1,
    uint32_t b0, uint32_t b1, float* __restrict__ ws){
  int ty = blockIdx.y;
  uint32_t k0 = ty ? b0 : a0, k1 = ty ? b1 : a1;
  int i = blockIdx.x*256 + threadIdx.x;
  uint32_t o0, o1;
  d_threefry(k0, k1, 0u, (uint32_t)i, o0, o1);
  uint32_t bits = o0 ^ o1;
  float fr = __uint_as_float((bits >> 9) | 0x3f800000u) - 1.0f;
  const float lo = -0.99999994f;
  float u = fr * 2.0f + lo;
  u = fmaxf(lo, u);
  float v = 1.41421356237f * erfinv_f32(u);
  int row = i >> 4, col = i & 15;
  ws[OFF_OMT + (size_t)ty*65536 + (size_t)col*4096 + row] = v;
}

// K6: Y(8192x16) = residual(x) * W  (W^T 16x4096 in ws)
__global__ __launch_bounds__(256) void k_atype(const float* __restrict__ x1,
    const float* __restrict__ x2, float* __restrict__ ws, size_t wtOff){
  int ty = blockIdx.y;
  const float* x = ty ? x2 : x1;
  const float* wt = ws + wtOff + (size_t)ty*65536;
  float* Y = ws + OFF_BIGY + (size_t)ty*131072;
  float t = ws[OFF_TSEL + ty];
  int wave = threadIdx.x >> 6, lane = threadIdx.x & 63;
  __shared__ __align__(16) float wts[16][256];
  __shared__ float outs[16][16];
  float acc[4][16];
  #pragma unroll
  for (int r = 0; r < 4; r++)
    #pragma unroll
    for (int j = 0; j < 16; j++) acc[r][j] = 0.f;
  int rowbase = blockIdx.x*16 + wave*4;
  for (int c = 0; c < 4096; c += 256){
    __syncthreads();
    for (int idx = threadIdx.x; idx < 16*64; idx += 256){
      int j = idx >> 6, q = idx & 63;
      ((float4*)&wts[j][0])[q] = ((const float4*)(wt + (size_t)j*4096 + c))[q];
    }
    __syncthreads();
    float4 xv[4];
    #pragma unroll
    for (int rr = 0; rr < 4; rr++){
      int row = rowbase + rr;
      float4 a = ((const float4*)(x + (size_t)row*4096 + c))[lane];
      a.x = fabsf(a.x) > t ? 0.f : a.x;
      a.y = fabsf(a.y) > t ? 0.f : a.y;
      a.z = fabsf(a.z) > t ? 0.f : a.z;
      a.w = fabsf(a.w) > t ? 0.f : a.w;
      xv[rr] = a;
    }
    #pragma unroll
    for (int j = 0; j < 16; j++){
      float4 w4 = ((const float4*)&wts[j][0])[lane];
      #pragma unroll
      for (int rr = 0; rr < 4; rr++){
        acc[rr][j] = fmaf(xv[rr].x, w4.x, acc[rr][j]);
        acc[rr][j] = fmaf(xv[rr].y, w4.y, acc[rr][j]);
        acc[rr][j] = fmaf(xv[rr].z, w4.z, acc[rr][j]);
        acc[rr][j] = fmaf(xv[rr].w, w4.w, acc[rr][j]);
      }
    }
  }
  #pragma unroll
  for (int rr = 0; rr < 4; rr++)
    for (int j = 0; j < 16; j++){
      float v = acc[rr][j];
      for (int off = 32; off > 0; off >>= 1) v += __shfl_xor(v, off, 64);
      if (lane == 0) outs[wave*4 + rr][j] = v;
    }
  __syncthreads();
  int r = threadIdx.x >> 4, cc = threadIdx.x & 15;
  Y[(size_t)(blockIdx.x*16 + r)*16 + cc] = outs[r][cc];
}

__global__ __launch_bounds__(256) void k_gramP(float* __restrict__ ws, size_t mOff,
    size_t mStr){
  int ty = blockIdx.y;
  const float* M = ws + mOff + (size_t)ty*mStr;
  float* gp = ws + OFF_GRAMP + (size_t)(ty*64 + blockIdx.x)*256;
  __shared__ __align__(16) float buf[128][16];
  int t = threadIdx.x;
  for (int q = t; q < 512; q += 256)
    ((float4*)&buf[0][0])[q] = ((const float4*)(M + (size_t)blockIdx.x*2048))[q];
  __syncthreads();
  int i = t >> 4, j = t & 15;
  float s = 0.f;
  int rstart = (blockIdx.x == 0) ? 16 : 0;
  for (int r = rstart; r < 128; r++) s += buf[r][i]*buf[r][j];
  gp[t] = s;
}

__global__ __launch_bounds__(256) void k_btype(const float* __restrict__ x1,
    const float* __restrict__ x2, float* __restrict__ ws){
  int ty = blockIdx.y;
  const float* x = ty ? x2 : x1;
  const float* Q = ws + OFF_BIGQ + (size_t)ty*131072;
  float t = ws[OFF_TSEL + ty];
  int cb = blockIdx.x & 15;
  int rc = blockIdx.x >> 4;
  int c = cb*256 + threadIdx.x;
  int r0 = rc*512;
  __shared__ __align__(16) float Qs[64][16];
  float acc[16];
  #pragma unroll
  for (int j = 0; j < 16; j++) acc[j] = 0.f;
  for (int tile = 0; tile < 8; tile++){
    __syncthreads();
    ((float4*)&Qs[0][0])[threadIdx.x] =
        ((const float4*)(Q + (size_t)(r0 + tile*64)*16))[threadIdx.x];
    __syncthreads();
    const float* xp = x + (size_t)(r0 + tile*64)*4096 + c;
    #pragma unroll 4
    for (int rr = 0; rr < 64; rr++){
      float v = xp[(size_t)rr*4096];
      v = fabsf(v) > t ? 0.f : v;
      float4 qa = ((const float4*)&Qs[rr][0])[0];
      float4 qb = ((const float4*)&Qs[rr][0])[1];
      float4 qc = ((const float4*)&Qs[rr][0])[2];
      float4 qd = ((const float4*)&Qs[rr][0])[3];
      acc[ 0] = fmaf(v, qa.x, acc[ 0]);
      acc[ 1] = fmaf(v, qa.y, acc[ 1]);
      acc[ 2] = fmaf(v, qa.z, acc[ 2]);
      acc[ 3] = fmaf(v, qa.w, acc[ 3]);
      acc[ 4] = fmaf(v, qb.x, acc[ 4]);
      acc[ 5] = fmaf(v, qb.y, acc[ 5]);
      acc[ 6] = fmaf(v, qb.z, acc[ 6]);
      acc[ 7] = fmaf(v, qb.w, acc[ 7]);
      acc[ 8] = fmaf(v, qc.x, acc[ 8]);
      acc[ 9] = fmaf(v, qc.y, acc[ 9]);
      acc[10] = fmaf(v, qc.z, acc[10]);
      acc[11] = fmaf(v, qc.w, acc[11]);
      acc[12] = fmaf(v, qd.x, acc[12]);
      acc[13] = fmaf(v, qd.y, acc[13]);
      acc[14] = fmaf(v, qd.z, acc[14]);
      acc[15] = fmaf(v, qd.w, acc[15]);
    }
  }
  float* BP = ws + OFF_BPART + (((size_t)(ty*16 + rc))<<16) + (size_t)c*16;
  #pragma unroll
  for (int q = 0; q < 4; q++){
    float4 o; o.x = acc[q*4]; o.y = acc[q*4+1]; o.z = acc[q*4+2]; o.w = acc[q*4+3];
    ((float4*)BP)[q] = o;
  }
}

__global__ __launch_bounds__(256) void k_bredgram(float* __restrict__ ws){
  int ty = blockIdx.y;
  const float* BP = ws + OFF_BPART + (((size_t)ty*16)<<16);
  float* T = ws + OFF_TMAT + (size_t)ty*65536;
  float* gp = ws + OFF_GRAMP + (size_t)(ty*64 + blockIdx.x)*256;
  __shared__ float sh[64][16];
  int t = threadIdx.x;
  for (int k = 0; k < 4; k++){
    int e = blockIdx.x*1024 + k*256 + t;
    float s = 0.f;
    #pragma unroll
    for (int rc = 0; rc < 16; rc++) s += BP[((size_t)rc<<16) + e];
    T[e] = s;
    int le = k*256 + t;
    sh[le >> 4][le & 15] = s;
  }
  __syncthreads();
  int i = t >> 4, j = t & 15;
  float s = 0.f;
  int rstart = (blockIdx.x == 0) ? 16 : 0;
  for (int r = rstart; r < 64; r++) s += sh[r][i]*sh[r][j];
  gp[t] = s;
}

// K9: register-resident tiny QR: gram-sum, chol (LDS), geqrf+org2r (regs),
//     back-solve. Lane j<16 holds column j.  (fast rcp/sqrt)
__global__ __launch_bounds__(64) void k_tiny(float* __restrict__ ws, size_t mOff,
    size_t mStr){
  int ty = blockIdx.x;
  const float* Mp = ws + mOff + (size_t)ty*mStr;
  float* sOut = ws + OFF_S + ty*256;
  float* qtOut = ws + OFF_QTOP + ty*256;
  float* rgOut = ws + OFF_RG + ty*256;
  __shared__ float G[16][16];
  __shared__ float Cld[32][16];
  __shared__ float bc[4];
  __shared__ float tau[16];
  int l = threadIdx.x;
  int j = l & 15;
  for (int e = l; e < 256; e += 64){
    const float* gp = ws + OFF_GRAMP + (size_t)ty*16384 + e;
    float s = 0.f;
    for (int p = 0; p < 64; p++) s += gp[(size_t)p*256];
    G[e>>4][e&15] = s;
  }
  for (int idx = l; idx < 256; idx += 64)
    Cld[idx>>4][idx&15] = Mp[idx];
  __syncthreads();
  // cholesky (upper) in place — fast rcp/sqrt
  for (int k = 0; k < 16; k++){
    float dk = fsqrtf_(G[k][k]);
    float rdk = frcp_(dk);
    if (l == k) G[k][k] = dk;
    else if (l > k && l < 16) G[k][l] = G[k][l] * rdk;
    __syncthreads();
    if (l > k && l < 16)
      for (int jj = l; jj < 16; jj++) G[l][jj] -= G[k][l]*G[k][jj];
    __syncthreads();
  }
  // build column registers: C = [M_top ; R_B]
  float Cc[32];
  #pragma unroll
  for (int r = 0; r < 32; r++){
    if (r < 16) Cc[r] = Cld[r][j];
    else Cc[r] = (j >= r - 16) ? G[r-16][j] : 0.f;
  }
  // geqrf (fast rcp/sqrt, same op order)
  #pragma unroll
  for (int i = 0; i < 16; i++){
    if (l == i){
      float alpha = Cc[i];
      float ssum = 0.f;
      #pragma unroll
      for (int r = i+1; r < 32; r++) ssum += Cc[r]*Cc[r];
      float xn = fsqrtf_(ssum);
      float beta, tv, sc;
      if (xn == 0.f){ tv = 0.f; beta = alpha; sc = 1.f; }
      else {
        beta = -copysignf(lapy2f(alpha, xn), alpha);
        tv = fdivf_(beta - alpha, beta);
        sc = frcp_(alpha - beta);
        #pragma unroll
        for (int r = i+1; r < 32; r++) Cc[r] *= sc;
      }
      Cc[i] = beta;
      bc[0] = beta; bc[1] = tv;
      tau[i] = tv;
      #pragma unroll
      for (int r = i; r < 32; r++) Cld[r][i] = Cc[r];
    }
    __syncthreads();
    float tv = bc[1];
    if (tv != 0.f && l < 16 && j > i){
      float w = Cc[i];
      #pragma unroll
      for (int r = i+1; r < 32; r++) w += Cld[r][i]*Cc[r];
      w *= tv;
      Cc[i] -= w;
      #pragma unroll
      for (int r = i+1; r < 32; r++) Cc[r] -= w*Cld[r][i];
    }
    __syncthreads();
  }
  // org2r (no barriers needed: Cld/tau now read-only)
  float Qc[32];
  #pragma unroll
  for (int r = 0; r < 32; r++) Qc[r] = 0.f;
  #pragma unroll
  for (int i = 15; i >= 0; i--){
    float tv = tau[i];
    if (i < 15 && l < 16 && j > i){
      float w = Qc[i];
      #pragma unroll
      for (int r = i+1; r < 32; r++) w += Cld[r][i]*Qc[r];
      w *= tv;
      Qc[i] -= w;
      #pragma unroll
      for (int r = i+1; r < 32; r++) Qc[r] -= w*Cld[r][i];
    }
    if (l == i){
      #pragma unroll
      for (int r = 0; r < 32; r++){
        if (r < i) Qc[r] = 0.f;
        else if (r == i) Qc[r] = 1.f - tv;
        else Qc[r] = -tv * Cld[r][i];
      }
    }
  }
  // back-solve S = R_B^{-1} * Q_bot
  float Sc[16];
  if (l < 16){
    #pragma unroll
    for (int i2 = 15; i2 >= 0; i2--){
      float v = Qc[16 + i2];
      #pragma unroll
      for (int k2 = i2+1; k2 < 16; k2++) v -= G[i2][k2]*Sc[k2];
      Sc[i2] = v * frcp_(G[i2][i2]);
    }
    #pragma unroll
    for (int r = 0; r < 16; r++){
      rgOut[r*16 + j] = (j >= r) ? Cc[r] : 0.f;
      sOut[r*16 + j] = Sc[r];
      qtOut[r*16 + j] = Qc[r];
    }
  }
}

__global__ __launch_bounds__(256) void k_applyq(float* __restrict__ ws, size_t mOff,
    size_t mStr, size_t oOff, size_t oStr, int nrows, int wN, int wT){
  int ty = blockIdx.y;
  const float* Mp = ws + mOff + (size_t)ty*mStr;
  const float* sP = ws + OFF_S + ty*256;
  const float* qtP = ws + OFF_QTOP + ty*256;
  float* oP = ws + oOff + (size_t)ty*oStr;
  __shared__ float Ss[16][16], Qt[16][16];
  int t = threadIdx.x;
  Ss[t>>4][t&15] = sP[t];
  Qt[t>>4][t&15] = qtP[t];
  __syncthreads();
  int row = blockIdx.x*256 + t;
  if (row >= nrows) return;
  float o[16];
  if (row < 16){
    #pragma unroll
    for (int j = 0; j < 16; j++) o[j] = Qt[row][j];
  } else {
    float mv[16];
    #pragma unroll
    for (int q = 0; q < 4; q++){
      float4 v = ((const float4*)(Mp + (size_t)row*16))[q];
      mv[q*4] = v.x; mv[q*4+1] = v.y; mv[q*4+2] = v.z; mv[q*4+3] = v.w;
    }
    #pragma unroll
    for (int j = 0; j < 16; j++){
      float sacc = 0.f;
      #pragma unroll
      for (int i = 0; i < 16; i++) sacc = fmaf(mv[i], Ss[i][j], sacc);
      o[j] = sacc;
    }
  }
  if (wN){
    #pragma unroll
    for (int q = 0; q < 4; q++){
      float4 v; v.x = o[q*4]; v.y = o[q*4+1]; v.z = o[q*4+2]; v.w = o[q*4+3];
      ((float4*)(oP + (size_t)row*16))[q] = v;
    }
  }
  if (wT){
    #pragma unroll
    for (int j = 0; j < 16; j++) oP[(size_t)j*4096 + row] = o[j];
  }
}

// ===========================================================================
// K11: gesdd tail. gebd2 (LDS) -> bdsqr (REGISTERS, lane=VT column) -> ormbr.
// r8: switch(readfirstlane)-scalar accessors + rsq-fused slartg.
// Same arithmetic values and iteration order as r1-r7.
// ===========================================================================
__global__ __launch_bounds__(64) void k_chain(float* __restrict__ ws){
  int ty = blockIdx.x;
  const float* rg = ws + OFF_RG + ty*256;
  float* vtlOut = ws + OFF_VTL + ty*256;
  const int n = 16;
  __shared__ float A[16][16];
  __shared__ float VTm[16][16];
  __shared__ float d_[16], e_[16], tauq[16], taup[16];
  int l = threadIdx.x;
  for (int idx = l; idx < 256; idx += 64){
    int r = idx >> 4, c = idx & 15;
    A[r][c] = (r >= c) ? rg[c*16 + r] : 0.f;   // L = Rg^T
  }
  __syncthreads();
  // ---- gebd2 (fast rcp/sqrt) ----
  for (int i = 0; i < n; i++){
    {
      float alpha = A[i][i];
      float ssum = 0.f;
      for (int r = i+1; r < n; r++) ssum += A[r][i]*A[r][i];
      float xn = fsqrtf_(ssum);
      float beta, tv;
      if (n - i <= 1 || xn == 0.f){ tv = 0.f; beta = alpha; }
      else {
        beta = -copysignf(lapy2f(alpha, xn), alpha);
        tv = fdivf_(beta - alpha, beta);
        float sc = frcp_(alpha - beta);
        if (l > i && l < n) A[l][i] *= sc;
      }
      if (l == 0){ d_[i] = beta; tauq[i] = tv; }
      __syncthreads();
      if (tv != 0.f && l > i && l < n){
        int jj = l;
        float w = A[i][jj];
        for (int r = i+1; r < n; r++) w += A[r][i]*A[r][jj];
        w *= tv;
        A[i][jj] -= w;
        for (int r = i+1; r < n; r++) A[r][jj] -= w*A[r][i];
      }
      __syncthreads();
    }
    if (i < n-1){
      float alpha = A[i][i+1];
      float ssum = 0.f;
      for (int c = i+2; c < n; c++) ssum += A[i][c]*A[i][c];
      float xn = fsqrtf_(ssum);
      float beta, tp;
      if (n - i - 1 <= 1 || xn == 0.f){ tp = 0.f; beta = alpha; }
      else {
        beta = -copysignf(lapy2f(alpha, xn), alpha);
        tp = fdivf_(beta - alpha, beta);
        float sc = frcp_(alpha - beta);
        if (l >= i+2 && l < n) A[i][l] *= sc;
      }
      if (l == 0){ e_[i] = beta; taup[i] = tp; }
      __syncthreads();
      if (tp != 0.f && l > i && l < n){
        int r = l;
        float w = A[r][i+1];
        for (int c = i+2; c < n; c++) w += A[i][c]*A[r][c];
        w *= tp;
        A[r][i+1] -= w;
        for (int c = i+2; c < n; c++) A[r][c] -= w*A[i][c];
      }
      __syncthreads();
    } else {
      if (l == 0) taup[i] = 0.f;
      __syncthreads();
    }
  }
  // ---- bdsqr: state in registers; scalar-branch accessors ----
  float D[16], E[16], vt[16];
  #pragma unroll
  for (int k = 0; k < 16; k++){
    D[k] = d_[k];
    E[k] = (k < 15) ? e_[k] : 0.f;
    vt[k] = (k == l) ? 1.f : 0.f;
  }
  // r8: switch on readfirstlane'd (wave-uniform) index -> s_cbranch tree,
  // replacing 16-deep v_cndmask chains. Values bit-identical.
  auto getD = [&](int i)->float{
    switch(rfl(i)){
      case 0: return D[0];  case 1: return D[1];  case 2: return D[2];  case 3: return D[3];
      case 4: return D[4];  case 5: return D[5];  case 6: return D[6];  case 7: return D[7];
      case 8: return D[8];  case 9: return D[9];  case 10: return D[10]; case 11: return D[11];
      case 12: return D[12]; case 13: return D[13]; case 14: return D[14]; default: return D[15];
    }
  };
  auto setD = [&](int i, float v){
    switch(rfl(i)){
      case 0: D[0]=v; break;  case 1: D[1]=v; break;  case 2: D[2]=v; break;  case 3: D[3]=v; break;
      case 4: D[4]=v; break;  case 5: D[5]=v; break;  case 6: D[6]=v; break;  case 7: D[7]=v; break;
      case 8: D[8]=v; break;  case 9: D[9]=v; break;  case 10: D[10]=v; break; case 11: D[11]=v; break;
      case 12: D[12]=v; break; case 13: D[13]=v; break; case 14: D[14]=v; break; default: D[15]=v; break;
    }
  };
  auto getE = [&](int i)->float{
    switch(rfl(i)){
      case 0: return E[0];  case 1: return E[1];  case 2: return E[2];  case 3: return E[3];
      case 4: return E[4];  case 5: return E[5];  case 6: return E[6];  case 7: return E[7];
      case 8: return E[8];  case 9: return E[9];  case 10: return E[10]; case 11: return E[11];
      case 12: return E[12]; case 13: return E[13]; case 14: return E[14]; default: return E[15];
    }
  };
  auto setE = [&](int i, float v){
    switch(rfl(i)){
      case 0: E[0]=v; break;  case 1: E[1]=v; break;  case 2: E[2]=v; break;  case 3: E[3]=v; break;
      case 4: E[4]=v; break;  case 5: E[5]=v; break;  case 6: E[6]=v; break;  case 7: E[7]=v; break;
      case 8: E[8]=v; break;  case 9: E[9]=v; break;  case 10: E[10]=v; break; case 11: E[11]=v; break;
      case 12: E[12]=v; break; case 13: E[13]=v; break; case 14: E[14]=v; break; default: E[15]=v; break;
    }
  };
  auto getVt = [&](int i)->float{
    switch(rfl(i)){
      case 0: return vt[0];  case 1: return vt[1];  case 2: return vt[2];  case 3: return vt[3];
      case 4: return vt[4];  case 5: return vt[5];  case 6: return vt[6];  case 7: return vt[7];
      case 8: return vt[8];  case 9: return vt[9];  case 10: return vt[10]; case 11: return vt[11];
      case 12: return vt[12]; case 13: return vt[13]; case 14: return vt[14]; default: return vt[15];
    }
  };
  auto setVt = [&](int i, float v){
    switch(rfl(i)){
      case 0: vt[0]=v; break;  case 1: vt[1]=v; break;  case 2: vt[2]=v; break;  case 3: vt[3]=v; break;
      case 4: vt[4]=v; break;  case 5: vt[5]=v; break;  case 6: vt[6]=v; break;  case 7: vt[7]=v; break;
      case 8: vt[8]=v; break;  case 9: vt[9]=v; break;  case 10: vt[10]=v; break; case 11: vt[11]=v; break;
      case 12: vt[12]=v; break; case 13: vt[13]=v; break; case 14: vt[14]=v; break; default: vt[15]=v; break;
    }
  };

  const float eps = 5.9604645e-08f;
  const float unfl = 1.17549435e-38f;
  const float tol = 10.f*eps;
  float sminoa = fabsf(D[0]);
  if (sminoa != 0.f){
    float mu = sminoa;
    #pragma unroll
    for (int i = 1; i < 16; i++){
      mu = fabsf(D[i])*fdivf_(mu, mu + fabsf(E[i-1]));
      sminoa = fminf(sminoa, mu);
    }
  }
  sminoa = sminoa * 0.25f;   // == / sqrtf(16)
  float thresh = fmaxf(tol*sminoa, (float)(6*n*n)*unfl);
  int maxit = 6*n*n;
  int iter = 0, oldll = -1, oldm = -1, mm = n, idir = 0;
  while (true){
    if (mm <= 1) break;
    if (iter > maxit) break;
    // ---- split scan (bitmask form; identical llv/smaxw semantics) ----
    uint32_t msk = 0u;
    #pragma unroll
    for (int c = 0; c < 15; c++) msk |= (fabsf(E[c]) <= thresh) ? (1u << c) : 0u;
    msk &= (1u << (mm-1)) - 1u;          // keep c <= mm-2  (mm >= 2 here)
    msk = rflu(msk);
    int llv, clow; bool split;
    if (msk){ int cmax = 31 - __clz((int)msk); split = true; llv = cmax + 1; clow = cmax + 1; }
    else    { split = false; llv = 1; clow = 0; }
    float dm1 = getD(mm-1);
    float smaxw = fabsf(dm1);
    #pragma unroll
    for (int c = 0; c < 15; c++)
      if (c >= clow && c <= mm-2) smaxw = fmaxf(smaxw, fmaxf(fabsf(D[c]), fabsf(E[c])));
    if (split){
      setE(llv-1, 0.f);
      if (llv == mm-1){ mm = rfl(mm - 1); continue; }
      llv = llv + 1;
    }
    float dm2 = getD(mm-2);
    float e_m2 = getE(mm-2);
    float dll = getD(llv-1);
    float e_ll = getE(llv-1);
    if (llv == mm-1){
      float sigmn, sigmx, sinr, cosr, sinl, cosl;
      slasv2_(dm2, e_m2, dm1, sigmn, sigmx, sinr, cosr, sinl, cosl);
      setD(mm-2, sigmx); setE(mm-2, 0.f); setD(mm-1, sigmn);
      float t1 = getVt(mm-2), t2 = getVt(mm-1);
      setVt(mm-2, cosr*t1 + sinr*t2);
      setVt(mm-1, cosr*t2 - sinr*t1);
      mm = rfl(mm - 2);
      continue;
    }
    if (llv > oldm || mm < oldll)
      idir = (fabsf(dll) >= fabsf(dm1)) ? 1 : 2;
    idir = rfl(idir);
    bool deflated = false;
    float sminl = 0.f;
    if (idir == 1){
      int pc = (fabsf(e_m2) <= tol*fabsf(dm1)) ? 1 : 0;
      if (rfl(pc)){ setE(mm-2, 0.f); continue; }
      float mu = fabsf(dll); sminl = mu;
      #pragma unroll
      for (int c = 0; c < 15; c++){
        if (c >= llv-1 && c <= mm-2 && !deflated){
          if (fabsf(E[c]) <= tol*mu){ E[c] = 0.f; deflated = true; }
          else {
            mu = fabsf(D[c+1])*fdivf_(mu, mu + fabsf(E[c]));
            sminl = fminf(sminl, mu);
          }
        }
      }
    } else {
      int pc = (fabsf(e_ll) <= tol*fabsf(dll)) ? 1 : 0;
      if (rfl(pc)){ setE(llv-1, 0.f); continue; }
      float mu = fabsf(dm1); sminl = mu;
      #pragma unroll
      for (int c = 14; c >= 0; c--){
        if (c >= llv-1 && c <= mm-2 && !deflated){
          if (fabsf(E[c]) <= tol*mu){ E[c] = 0.f; deflated = true; }
          else {
            mu = fabsf(D[c])*fdivf_(mu, mu + fabsf(E[c]));
            sminl = fminf(sminl, mu);
          }
        }
      }
    }
    {
      int dfl = deflated ? 1 : 0;
      if (rfl(dfl)) continue;
    }
    oldll = llv; oldm = mm;
    float shift = 0.f, rdum;
    {
      int nosh = (!((float)n*tol*fdivf_(sminl, smaxw) <= fmaxf(eps, 0.01f*tol))) ? 1 : 0;
      if (rfl(nosh)){
        float sll;
        if (idir == 1){ sll = fabsf(dll); slas2_(dm2, e_m2, dm1, shift, rdum); }
        else          { sll = fabsf(dm1); slas2_(dll, e_ll, getD(llv), shift, rdum); }
        if (sll > 0.f){ float q = fdivf_(shift, sll); if (q*q < eps) shift = 0.f; }
      }
    }
    iter += mm - llv;
    int zsh = (shift == 0.f) ? 1 : 0;
    if (rfl(zsh)){
      if (idir == 1){
        float cs = 1.f, oldcs = 1.f, sn = 0.f, oldsn = 0.f, rr, dnew;
        #pragma unroll
        for (int i0 = 0; i0 < 15; i0++){
          if (i0 >= llv-1 && i0 <= mm-2){
            slartg_(D[i0]*cs, E[i0], cs, sn, rr);
            if (i0 > llv-1) E[i0-1 < 0 ? 0 : i0-1] = oldsn*rr;
            slartg_(oldcs*rr, D[i0+1]*sn, oldcs, oldsn, dnew);
            D[i0] = dnew;
            if (cs != 1.f || sn != 0.f){
              float t1 = vt[i0], t2 = vt[i0+1];
              vt[i0+1] = cs*t2 - sn*t1;
              vt[i0]   = sn*t2 + cs*t1;
            }
          }
        }
        float h = dm1*cs;           // D[mm-1] untouched in this sweep
        setD(mm-1, h*oldcs);
        float hv = h*oldsn;
        setE(mm-2, (fabsf(hv) <= thresh) ? 0.f : hv);
      } else {
        float cs = 1.f, oldcs = 1.f, sn = 0.f, oldsn = 0.f, rr, dnew;
        #pragma unroll
        for (int i0 = 15; i0 >= 1; i0--){
          if (i0 >= llv && i0 <= mm-1){
            slartg_(D[i0]*cs, E[i0-1], cs, sn, rr);
            if (i0 < mm-1) E[i0] = oldsn*rr;
            slartg_(oldcs*rr, D[i0-1]*sn, oldcs, oldsn, dnew);
            D[i0] = dnew;
            float cR = oldcs, sR = -oldsn;
            if (cR != 1.f || sR != 0.f){
              float t1 = vt[i0-1], t2 = vt[i0];
              vt[i0]   = cR*t2 - sR*t1;
              vt[i0-1] = sR*t2 + cR*t1;
            }
          }
        }
        float h = dll*cs;           // D[llv-1] untouched in this sweep
        setD(llv-1, h*oldcs);
        float hv = h*oldsn;
        setE(llv-1, (fabsf(hv) <= thresh) ? 0.f : hv);
      }
    } else {
      if (idir == 1){
        float dl = dll;
        float ff = (fabsf(dl) - shift)*(copysignf(1.f, dl) + fdivf_(shift, dl));
        float gg = e_ll;
        float cosr, sinr, cosl, sinl, rr;
        #pragma unroll
        for (int i0 = 0; i0 < 15; i0++){
          if (i0 >= llv-1 && i0 <= mm-2){
            slartg_(ff, gg, cosr, sinr, rr);
            if (i0 > llv-1) E[i0-1 < 0 ? 0 : i0-1] = rr;
            float di = D[i0], ei = E[i0];
            ff = cosr*di + sinr*ei;
            E[i0] = cosr*ei - sinr*di;
            gg = sinr*D[i0+1];
            D[i0+1] = cosr*D[i0+1];
            slartg_(ff, gg, cosl, sinl, rr);
            D[i0] = rr;
            float ei2 = E[i0], dip = D[i0+1];
            ff = cosl*ei2 + sinl*dip;
            D[i0+1] = cosl*dip - sinl*ei2;
            if (i0 < mm-2){
              gg = sinl*E[i0+1];
              E[i0+1] = cosl*E[i0+1];
            }
            if (cosr != 1.f || sinr != 0.f){
              float t1 = vt[i0], t2 = vt[i0+1];
              vt[i0+1] = cosr*t2 - sinr*t1;
              vt[i0]   = sinr*t2 + cosr*t1;
            }
          }
        }
        setE(mm-2, (fabsf(ff) <= thresh) ? 0.f : ff);
      } else {
        float dm = dm1;
        float ff = (fabsf(dm) - shift)*(copysignf(1.f, dm) + fdivf_(shift, dm));
        float gg = e_m2;
        float cosr, sinr, cosl, sinl, rr;
        #pragma unroll
        for (int i0 = 15; i0 >= 1; i0--){
          if (i0 >= llv && i0 <= mm-1){
            slartg_(ff, gg, cosr, sinr, rr);
            if (i0 < mm-1) E[i0] = rr;
            float di = D[i0], eim = E[i0-1];
            ff = cosr*di + sinr*eim;
            E[i0-1] = cosr*eim - sinr*di;
            gg = sinr*D[i0-1];
            D[i0-1] = cosr*D[i0-1];
            slartg_(ff, gg, cosl, sinl, rr);
            D[i0] = rr;
            float eim2 = E[i0-1], dim = D[i0-1];
            ff = cosl*eim2 + sinl*dim;
            D[i0-1] = cosl*dim - sinl*eim2;
            if (i0 > llv){
              gg = sinl*E[i0-2 < 0 ? 0 : i0-2];
              E[i0-2 < 0 ? 0 : i0-2] = cosl*E[i0-2 < 0 ? 0 : i0-2];
            }
            float cR = cosr, sR = -sinr;
            if (cR != 1.f || sR != 0.f){
              float t1 = vt[i0-1], t2 = vt[i0];
              vt[i0]   = cR*t2 - sR*t1;
              vt[i0-1] = sR*t2 + cR*t1;
            }
          }
        }
        setE(llv-1, (fabsf(ff) <= thresh) ? 0.f : ff);
      }
    }
  }
  // make positive
  #pragma unroll
  for (int k = 0; k < 16; k++){
    if (D[k] < 0.f){ D[k] = -D[k]; vt[k] = -vt[k]; }
  }
  // sort decreasing (selection, same tie-breaks as LAPACK slasrt-path in bdsqr)
  #pragma unroll
  for (int i = 1; i <= 15; i++){
    int isub = 1; float smn = D[0];
    #pragma unroll
    for (int jj = 2; jj <= 16; jj++){
      if (jj <= 16 + 1 - i){
        if (D[jj-1] <= smn){ isub = jj; smn = D[jj-1]; }
      }
    }
    if (isub != 16 + 1 - i){
      setD(isub - 1, D[16 - i]);
      D[16 - i] = smn;
      float tmp = getVt(isub - 1);
      setVt(isub - 1, vt[16 - i]);
      vt[16 - i] = tmp;
    }
  }
  // dump VT to LDS for row-wise ormbr
  if (l < 16){
    #pragma unroll
    for (int r = 0; r < 16; r++) VTm[r][l] = vt[r];
  }
  __syncthreads();
  // ormbr('P','R','T'): VT := VT * G(n-1)...G(1)
  for (int i = n-2; i >= 0; i--){
    float tp = taup[i];
    if (tp != 0.f && l < 16){
      int r = l;
      float w = VTm[r][i+1];
      for (int c = i+2; c < n; c++) w += VTm[r][c]*A[i][c];
      w *= tp;
      VTm[r][i+1] -= w;
      for (int c = i+2; c < n; c++) VTm[r][c] -= w*A[i][c];
    }
    __syncthreads();
  }
  for (int idx = l; idx < 256; idx += 64) vtlOut[idx] = VTm[idx>>4][idx&15];
}

// K12: R = Qqr * VT_L^T ; Rinv = R^T
__global__ __launch_bounds__(256) void k_rout(float* __restrict__ ws, float* __restrict__ out){
  int ty = blockIdx.y;
  const float* Qq = ws + OFF_QQR + (size_t)ty*65536;
  const float* vtl = ws + OFF_VTL + ty*256;
  long long Roff  = ty ? OUT_R2  : OUT_R1;
  long long RIoff = ty ? OUT_RI2 : OUT_RI1;
  __shared__ float V[16][16];
  int t = threadIdx.x;
  V[t>>4][t&15] = vtl[t];
  __syncthreads();
  int row = blockIdx.x*256 + t;
  float mv[16];
  #pragma unroll
  for (int q = 0; q < 4; q++){
    float4 v = ((const float4*)(Qq + (size_t)row*16))[q];
    mv[q*4] = v.x; mv[q*4+1] = v.y; mv[q*4+2] = v.z; mv[q*4+3] = v.w;
  }
  #pragma unroll
  for (int j = 0; j < 16; j++){
    float s = 0.f;
    #pragma unroll
    for (int i = 0; i < 16; i++) s = fmaf(mv[i], V[j][i], s);
    out[Roff + (long long)row*16 + j] = s;
    out[RIoff + (long long)j*4096 + row] = s;
  }
}

// ===========================================================================
extern "C" void kernel_launch(void* const* d_in, const int* in_sizes, int n_in,
                              void* d_out, int out_size, void* d_ws, size_t ws_size,
                              hipStream_t stream){
  const float* x1 = (const float*)d_in[0];
  const float* x2 = (const float*)d_in[1];
  float* out = (float*)d_out;
  float* ws = (float*)d_ws;
  (void)in_sizes; (void)n_in; (void)out_size; (void)ws_size;

  hipMemsetAsync(ws + ZERO_BASE, 0, ZERO_FLOATS*sizeof(float), stream);

  k_had<<<dim3(1024), 256, 0, stream>>>(x1, x2, out, ws);
  k_red<<<dim3(8, 2), 1024, 0, stream>>>(ws);
  k_wselect<<<dim3(2), 256, 0, stream>>>(ws);
  k_fine<<<dim3(1024, 2), 256, 0, stream>>>(x1, x2, ws);
  k_fine_sel<<<dim3(2), 256, 0, stream>>>(ws, out);
  k_fallback<<<dim3(2), 256, 0, stream>>>(x1, x2, ws, out);  // early-exit normally

  uint32_t a0, a1, b0, b1;
  h_threefry(0u, 42u, 0u, 0u, a0, a1);
  h_threefry(0u, 42u, 0u, 1u, b0, b1);
  k_omega<<<dim3(256, 2), 256, 0, stream>>>(a0, a1, b0, b1, ws);

  // QR1
  k_atype<<<dim3(512, 2), 256, 0, stream>>>(x1, x2, ws, OFF_OMT);
  k_gramP<<<dim3(64, 2), 256, 0, stream>>>(ws, OFF_BIGY, 131072);
  k_tiny<<<dim3(2), 64, 0, stream>>>(ws, OFF_BIGY, 131072);
  k_applyq<<<dim3(32, 2), 256, 0, stream>>>(ws, OFF_BIGY, 131072, OFF_BIGQ, 131072, 8192, 1, 0);
  // QR2
  k_btype<<<dim3(256, 2), 256, 0, stream>>>(x1, x2, ws);
  k_bredgram<<<dim3(64, 2), 256, 0, stream>>>(ws);
  k_tiny<<<dim3(2), 64, 0, stream>>>(ws, OFF_TMAT, 65536);
  k_applyq<<<dim3(16, 2), 256, 0, stream>>>(ws, OFF_TMAT, 65536, OFF_ZT, 65536, 4096, 0, 1);
  // QR3
  k_atype<<<dim3(512, 2), 256, 0, stream>>>(x1, x2, ws, OFF_ZT);
  k_gramP<<<dim3(64, 2), 256, 0, stream>>>(ws, OFF_BIGY, 131072);
  k_tiny<<<dim3(2), 64, 0, stream>>>(ws, OFF_BIGY, 131072);
  k_applyq<<<dim3(32, 2), 256, 0, stream>>>(ws, OFF_BIGY, 131072, OFF_BIGQ, 131072, 8192, 1, 0);
  // QR4
  k_btype<<<dim3(256, 2), 256, 0, stream>>>(x1, x2, ws);
  k_bredgram<<<dim3(64, 2), 256, 0, stream>>>(ws);
  k_tiny<<<dim3(2), 64, 0, stream>>>(ws, OFF_TMAT, 65536);
  k_applyq<<<dim3(16, 2), 256, 0, stream>>>(ws, OFF_TMAT, 65536, OFF_ZT, 65536, 4096, 0, 1);
  // QR5
  k_atype<<<dim3(512, 2), 256, 0, stream>>>(x1, x2, ws, OFF_ZT);
  k_gramP<<<dim3(64, 2), 256, 0, stream>>>(ws, OFF_BIGY, 131072);
  k_tiny<<<dim3(2), 64, 0, stream>>>(ws, OFF_BIGY, 131072);
  k_applyq<<<dim3(32, 2), 256, 0, stream>>>(ws, OFF_BIGY, 131072, OFF_BIGQ, 131072, 8192, 1, 0);
  // QR6
  k_btype<<<dim3(256, 2), 256, 0, stream>>>(x1, x2, ws);
  k_bredgram<<<dim3(64, 2), 256, 0, stream>>>(ws);
  k_tiny<<<dim3(2), 64, 0, stream>>>(ws, OFF_TMAT, 65536);
  k_applyq<<<dim3(16, 2), 256, 0, stream>>>(ws, OFF_TMAT, 65536, OFF_QQR, 65536, 4096, 1, 0);

  k_chain<<<dim3(2), 64, 0, stream>>>(ws);
  k_rout<<<dim3(16, 2), 256, 0, stream>>>(ws, out);
}